// Round 3
// baseline (21980.020 us; speedup 1.0000x reference)
//
#include <hip/hip_runtime.h>
#include <hip/hip_bf16.h>

using bf16 = __hip_bfloat16;
typedef unsigned char u8;

#define BNS 0.9999950000374997f   // 1/sqrt(1+1e-5)

__device__ __forceinline__ float b2f(bf16 v){ return __bfloat162float(v); }
__device__ __forceinline__ bf16 f2b(float v){ return __float2bfloat16(v); }

// ---------------- mask kernels ----------------

__global__ __launch_bounds__(256) void k_mask1(const float* __restrict__ roi, u8* __restrict__ m1, int total){
    int i = blockIdx.x*256 + threadIdx.x;
    if (i < total) m1[i] = (roi[i] > 0.8f) ? 1 : 0;
}

// 3x3 stride-2 pad-1 max-pool on a binary mask (== active-site rule)
__global__ __launch_bounds__(256) void k_down(const u8* __restrict__ mi, u8* __restrict__ mo,
                                              int IH, int IW, int OH, int OW){
    int p = blockIdx.x*256 + threadIdx.x;
    int n = blockIdx.y;
    if (p >= OH*OW) return;
    int oy = p / OW, ox = p - oy*OW;
    const u8* src = mi + (size_t)n*IH*IW;
    int v = 0;
    #pragma unroll
    for (int ky=0; ky<3; ky++){
        int iy = 2*oy + ky - 1;
        if ((unsigned)iy >= (unsigned)IH) continue;
        #pragma unroll
        for (int kx=0; kx<3; kx++){
            int ix = 2*ox + kx - 1;
            if ((unsigned)ix < (unsigned)IW) v |= src[iy*IW + ix];
        }
    }
    mo[(size_t)n*OH*OW + p] = (u8)v;
}

// ---------------- simple direct 3x3 conv (OS2/OS4 stages) ----------------
// reads bf16 intermediates from ws; weights fp32 (global inputs)
// EPI: 0 = mask ? relu(acc)*BNS : 0
//      1 = mask ? leaky(acc*BNS, 0.2) : 0
//      3 = mask ? relu(acc)*BNS + res[(n/4),co,p] : 0   (xs = xg + fea3; res fp32)
//      4 = mask ? acc + bias : -99                      (refine head, COUT=1)
template<int CIN, int COUT, int STRIDE, int EPI, typename OutT>
__global__ __launch_bounds__(256) void conv3x3_k(const bf16* __restrict__ in, int IH, int IW,
                                                 const float* __restrict__ w,
                                                 const float* __restrict__ wb,
                                                 const u8*   __restrict__ mask,
                                                 const float* __restrict__ res,
                                                 OutT* __restrict__ out, int OH, int OW)
{
    __shared__ float ws[CIN*9];
    int n = blockIdx.z, co = blockIdx.y;
    for (int i = threadIdx.x; i < CIN*9; i += blockDim.x)
        ws[i] = w[(size_t)co*CIN*9 + i];
    __syncthreads();

    int p = blockIdx.x*blockDim.x + threadIdx.x;
    if (p >= OH*OW) return;
    int oy = p / OW, ox = p - oy*OW;
    int ybase = oy*STRIDE - 1, xbase = ox*STRIDE - 1;

    float acc = 0.f;
    const bf16* ibase = in + (size_t)n*CIN*IH*IW;
    for (int c = 0; c < CIN; ++c) {
        const bf16* ic = ibase + (size_t)c*IH*IW;
        const float* wc = ws + c*9;
        #pragma unroll
        for (int ky = 0; ky < 3; ++ky) {
            int iy = ybase + ky;
            if ((unsigned)iy >= (unsigned)IH) continue;
            const bf16* irow = ic + (size_t)iy*IW;
            #pragma unroll
            for (int kx = 0; kx < 3; ++kx) {
                int ix = xbase + kx;
                if ((unsigned)ix < (unsigned)IW)
                    acc += b2f(irow[ix]) * wc[ky*3 + kx];
            }
        }
    }

    bool m = mask[(size_t)n*OH*OW + p] != 0;
    float o;
    if      (EPI == 0) { o = m ? fmaxf(acc, 0.f)*BNS : 0.f; }
    else if (EPI == 1) { float s = acc*BNS; o = m ? (s > 0.f ? s : 0.2f*s) : 0.f; }
    else if (EPI == 3) { o = m ? fmaxf(acc, 0.f)*BNS + res[((size_t)(n>>2)*COUT + co)*(size_t)(OH*OW) + p] : 0.f; }
    else               { o = m ? acc + wb[0] : -99.f; }
    size_t oidx = ((size_t)n*COUT + co)*(size_t)(OH*OW) + p;
    if constexpr (sizeof(OutT) == 4) out[oidx] = o; else out[oidx] = f2b(o);
}

// ---------------- fused OS1 front: build-input + conv1a + conv1b -> fea1 ----------------
// 16x16 output tile; f (18x18x32) lives in LDS; ~47 KB LDS.
__global__ __launch_bounds__(256) void fk_front(const float* __restrict__ image,
                                                const float* __restrict__ masks,
                                                const u8*  __restrict__ M1,
                                                const float* __restrict__ w1a,
                                                const float* __restrict__ w1b,
                                                bf16* __restrict__ fea1)
{
    const int H = 384; const int HW = H*H;
    int tY = blockIdx.x / 24, tX = blockIdx.x % 24, n = blockIdx.y;
    int y0 = tY*16, x0 = tX*16;

    __shared__ bf16  s_inp[4][20][20];
    __shared__ u8    s_m[20][20];
    __shared__ bf16  s_f[32][18][18];
    __shared__ float s_wa[32*4*9];
    __shared__ bf16  s_wb[32*32*9];

    int tid = threadIdx.x;
    for (int i = tid; i < 32*4*9;  i += 256) s_wa[i] = w1a[i];
    for (int i = tid; i < 32*32*9; i += 256) s_wb[i] = f2b(w1b[i]);

    // input tile, origin (y0-2, x0-2), masked by mask1; OOB -> 0
    for (int i = tid; i < 400; i += 256){
        int ly = i/20, lx = i%20;
        int gy = y0-2+ly, gx = x0-2+lx;
        bool inb = ((unsigned)gy < 384u) && ((unsigned)gx < 384u);
        u8 mv = inb ? M1[(size_t)n*HW + gy*H + gx] : 0;
        s_m[ly][lx] = mv;
        float mm = (float)mv;
        int p = gy*H + gx;
        #pragma unroll
        for (int c = 0; c < 4; ++c){
            float v = 0.f;
            if (inb) v = (c < 3) ? image[((size_t)(n>>2)*3 + c)*HW + p]
                                 : masks[(size_t)n*HW + p];
            s_inp[c][ly][lx] = f2b(v*mm);
        }
    }
    __syncthreads();

    // stage 1: f tile 18x18x32, origin (y0-1, x0-1)
    for (int i = tid; i < 18*18*32; i += 256){
        int c = i / 324; int r = i - c*324; int fy = r/18, fx = r%18;
        float acc = 0.f;
        const float* w = s_wa + c*36;
        #pragma unroll
        for (int ci = 0; ci < 4; ++ci)
            #pragma unroll
            for (int k = 0; k < 9; ++k)
                acc += b2f(s_inp[ci][fy + k/3][fx + k%3]) * w[ci*9 + k];
        float o = s_m[fy+1][fx+1] ? fmaxf(acc, 0.f)*BNS : 0.f;
        s_f[c][fy][fx] = f2b(o);
    }
    __syncthreads();

    // stage 2: fea1 16x16, one pixel per thread
    int ty = tid/16, tx = tid%16;
    int gy = y0+ty, gx = x0+tx;
    u8 m = s_m[ty+2][tx+2];
    for (int co = 0; co < 32; ++co){
        float acc = 0.f;
        const bf16* w = s_wb + co*288;
        for (int ci = 0; ci < 32; ++ci){
            const bf16* wc = w + ci*9;
            #pragma unroll
            for (int ky = 0; ky < 3; ++ky)
                #pragma unroll
                for (int kx = 0; kx < 3; ++kx)
                    acc += b2f(s_f[ci][ty+ky][tx+kx]) * b2f(wc[ky*3+kx]);
        }
        float o = m ? fmaxf(acc, 0.f)*BNS : 0.f;
        fea1[((size_t)n*32 + co)*HW + gy*H + gx] = f2b(o);
    }
}

// ---------------- fused layer4: invconv(64->64)+leaky + l4_sub(64->32)+fea2 -> u ----------------
// OS2 16x16 tile; ~54.6 KB LDS; weights read from global fp32 (uniform -> L1 broadcast).
__global__ __launch_bounds__(256) void fk_layer4(const bf16* __restrict__ xs,
                                                 const bf16* __restrict__ fea2,
                                                 const u8*  __restrict__ M2,
                                                 const float* __restrict__ w_inv,
                                                 const float* __restrict__ w_sub,
                                                 bf16* __restrict__ u_out)
{
    const int H2 = 192, HW2 = H2*H2, H4 = 96, HW4 = H4*H4;
    int tY = blockIdx.x / 12, tX = blockIdx.x % 12, n = blockIdx.y;
    int y0 = tY*16, x0 = tX*16;
    int uy0 = y0/2 - 1, ux0 = x0/2 - 1;     // xs tile origin (10x10)

    __shared__ bf16 s_xs[64][10][10];
    __shared__ bf16 s_ul[64][18][18];
    __shared__ u8   s_m[18][18];

    int tid = threadIdx.x;
    for (int i = tid; i < 64*100; i += 256){
        int c = i/100, r = i%100; int ly = r/10, lx = r%10;
        int gy = uy0+ly, gx = ux0+lx;
        bf16 v = f2b(0.f);
        if ((unsigned)gy < 96u && (unsigned)gx < 96u) v = xs[((size_t)n*64 + c)*HW4 + gy*H4 + gx];
        s_xs[c][ly][lx] = v;
    }
    for (int i = tid; i < 324; i += 256){
        int ly = i/18, lx = i%18; int gy = y0-1+ly, gx = x0-1+lx;
        s_m[ly][lx] = ((unsigned)gy < 192u && (unsigned)gx < 192u) ? M2[(size_t)n*HW2 + gy*H2 + gx] : 0;
    }
    __syncthreads();

    // stage 1: u_leaky 18x18x64, origin (y0-1, x0-1)
    for (int i = tid; i < 64*324; i += 256){
        int c = i/324; int r = i - c*324; int Y = r/18, X = r%18;
        float o = 0.f;
        if (s_m[Y][X]){
            int gY = y0-1+Y, gX = x0-1+X;
            float acc = 0.f;
            #pragma unroll
            for (int ky = 0; ky < 3; ++ky){
                int t = gY + ky - 1; if (t < 0 || (t & 1)) continue;
                int iy = t >> 1; if (iy >= 96) continue;
                int liy = iy - uy0;
                #pragma unroll
                for (int kx = 0; kx < 3; ++kx){
                    int s = gX + kx - 1; if (s < 0 || (s & 1)) continue;
                    int ix = s >> 1; if (ix >= 96) continue;
                    int lix = ix - ux0;
                    const float* wp = w_inv + (size_t)((2-ky)*3 + (2-kx));
                    float sum = 0.f;
                    for (int ci = 0; ci < 64; ++ci)
                        sum += b2f(s_xs[ci][liy][lix]) * wp[(size_t)(c*64 + ci)*9];
                    acc += sum;
                }
            }
            float sc = acc * BNS;
            o = sc > 0.f ? sc : 0.2f*sc;
        }
        s_ul[c][Y][X] = f2b(o);
    }
    __syncthreads();

    // stage 2: u = conv(u_leaky, l4_sub)*m + fea2, one pixel per thread
    int ty = tid/16, tx = tid%16;
    int gy = y0+ty, gx = x0+tx;
    u8 m = s_m[ty+1][tx+1];
    for (int co = 0; co < 32; ++co){
        float acc = 0.f;
        if (m){
            for (int ci = 0; ci < 64; ++ci){
                const float* w9 = w_sub + (size_t)(co*64 + ci)*9;
                #pragma unroll
                for (int ky = 0; ky < 3; ++ky)
                    #pragma unroll
                    for (int kx = 0; kx < 3; ++kx)
                        acc += b2f(s_ul[ci][ty+ky][tx+kx]) * w9[ky*3+kx];
            }
            acc += b2f(fea2[((size_t)n*32 + co)*HW2 + gy*H2 + gx]);
        }
        u_out[((size_t)n*32 + co)*HW2 + gy*H2 + gx] = f2b(acc);
    }
}

// ---------------- fused back end: invconv(32->32)+l5_sub+fea1 + refine_OS1 -> out1 ----------------
// OS1 16x16 tile; 4 chained stages, LDS regions aliased; 59.1 KB LDS.
__global__ __launch_bounds__(256) void fk_back(const bf16* __restrict__ u,
                                               const bf16* __restrict__ fea1,
                                               const u8*  __restrict__ M1,
                                               const float* __restrict__ w_inv2,
                                               const float* __restrict__ w_l5,
                                               const float* __restrict__ w_r1a,
                                               const float* __restrict__ w_r1b,
                                               const float* __restrict__ r1_b2,
                                               float* __restrict__ out1)
{
    const int H1 = 384, HW1 = H1*H1, H2 = 192, HW2 = H2*H2;
    int tY = blockIdx.x / 24, tX = blockIdx.x % 24, n = blockIdx.y;
    int y0 = tY*16, x0 = tX*16;
    int uy0 = y0/2 - 2, ux0 = x0/2 - 2;      // u tile origin (12x12)

    __shared__ __align__(16) char smem[59120];
    bf16* s_u  = (bf16*)smem;                         // 32*144  = 4608 el, 9216 B
    bf16* s_w  = (bf16*)(smem + 9216);                // 9216 el, 18432 B (inv2 stage only)
    bf16* s_vl = (bf16*)(smem + 9216 + 18432);        // 32*484 = 15488 el, 30976 B
    u8*   s_m  = (u8*)(smem + 9216 + 18432 + 30976);  // 484 B
    bf16* s_v  = (bf16*)smem;                         // alias s_u+s_w: 32*400 el, 25600 B
    bf16* s_t1 = (bf16*)(smem + 9216 + 18432);        // alias s_vl: 32*324 el, 20736 B

    int tid = threadIdx.x;
    for (int i = tid; i < 32*144; i += 256){
        int c = i/144, r = i%144; int ly = r/12, lx = r%12;
        int gy = uy0+ly, gx = ux0+lx;
        bf16 v = f2b(0.f);
        if ((unsigned)gy < 192u && (unsigned)gx < 192u) v = u[((size_t)n*32 + c)*HW2 + gy*H2 + gx];
        s_u[c*144 + r] = v;
    }
    for (int i = tid; i < 32*32*9; i += 256) s_w[i] = f2b(w_inv2[i]);
    for (int i = tid; i < 484; i += 256){
        int ly = i/22, lx = i%22; int gy = y0-3+ly, gx = x0-3+lx;
        s_m[i] = ((unsigned)gy < 384u && (unsigned)gx < 384u) ? M1[(size_t)n*HW1 + gy*H1 + gx] : 0;
    }
    __syncthreads();

    // stage 1: v_leaky 22x22x32, origin (y0-3, x0-3)
    for (int i = tid; i < 32*484; i += 256){
        int c = i/484; int r = i - c*484; int Y = r/22, X = r%22;
        float o = 0.f;
        if (s_m[r]){
            int gY = y0-3+Y, gX = x0-3+X;
            float acc = 0.f;
            #pragma unroll
            for (int ky = 0; ky < 3; ++ky){
                int t = gY + ky - 1; if (t < 0 || (t & 1)) continue;
                int iy = t >> 1; if (iy >= 192) continue;
                int liy = iy - uy0;
                #pragma unroll
                for (int kx = 0; kx < 3; ++kx){
                    int s = gX + kx - 1; if (s < 0 || (s & 1)) continue;
                    int ix = s >> 1; if (ix >= 192) continue;
                    int lix = ix - ux0;
                    int wk = (2-ky)*3 + (2-kx);
                    float sum = 0.f;
                    for (int ci = 0; ci < 32; ++ci)
                        sum += b2f(s_u[ci*144 + liy*12 + lix]) * b2f(s_w[(c*32 + ci)*9 + wk]);
                    acc += sum;
                }
            }
            float sc = acc * BNS;
            o = sc > 0.f ? sc : 0.2f*sc;
        }
        s_vl[c*484 + r] = f2b(o);
    }
    __syncthreads();

    // stage 2: v 20x20x32, origin (y0-2, x0-2) -> aliases s_u/s_w region (both dead)
    for (int i = tid; i < 32*400; i += 256){
        int c = i/400; int r = i - c*400; int vy = r/20, vx = r%20;
        float o = 0.f;
        u8 m = s_m[(vy+1)*22 + (vx+1)];
        if (m){
            int gY = y0-2+vy, gX = x0-2+vx;
            float acc = 0.f;
            for (int ci = 0; ci < 32; ++ci){
                const float* w9 = w_l5 + (size_t)(c*32 + ci)*9;
                const bf16* vb = s_vl + ci*484 + vy*22 + vx;
                #pragma unroll
                for (int ky = 0; ky < 3; ++ky)
                    #pragma unroll
                    for (int kx = 0; kx < 3; ++kx)
                        acc += b2f(vb[ky*22 + kx]) * w9[ky*3+kx];
            }
            o = acc + b2f(fea1[((size_t)n*32 + c)*HW1 + gY*H1 + gX]);
        }
        s_v[c*400 + r] = f2b(o);
    }
    __syncthreads();

    // stage 3: t1 18x18x32, origin (y0-1, x0-1) -> aliases s_vl (dead)
    for (int i = tid; i < 32*324; i += 256){
        int c = i/324; int r = i - c*324; int qy = r/18, qx = r%18;
        float o = 0.f;
        if (s_m[(qy+2)*22 + (qx+2)]){
            float acc = 0.f;
            for (int ci = 0; ci < 32; ++ci){
                const float* w9 = w_r1a + (size_t)(c*32 + ci)*9;
                const bf16* vb = s_v + ci*400 + qy*20 + qx;
                #pragma unroll
                for (int ky = 0; ky < 3; ++ky)
                    #pragma unroll
                    for (int kx = 0; kx < 3; ++kx)
                        acc += b2f(vb[ky*20 + kx]) * w9[ky*3+kx];
            }
            float sc = acc * BNS;
            o = sc > 0.f ? sc : 0.2f*sc;
        }
        s_t1[c*324 + r] = f2b(o);
    }
    __syncthreads();

    // stage 4: out1 16x16, one pixel per thread
    int ty = tid/16, tx = tid%16;
    int gy = y0+ty, gx = x0+tx;
    u8 m = s_m[(ty+3)*22 + (tx+3)];
    float o = -99.f;
    if (m){
        float acc = 0.f;
        for (int ci = 0; ci < 32; ++ci){
            const float* w9 = w_r1b + ci*9;
            const bf16* vb = s_t1 + ci*324 + ty*18 + tx;
            #pragma unroll
            for (int ky = 0; ky < 3; ++ky)
                #pragma unroll
                for (int kx = 0; kx < 3; ++kx)
                    acc += b2f(vb[ky*18 + kx]) * w9[ky*3+kx];
        }
        o = acc + r1_b2[0];
    }
    out1[(size_t)n*HW1 + gy*H1 + gx] = o;
}

// ---------------- launch ----------------

extern "C" void kernel_launch(void* const* d_in, const int* in_sizes, int n_in,
                              void* d_out, int out_size, void* d_ws, size_t ws_size,
                              hipStream_t stream)
{
    const float* x      = (const float*)d_in[0];
    const float* image  = (const float*)d_in[1];
    const float* masks  = (const float*)d_in[2];
    const float* roi    = (const float*)d_in[3];
    const float* w1a    = (const float*)d_in[4];
    const float* w1b    = (const float*)d_in[5];
    const float* w2a    = (const float*)d_in[6];
    const float* w2b    = (const float*)d_in[7];
    const float* w4a    = (const float*)d_in[8];
    const float* w4b    = (const float*)d_in[9];
    const float* inv4_w = (const float*)d_in[10];
    const float* l4_sub = (const float*)d_in[11];
    const float* inv2_w = (const float*)d_in[12];
    const float* l5_sub = (const float*)d_in[13];
    const float* r4_w1  = (const float*)d_in[14];
    const float* r4_w2  = (const float*)d_in[15];
    const float* r4_b2  = (const float*)d_in[16];
    const float* r1_w1  = (const float*)d_in[17];
    const float* r1_w2  = (const float*)d_in[18];
    const float* r1_b2  = (const float*)d_in[19];
    float* out = (float*)d_out;

    const int N = 8;
    const int H1 = 384, HW1 = 384*384;
    const int H2 = 192, HW2 = 192*192;
    const int H4 = 96,  HW4 = 96*96;

    char* wsp = (char*)d_ws;
    size_t off = 0;
    auto alloc = [&](size_t bytes) -> char* {
        char* p = wsp + off;
        off += (bytes + 255) & ~(size_t)255;
        return p;
    };
    bf16* FEA1 = (bf16*)alloc((size_t)N*32*HW1*2);  // 72 MiB
    bf16* GU   = (bf16*)alloc((size_t)N*32*HW2*2);  // g, later u  (18 MiB)
    bf16* FEA2 = (bf16*)alloc((size_t)N*32*HW2*2);  // 18 MiB
    bf16* HT   = (bf16*)alloc((size_t)N*64*HW4*2);  // h, later t_leaky (9.4 MiB)
    bf16* XS   = (bf16*)alloc((size_t)N*64*HW4*2);  // 9.4 MiB
    u8*   M1   = (u8*)alloc((size_t)N*HW1);
    u8*   M2   = (u8*)alloc((size_t)N*HW2);
    u8*   M4   = (u8*)alloc((size_t)N*HW4);
    (void)ws_size; (void)in_sizes; (void)n_in; (void)out_size;

    dim3 blk(256);

    // masks
    k_mask1<<<dim3((N*HW1 + 255)/256), blk, 0, stream>>>(roi, M1, N*HW1);
    k_down<<<dim3((HW2 + 255)/256, N), blk, 0, stream>>>(M1, M2, H1, H1, H2, H2);
    k_down<<<dim3((HW4 + 255)/256, N), blk, 0, stream>>>(M2, M4, H2, H2, H4, H4);

    // fused OS1 front -> fea1
    fk_front<<<dim3(576, N), blk, 0, stream>>>(image, masks, M1, w1a, w1b, FEA1);

    // low_os2: g, fea2
    conv3x3_k<32,32,2,0,bf16><<<dim3(HW2/256, 32, N), blk, 0, stream>>>(FEA1, H1, H1, w2a, nullptr, M2, nullptr, GU, H2, H2);
    conv3x3_k<32,32,1,0,bf16><<<dim3(HW2/256, 32, N), blk, 0, stream>>>(GU, H2, H2, w2b, nullptr, M2, nullptr, FEA2, H2, H2);
    // low_os4: h, xs = fea3 + x*mask4
    conv3x3_k<32,64,2,0,bf16><<<dim3(HW4/256, 64, N), blk, 0, stream>>>(FEA2, H2, H2, w4a, nullptr, M4, nullptr, HT, H4, H4);
    conv3x3_k<64,64,1,3,bf16><<<dim3(HW4/256, 64, N), blk, 0, stream>>>(HT, H4, H4, w4b, nullptr, M4, x, XS, H4, H4);

    // refine_OS4 (h buffer reused for t_leaky)
    conv3x3_k<64,32,1,1,bf16><<<dim3(HW4/256, 32, N), blk, 0, stream>>>(XS, H4, H4, r4_w1, nullptr, M4, nullptr, HT, H4, H4);
    conv3x3_k<32,1,1,4,float><<<dim3(HW4/256, 1, N), blk, 0, stream>>>(HT, H4, H4, r4_w2, r4_b2, M4, nullptr, out, H4, H4);

    // fused layer4 -> u (reuses g buffer)
    fk_layer4<<<dim3(144, N), blk, 0, stream>>>(XS, FEA2, M2, inv4_w, l4_sub, GU);

    // fused layer5 + refine_OS1 -> out1
    fk_back<<<dim3(576, N), blk, 0, stream>>>(GU, FEA1, M1, inv2_w, l5_sub, r1_w1, r1_w2, r1_b2,
                                              out + (size_t)N*HW4);
}

// Round 4
// 7538.055 us; speedup vs baseline: 2.9159x; 2.9159x over previous
//
#include <hip/hip_runtime.h>
#include <hip/hip_bf16.h>

using bf16 = __hip_bfloat16;
typedef unsigned char u8;

#define BNS 0.9999950000374997f   // 1/sqrt(1+1e-5)

__device__ __forceinline__ float b2f(bf16 v){ return __bfloat162float(v); }
__device__ __forceinline__ bf16 f2b(float v){ return __float2bfloat16(v); }

// ---------------- mask kernels ----------------

__global__ __launch_bounds__(256) void k_mask1(const float* __restrict__ roi, u8* __restrict__ m1, int total){
    int i = blockIdx.x*256 + threadIdx.x;
    if (i < total) m1[i] = (roi[i] > 0.8f) ? 1 : 0;
}

__global__ __launch_bounds__(256) void k_down(const u8* __restrict__ mi, u8* __restrict__ mo,
                                              int IH, int IW, int OH, int OW){
    int p = blockIdx.x*256 + threadIdx.x;
    int n = blockIdx.y;
    if (p >= OH*OW) return;
    int oy = p / OW, ox = p - oy*OW;
    const u8* src = mi + (size_t)n*IH*IW;
    int v = 0;
    #pragma unroll
    for (int ky=0; ky<3; ky++){
        int iy = 2*oy + ky - 1;
        if ((unsigned)iy >= (unsigned)IH) continue;
        #pragma unroll
        for (int kx=0; kx<3; kx++){
            int ix = 2*ox + kx - 1;
            if ((unsigned)ix < (unsigned)IW) v |= src[iy*IW + ix];
        }
    }
    mo[(size_t)n*OH*OW + p] = (u8)v;
}

// ---------------- proven round-3 kernel, kept for COUT=1 heads (EPI4) ----------------
template<int CIN, int COUT, int STRIDE, int EPI, typename OutT>
__global__ __launch_bounds__(256) void conv3x3_k(const bf16* __restrict__ in, int IH, int IW,
                                                 const float* __restrict__ w,
                                                 const float* __restrict__ wb,
                                                 const u8*   __restrict__ mask,
                                                 const float* __restrict__ res,
                                                 OutT* __restrict__ out, int OH, int OW)
{
    __shared__ float ws[CIN*9];
    int n = blockIdx.z, co = blockIdx.y;
    for (int i = threadIdx.x; i < CIN*9; i += blockDim.x)
        ws[i] = w[(size_t)co*CIN*9 + i];
    __syncthreads();

    int p = blockIdx.x*blockDim.x + threadIdx.x;
    if (p >= OH*OW) return;
    int oy = p / OW, ox = p - oy*OW;
    int ybase = oy*STRIDE - 1, xbase = ox*STRIDE - 1;

    float acc = 0.f;
    const bf16* ibase = in + (size_t)n*CIN*IH*IW;
    for (int c = 0; c < CIN; ++c) {
        const bf16* ic = ibase + (size_t)c*IH*IW;
        const float* wc = ws + c*9;
        #pragma unroll
        for (int ky = 0; ky < 3; ++ky) {
            int iy = ybase + ky;
            if ((unsigned)iy >= (unsigned)IH) continue;
            const bf16* irow = ic + (size_t)iy*IW;
            #pragma unroll
            for (int kx = 0; kx < 3; ++kx) {
                int ix = xbase + kx;
                if ((unsigned)ix < (unsigned)IW)
                    acc += b2f(irow[ix]) * wc[ky*3 + kx];
            }
        }
    }
    bool m = mask[(size_t)n*OH*OW + p] != 0;
    float o;
    if      (EPI == 0) { o = m ? fmaxf(acc, 0.f)*BNS : 0.f; }
    else if (EPI == 1) { float s = acc*BNS; o = m ? (s > 0.f ? s : 0.2f*s) : 0.f; }
    else               { o = m ? acc + wb[0] : -99.f; }
    size_t oidx = ((size_t)n*COUT + co)*(size_t)(OH*OW) + p;
    if constexpr (sizeof(OutT) == 4) out[oidx] = o; else out[oidx] = f2b(o);
}

// ---------------- v2 engine: stride-1 conv, tile 32x16, 2 px/thread, COUTB co/block ----
// weights via uniform (scalar) loads; features fp32 in LDS, 8 ci per sync round.
// EPI: 0 relu*BNS*m | 1 m?leaky(acc*BNS) | 3 m?relu*BNS + res32[(n>>2),cog] : 0
template<int CIN, int COUTB, int COUT_TOT, int EPI>
__global__ __launch_bounds__(256) void conv_s1(const bf16* __restrict__ in, int IH, int IW,
                                               const float* __restrict__ w,   // [COUT_TOT][CIN][9]
                                               const u8* __restrict__ mask,
                                               const float* __restrict__ res32,
                                               bf16* __restrict__ out, int OH, int OW, int tilesX)
{
    const int TH=32, TW=16;
    int n = blockIdx.z, cog = blockIdx.y;
    int tY = blockIdx.x / tilesX, tX = blockIdx.x % tilesX;
    int y0 = tY*TH, x0 = tX*TW;
    const float* wB = w + (size_t)cog*COUTB*CIN*9;

    __shared__ float s_in[8][34*18];

    int tid = threadIdx.x;
    int lx = tid & 15;
    int lyb = (tid >> 4) * 2;

    float acc[2][COUTB];
    #pragma unroll
    for (int j=0;j<2;++j)
        #pragma unroll
        for (int c=0;c<COUTB;++c) acc[j][c]=0.f;

    const bf16* inN = in + (size_t)n*CIN*IH*IW;
    for (int c0 = 0; c0 < CIN; c0 += 8){
        __syncthreads();
        for (int i = tid; i < 8*612; i += 256){
            int cc = i / 612; int r = i % 612;
            int ly = r / 18, lxx = r % 18;
            int gy = y0-1+ly, gx = x0-1+lxx;
            float v = 0.f;
            if ((unsigned)gy < (unsigned)IH && (unsigned)gx < (unsigned)IW)
                v = b2f(inN[(size_t)(c0+cc)*IH*IW + (size_t)gy*IW + gx]);
            s_in[cc][r] = v;
        }
        __syncthreads();
        for (int cc = 0; cc < 8; ++cc){
            float p[4][3];
            #pragma unroll
            for (int r=0;r<4;++r)
                #pragma unroll
                for (int q=0;q<3;++q)
                    p[r][q] = s_in[cc][(lyb+r)*18 + lx+q];
            #pragma unroll
            for (int co = 0; co < COUTB; ++co){
                const float* w9 = wB + ((size_t)co*CIN + (c0+cc))*9;
                #pragma unroll
                for (int ky=0;ky<3;++ky)
                    #pragma unroll
                    for (int kx=0;kx<3;++kx){
                        float wv = w9[ky*3+kx];
                        acc[0][co] += p[ky][kx]*wv;
                        acc[1][co] += p[ky+1][kx]*wv;
                    }
            }
        }
    }
    #pragma unroll
    for (int j=0;j<2;++j){
        int oy = y0 + lyb + j, ox = x0 + lx;
        int p = oy*OW + ox;
        bool m = mask[(size_t)n*OH*OW + p] != 0;
        #pragma unroll
        for (int co=0; co<COUTB; ++co){
            float a = acc[j][co], o;
            if      (EPI == 0) o = m ? fmaxf(a,0.f)*BNS : 0.f;
            else if (EPI == 1){ float s = a*BNS; o = m ? (s>0.f ? s : 0.2f*s) : 0.f; }
            else { int cg = cog*COUTB+co;
                   o = m ? fmaxf(a,0.f)*BNS + res32[((size_t)(n>>2)*COUT_TOT + cg)*(size_t)(OH*OW) + p] : 0.f; }
            out[((size_t)n*COUT_TOT + cog*COUTB + co)*(size_t)(OH*OW) + p] = f2b(o);
        }
    }
}

// ---------------- v2 engine: stride-2 conv, tile 16x16, 1 px/thread ----------------
template<int CIN, int COUTB, int COUT_TOT>
__global__ __launch_bounds__(256) void conv_s2(const bf16* __restrict__ in, int IH, int IW,
                                               const float* __restrict__ w,
                                               const u8* __restrict__ mask,
                                               bf16* __restrict__ out, int OH, int OW, int tilesX)
{
    int n = blockIdx.z, cog = blockIdx.y;
    int tY = blockIdx.x / tilesX, tX = blockIdx.x % tilesX;
    int y0 = tY*16, x0 = tX*16;
    const float* wB = w + (size_t)cog*COUTB*CIN*9;

    __shared__ float s_in[8][33*34];

    int tid = threadIdx.x;
    int lx = tid & 15, ly = tid >> 4;

    float acc[COUTB];
    #pragma unroll
    for (int c=0;c<COUTB;++c) acc[c]=0.f;

    const bf16* inN = in + (size_t)n*CIN*IH*IW;
    for (int c0 = 0; c0 < CIN; c0 += 8){
        __syncthreads();
        for (int i = tid; i < 8*1089; i += 256){
            int cc = i / 1089; int r = i % 1089;
            int ry = r / 33, rx = r % 33;
            int gy = 2*y0-1+ry, gx = 2*x0-1+rx;
            float v = 0.f;
            if ((unsigned)gy < (unsigned)IH && (unsigned)gx < (unsigned)IW)
                v = b2f(inN[(size_t)(c0+cc)*IH*IW + (size_t)gy*IW + gx]);
            s_in[cc][ry*34 + rx] = v;
        }
        __syncthreads();
        for (int cc = 0; cc < 8; ++cc){
            float p[3][3];
            #pragma unroll
            for (int r=0;r<3;++r)
                #pragma unroll
                for (int q=0;q<3;++q)
                    p[r][q] = s_in[cc][(2*ly+r)*34 + 2*lx+q];
            #pragma unroll
            for (int co = 0; co < COUTB; ++co){
                const float* w9 = wB + ((size_t)co*CIN + (c0+cc))*9;
                #pragma unroll
                for (int k=0;k<9;++k)
                    acc[co] += p[k/3][k%3]*w9[k];
            }
        }
    }
    int oy = y0+ly, ox = x0+lx;
    int p = oy*OW + ox;
    bool m = mask[(size_t)n*OH*OW + p] != 0;
    #pragma unroll
    for (int co=0; co<COUTB; ++co){
        float o = m ? fmaxf(acc[co],0.f)*BNS : 0.f;
        out[((size_t)n*COUT_TOT + cog*COUTB + co)*(size_t)(OH*OW) + p] = f2b(o);
    }
}

// ---------------- fused conv1a+conv1b -> fea1 (tile 16x16, f tile fp32 in LDS) --------
__global__ __launch_bounds__(256) void conv1ab(const float* __restrict__ image,
                                               const float* __restrict__ masks,
                                               const u8*  __restrict__ M1,
                                               const float* __restrict__ w1a,  // [32][4][9]
                                               const float* __restrict__ w1b,  // [32][32][9]
                                               bf16* __restrict__ fea1)
{
    const int H = 384; const int HW = H*H;
    int tY = blockIdx.x / 24, tX = blockIdx.x % 24, n = blockIdx.z;
    int y0 = tY*16, x0 = tX*16;

    __shared__ float s_inp[4][20*20];
    __shared__ u8    s_m[20*20];
    __shared__ float s_f[32*324];

    int tid = threadIdx.x;
    for (int i = tid; i < 400; i += 256){
        int ly = i/20, lxx = i%20;
        int gy = y0-2+ly, gx = x0-2+lxx;
        bool inb = ((unsigned)gy < 384u) && ((unsigned)gx < 384u);
        u8 mv = inb ? M1[(size_t)n*HW + gy*H + gx] : 0;
        s_m[i] = mv;
        float mm = (float)mv;
        int p = gy*H + gx;
        #pragma unroll
        for (int c = 0; c < 4; ++c){
            float v = 0.f;
            if (inb) v = (c < 3) ? image[((size_t)(n>>2)*3 + c)*HW + p]
                                 : masks[(size_t)n*HW + p];
            s_inp[c][i] = v*mm;
        }
    }
    __syncthreads();

    // f: 18x18 x 32ch, fp32
    for (int ch = 0; ch < 32; ++ch){
        const float* wA = w1a + ch*36;
        for (int i = tid; i < 324; i += 256){
            int fy = i/18, fx = i%18;
            float a = 0.f;
            #pragma unroll
            for (int ci=0; ci<4; ++ci)
                #pragma unroll
                for (int k=0;k<9;++k)
                    a += s_inp[ci][(fy + k/3)*20 + fx + k%3] * wA[ci*9+k];
            float o = s_m[(fy+1)*20 + fx+1] ? fmaxf(a,0.f)*BNS : 0.f;
            s_f[ch*324 + i] = o;
        }
    }
    __syncthreads();

    int ty = tid>>4, tx = tid&15;
    float acc[32];
    #pragma unroll
    for (int c=0;c<32;++c) acc[c]=0.f;
    for (int ci=0; ci<32; ++ci){
        float p[3][3];
        #pragma unroll
        for (int ky=0;ky<3;++ky)
            #pragma unroll
            for (int kx=0;kx<3;++kx)
                p[ky][kx] = s_f[ci*324 + (ty+ky)*18 + tx+kx];
        #pragma unroll
        for (int co=0; co<32; ++co){
            const float* w9 = w1b + ((size_t)co*32+ci)*9;
            #pragma unroll
            for (int k=0;k<9;++k)
                acc[co] += p[k/3][k%3]*w9[k];
        }
    }
    int gy = y0+ty, gx = x0+tx;
    bool m = s_m[(ty+2)*20 + tx+2] != 0;
    #pragma unroll
    for (int co=0; co<32; ++co){
        float o = m ? fmaxf(acc[co],0.f)*BNS : 0.f;
        fea1[((size_t)n*32 + co)*HW + gy*H + gx] = f2b(o);
    }
}

// ------- inner dot for inverse-conv: sum over CJ input channels at one tap -------
template<int CJ>
__device__ __forceinline__ float inv_dot(const float* __restrict__ s_x,  // [CJ][100]
                                         const float* __restrict__ wc,   // w + c*CJ*9
                                         int liy, int lix, int wk)
{
    float s = 0.f;
    #pragma unroll 8
    for (int cj = 0; cj < CJ; ++cj)
        s += s_x[cj*100 + liy*10 + lix] * wc[cj*9 + wk];
    return s;
}

// -------- fused inverse-conv (CJ->CJ2) + leaky + subm conv (CJ2->32) + residual ------
// tile 16x16 at output resolution OH(=2*IHin). ul double-buffered per channel.
// out = m ? conv(ul, w_sub) + res(bf16) : 0
template<int CJ>   // input channels of inverse conv == its output channels
__global__ __launch_bounds__(256) void inv_sub_fused(const bf16* __restrict__ xin,  // [CJ][IHin^2] per n (or full batch w/ blockIdx.z)
                                                     const bf16* __restrict__ resi, // [32][OH^2]
                                                     const u8*  __restrict__ Mo,    // [OH^2]
                                                     const float* __restrict__ w_inv, // [CJ][CJ][9]
                                                     const float* __restrict__ w_sub, // [32][CJ][9]
                                                     bf16* __restrict__ uout,       // [32][OH^2]
                                                     int IHin, int OH, int tilesX, int nZ)
{
    int n = nZ < 0 ? blockIdx.z : nZ;
    int tY = blockIdx.x / tilesX, tX = blockIdx.x % tilesX;
    int y0 = tY*16, x0 = tX*16;
    int uy0 = (y0>>1) - 1, ux0 = (x0>>1) - 1;
    const int OHW = OH*OH, IHW = IHin*IHin;

    __shared__ float s_x[CJ*100];
    __shared__ float s_ul[2][324];
    __shared__ u8    s_m[324];

    int tid = threadIdx.x;
    const bf16* xN = xin + (size_t)n*CJ*IHW;
    for (int i = tid; i < CJ*100; i += 256){
        int c = i/100, r = i%100; int ly = r/10, lxx = r%10;
        int gy = uy0+ly, gx = ux0+lxx;
        float v = 0.f;
        if ((unsigned)gy < (unsigned)IHin && (unsigned)gx < (unsigned)IHin)
            v = b2f(xN[(size_t)c*IHW + gy*IHin + gx]);
        s_x[c*100 + r] = v;
    }
    for (int i = tid; i < 324; i += 256){
        int ry = i/18, rx = i%18;
        int gy = y0-1+ry, gx = x0-1+rx;
        s_m[i] = ((unsigned)gy < (unsigned)OH && (unsigned)gx < (unsigned)OH) ? Mo[(size_t)n*OHW + gy*OH + gx] : 0;
    }
    __syncthreads();

    // compute ul channel c into buffer buf
    auto compute_ul = [&](int c, int buf){
        const float* wc = w_inv + (size_t)c*CJ*9;
        #pragma unroll
        for (int it = 0; it < 2; ++it){
            int idx = it*256 + tid;
            int cls = idx >> 7, j = idx & 127;
            if (j < 81){
                int jr = j/9, jc = j%9;
                int Y, X, ry, rx;
                if (cls & 2){ Y = y0 + 2*jr;   ry = 2*jr+1; }   // Y even
                else        { Y = y0-1 + 2*jr; ry = 2*jr;   }   // Y odd
                if (cls & 1){ X = x0 + 2*jc;   rx = 2*jc+1; }
                else        { X = x0-1 + 2*jc; rx = 2*jc;   }
                float o = 0.f;
                if (s_m[ry*18+rx]){
                    float a = 0.f;
                    if (!(cls & 2)){ // Y odd: ky in {0,2}
                        int iy0 = (Y-1)>>1, iy2 = (Y+1)>>1;
                        bool v0 = (unsigned)iy0 < (unsigned)IHin, v2 = (unsigned)iy2 < (unsigned)IHin;
                        if (!(cls & 1)){ // X odd: kx {0,2}
                            int ix0 = (X-1)>>1, ix2 = (X+1)>>1;
                            bool u0 = (unsigned)ix0 < (unsigned)IHin, u2 = (unsigned)ix2 < (unsigned)IHin;
                            if (v0&&u0) a += inv_dot<CJ>(s_x, wc, iy0-uy0, ix0-ux0, 2*3+2);
                            if (v0&&u2) a += inv_dot<CJ>(s_x, wc, iy0-uy0, ix2-ux0, 2*3+0);
                            if (v2&&u0) a += inv_dot<CJ>(s_x, wc, iy2-uy0, ix0-ux0, 0*3+2);
                            if (v2&&u2) a += inv_dot<CJ>(s_x, wc, iy2-uy0, ix2-ux0, 0*3+0);
                        } else {         // X even: kx=1
                            int ix = X>>1; bool u = (unsigned)ix < (unsigned)IHin;
                            if (v0&&u) a += inv_dot<CJ>(s_x, wc, iy0-uy0, ix-ux0, 2*3+1);
                            if (v2&&u) a += inv_dot<CJ>(s_x, wc, iy2-uy0, ix-ux0, 0*3+1);
                        }
                    } else {            // Y even: ky=1
                        int iy = Y>>1; bool v = (unsigned)iy < (unsigned)IHin;
                        if (!(cls & 1)){
                            int ix0 = (X-1)>>1, ix2 = (X+1)>>1;
                            bool u0 = (unsigned)ix0 < (unsigned)IHin, u2 = (unsigned)ix2 < (unsigned)IHin;
                            if (v&&u0) a += inv_dot<CJ>(s_x, wc, iy-uy0, ix0-ux0, 1*3+2);
                            if (v&&u2) a += inv_dot<CJ>(s_x, wc, iy-uy0, ix2-ux0, 1*3+0);
                        } else {
                            int ix = X>>1; bool u = (unsigned)ix < (unsigned)IHin;
                            if (v&&u) a += inv_dot<CJ>(s_x, wc, iy-uy0, ix-ux0, 1*3+1);
                        }
                    }
                    float sc = a * BNS;
                    o = sc > 0.f ? sc : 0.2f*sc;
                }
                s_ul[buf][ry*18+rx] = o;
            }
        }
    };

    compute_ul(0, 0);
    __syncthreads();

    int ty = tid>>4, tx = tid&15;
    float acc[32];
    #pragma unroll
    for (int c=0;c<32;++c) acc[c]=0.f;

    for (int c = 0; c < CJ; ++c){
        // consume ul[c]
        float p[3][3];
        #pragma unroll
        for (int ky=0;ky<3;++ky)
            #pragma unroll
            for (int kx=0;kx<3;++kx)
                p[ky][kx] = s_ul[c&1][(ty+ky)*18 + tx+kx];
        #pragma unroll
        for (int co=0; co<32; ++co){
            const float* w9 = w_sub + ((size_t)co*CJ + c)*9;
            #pragma unroll
            for (int k=0;k<9;++k)
                acc[co] += p[k/3][k%3]*w9[k];
        }
        if (c+1 < CJ) compute_ul(c+1, (c+1)&1);
        __syncthreads();
    }

    int gy = y0+ty, gx = x0+tx;
    int p = gy*OH + gx;
    bool m = s_m[(ty+1)*18 + tx+1] != 0;
    #pragma unroll
    for (int co=0; co<32; ++co){
        float o = m ? acc[co] + b2f(resi[((size_t)n*32 + co)*OHW + p]) : 0.f;
        uout[((size_t)n*32 + co)*OHW + p] = f2b(o);
    }
}

// ---------------- launch ----------------

extern "C" void kernel_launch(void* const* d_in, const int* in_sizes, int n_in,
                              void* d_out, int out_size, void* d_ws, size_t ws_size,
                              hipStream_t stream)
{
    const float* x      = (const float*)d_in[0];
    const float* image  = (const float*)d_in[1];
    const float* masks  = (const float*)d_in[2];
    const float* roi    = (const float*)d_in[3];
    const float* w1a    = (const float*)d_in[4];
    const float* w1b    = (const float*)d_in[5];
    const float* w2a    = (const float*)d_in[6];
    const float* w2b    = (const float*)d_in[7];
    const float* w4a    = (const float*)d_in[8];
    const float* w4b    = (const float*)d_in[9];
    const float* inv4_w = (const float*)d_in[10];
    const float* l4_sub = (const float*)d_in[11];
    const float* inv2_w = (const float*)d_in[12];
    const float* l5_sub = (const float*)d_in[13];
    const float* r4_w1  = (const float*)d_in[14];
    const float* r4_w2  = (const float*)d_in[15];
    const float* r4_b2  = (const float*)d_in[16];
    const float* r1_w1  = (const float*)d_in[17];
    const float* r1_w2  = (const float*)d_in[18];
    const float* r1_b2  = (const float*)d_in[19];
    float* out = (float*)d_out;

    const int N = 8;
    const int H1 = 384, HW1 = 384*384;
    const int H2 = 192, HW2 = 192*192;
    const int H4 = 96,  HW4 = 96*96;

    char* wsp = (char*)d_ws;
    size_t off = 0;
    auto alloc = [&](size_t bytes) -> char* {
        char* p = wsp + off;
        off += (bytes + 255) & ~(size_t)255;
        return p;
    };
    bf16* FEA1 = (bf16*)alloc((size_t)N*32*HW1*2);  // 75.5 MB
    u8*   M1   = (u8*)alloc((size_t)N*HW1);
    u8*   M2   = (u8*)alloc((size_t)N*HW2);
    u8*   M4   = (u8*)alloc((size_t)N*HW4);
    bf16* FEA2 = (bf16*)alloc((size_t)N*32*HW2*2);  // later: V (per-n)
    bf16* XS   = (bf16*)alloc((size_t)N*64*HW4*2);
    bf16* GU   = (bf16*)alloc((size_t)N*32*HW2*2);  // g, then u
    bf16* HT   = (bf16*)alloc((size_t)N*64*HW4*2);  // h, then t_leaky, then T1 (per-n)
    bf16* V    = FEA2;                              // aliases (fea2 dead by then)
    bf16* T1   = HT;
    (void)ws_size; (void)in_sizes; (void)n_in; (void)out_size;

    dim3 blk(256);

    // masks
    k_mask1<<<dim3((N*HW1 + 255)/256), blk, 0, stream>>>(roi, M1, N*HW1);
    k_down<<<dim3((HW2 + 255)/256, N), blk, 0, stream>>>(M1, M2, H1, H1, H2, H2);
    k_down<<<dim3((HW4 + 255)/256, N), blk, 0, stream>>>(M2, M4, H2, H2, H4, H4);

    // fused conv1a+conv1b -> fea1
    conv1ab<<<dim3(576, 1, N), blk, 0, stream>>>(image, masks, M1, w1a, w1b, FEA1);

    // low_os2
    conv_s2<32,32,32><<<dim3(144, 1, N), blk, 0, stream>>>(FEA1, H1, H1, w2a, M2, GU, H2, H2, 12);
    conv_s1<32,32,32,0><<<dim3(72, 1, N), blk, 0, stream>>>(GU, H2, H2, w2b, M2, nullptr, FEA2, H2, H2, 12);
    // low_os4
    conv_s2<32,32,64><<<dim3(36, 2, N), blk, 0, stream>>>(FEA2, H2, H2, w4a, M4, HT, H4, H4, 6);
    conv_s1<64,32,64,3><<<dim3(18, 2, N), blk, 0, stream>>>(HT, H4, H4, w4b, M4, x, XS, H4, H4, 6);

    // refine_OS4
    conv_s1<64,32,32,1><<<dim3(18, 1, N), blk, 0, stream>>>(XS, H4, H4, r4_w1, M4, nullptr, HT, H4, H4, 6);
    conv3x3_k<32,1,1,4,float><<<dim3(36, 1, N), blk, 0, stream>>>(HT, H4, H4, r4_w2, r4_b2, M4, nullptr, out, H4, H4);

    // layer4: inv4(64->64)+leaky + l4_sub(64->32) + fea2 -> u (into GU)
    inv_sub_fused<64><<<dim3(144, 1, N), blk, 0, stream>>>(XS, FEA2, M2, inv4_w, l4_sub, GU, H4, H2, 12, -1);

    // back end per sample: layer5 fused -> V; refine_OS1
    for (int n = 0; n < N; ++n){
        inv_sub_fused<32><<<dim3(576, 1, 1), blk, 0, stream>>>(GU + (size_t)n*32*HW2, FEA1 + (size_t)n*32*HW1,
                                                               M1 + (size_t)n*HW1, inv2_w, l5_sub,
                                                               V, H2, H1, 24, 0);
        conv_s1<32,32,32,1><<<dim3(288, 1, 1), blk, 0, stream>>>(V, H1, H1, r1_w1, M1 + (size_t)n*HW1,
                                                                 nullptr, T1, H1, H1, 24);
        conv3x3_k<32,1,1,4,float><<<dim3(576, 1, 1), blk, 0, stream>>>(T1, H1, H1, r1_w2, r1_b2,
                                                                       M1 + (size_t)n*HW1, nullptr,
                                                                       out + (size_t)N*HW4 + (size_t)n*HW1, H1, H1);
    }
}

// Round 5
// 7263.902 us; speedup vs baseline: 3.0259x; 1.0377x over previous
//
#include <hip/hip_runtime.h>
#include <hip/hip_bf16.h>

using bf16 = __hip_bfloat16;
typedef unsigned char u8;

#define BNS 0.9999950000374997f   // 1/sqrt(1+1e-5)

__device__ __forceinline__ float b2f(bf16 v){ return __bfloat162float(v); }
__device__ __forceinline__ bf16 f2b(float v){ return __float2bfloat16(v); }

// ---------------- mask kernels ----------------

__global__ __launch_bounds__(256) void k_mask1(const float* __restrict__ roi, u8* __restrict__ m1, int total){
    int i = blockIdx.x*256 + threadIdx.x;
    if (i < total) m1[i] = (roi[i] > 0.8f) ? 1 : 0;
}

__global__ __launch_bounds__(256) void k_down(const u8* __restrict__ mi, u8* __restrict__ mo,
                                              int IH, int IW, int OH, int OW){
    int p = blockIdx.x*256 + threadIdx.x;
    int n = blockIdx.y;
    if (p >= OH*OW) return;
    int oy = p / OW, ox = p - oy*OW;
    const u8* src = mi + (size_t)n*IH*IW;
    int v = 0;
    #pragma unroll
    for (int ky=0; ky<3; ky++){
        int iy = 2*oy + ky - 1;
        if ((unsigned)iy >= (unsigned)IH) continue;
        #pragma unroll
        for (int kx=0; kx<3; kx++){
            int ix = 2*ox + kx - 1;
            if ((unsigned)ix < (unsigned)IW) v |= src[iy*IW + ix];
        }
    }
    mo[(size_t)n*OH*OW + p] = (u8)v;
}

// ---------------- COUT=1 head (refine_OS4 second conv) ----------------
template<int CIN>
__global__ __launch_bounds__(256) void conv3x3_head(const bf16* __restrict__ in, int IH, int IW,
                                                    const float* __restrict__ w,
                                                    const float* __restrict__ wb,
                                                    const u8*   __restrict__ mask,
                                                    float* __restrict__ out)
{
    __shared__ float ws[CIN*9];
    int n = blockIdx.z;
    for (int i = threadIdx.x; i < CIN*9; i += blockDim.x) ws[i] = w[i];
    __syncthreads();

    int p = blockIdx.x*blockDim.x + threadIdx.x;
    if (p >= IH*IW) return;
    int oy = p / IW, ox = p - oy*IW;

    float acc = 0.f;
    const bf16* ibase = in + (size_t)n*CIN*IH*IW;
    for (int c = 0; c < CIN; ++c) {
        const bf16* ic = ibase + (size_t)c*IH*IW;
        const float* wc = ws + c*9;
        #pragma unroll
        for (int ky = 0; ky < 3; ++ky) {
            int iy = oy-1+ky;
            if ((unsigned)iy >= (unsigned)IH) continue;
            const bf16* irow = ic + (size_t)iy*IW;
            #pragma unroll
            for (int kx = 0; kx < 3; ++kx) {
                int ix = ox-1+kx;
                if ((unsigned)ix < (unsigned)IW)
                    acc += b2f(irow[ix]) * wc[ky*3 + kx];
            }
        }
    }
    bool m = mask[(size_t)n*IH*IW + p] != 0;
    out[(size_t)n*IH*IW + p] = m ? acc + wb[0] : -99.f;
}

// ---------------- v2 engine: stride-1 conv, tile 32x16, 2 px/thread ----------------
// EPI: 0 relu*BNS*m | 1 m?leaky(acc*BNS) | 3 m?relu*BNS + res32[(n>>2),cog] : 0
template<int CIN, int COUTB, int COUT_TOT, int EPI>
__global__ __launch_bounds__(256) void conv_s1(const bf16* __restrict__ in, int IH, int IW,
                                               const float* __restrict__ w,
                                               const u8* __restrict__ mask,
                                               const float* __restrict__ res32,
                                               bf16* __restrict__ out, int OH, int OW, int tilesX)
{
    const int TH=32, TW=16;
    int n = blockIdx.z, cog = blockIdx.y;
    int tY = blockIdx.x / tilesX, tX = blockIdx.x % tilesX;
    int y0 = tY*TH, x0 = tX*TW;
    const float* wB = w + (size_t)cog*COUTB*CIN*9;

    __shared__ float s_in[8][34*18];

    int tid = threadIdx.x;
    int lx = tid & 15;
    int lyb = (tid >> 4) * 2;

    float acc[2][COUTB];
    #pragma unroll
    for (int j=0;j<2;++j)
        #pragma unroll
        for (int c=0;c<COUTB;++c) acc[j][c]=0.f;

    const bf16* inN = in + (size_t)n*CIN*IH*IW;
    for (int c0 = 0; c0 < CIN; c0 += 8){
        __syncthreads();
        for (int i = tid; i < 8*612; i += 256){
            int cc = i / 612; int r = i % 612;
            int ly = r / 18, lxx = r % 18;
            int gy = y0-1+ly, gx = x0-1+lxx;
            float v = 0.f;
            if ((unsigned)gy < (unsigned)IH && (unsigned)gx < (unsigned)IW)
                v = b2f(inN[(size_t)(c0+cc)*IH*IW + (size_t)gy*IW + gx]);
            s_in[cc][r] = v;
        }
        __syncthreads();
        for (int cc = 0; cc < 8; ++cc){
            float p[4][3];
            #pragma unroll
            for (int r=0;r<4;++r)
                #pragma unroll
                for (int q=0;q<3;++q)
                    p[r][q] = s_in[cc][(lyb+r)*18 + lx+q];
            #pragma unroll
            for (int co = 0; co < COUTB; ++co){
                const float* w9 = wB + ((size_t)co*CIN + (c0+cc))*9;
                #pragma unroll
                for (int ky=0;ky<3;++ky)
                    #pragma unroll
                    for (int kx=0;kx<3;++kx){
                        float wv = w9[ky*3+kx];
                        acc[0][co] += p[ky][kx]*wv;
                        acc[1][co] += p[ky+1][kx]*wv;
                    }
            }
        }
    }
    #pragma unroll
    for (int j=0;j<2;++j){
        int oy = y0 + lyb + j, ox = x0 + lx;
        int p = oy*OW + ox;
        bool m = mask[(size_t)n*OH*OW + p] != 0;
        #pragma unroll
        for (int co=0; co<COUTB; ++co){
            float a = acc[j][co], o;
            if      (EPI == 0) o = m ? fmaxf(a,0.f)*BNS : 0.f;
            else if (EPI == 1){ float s = a*BNS; o = m ? (s>0.f ? s : 0.2f*s) : 0.f; }
            else { int cg = cog*COUTB+co;
                   o = m ? fmaxf(a,0.f)*BNS + res32[((size_t)(n>>2)*COUT_TOT + cg)*(size_t)(OH*OW) + p] : 0.f; }
            out[((size_t)n*COUT_TOT + cog*COUTB + co)*(size_t)(OH*OW) + p] = f2b(o);
        }
    }
}

// ---------------- v2 engine: stride-2 conv, tile 16x16 ----------------
template<int CIN, int COUTB, int COUT_TOT>
__global__ __launch_bounds__(256) void conv_s2(const bf16* __restrict__ in, int IH, int IW,
                                               const float* __restrict__ w,
                                               const u8* __restrict__ mask,
                                               bf16* __restrict__ out, int OH, int OW, int tilesX)
{
    int n = blockIdx.z, cog = blockIdx.y;
    int tY = blockIdx.x / tilesX, tX = blockIdx.x % tilesX;
    int y0 = tY*16, x0 = tX*16;
    const float* wB = w + (size_t)cog*COUTB*CIN*9;

    __shared__ float s_in[8][33*34];

    int tid = threadIdx.x;
    int lx = tid & 15, ly = tid >> 4;

    float acc[COUTB];
    #pragma unroll
    for (int c=0;c<COUTB;++c) acc[c]=0.f;

    const bf16* inN = in + (size_t)n*CIN*IH*IW;
    for (int c0 = 0; c0 < CIN; c0 += 8){
        __syncthreads();
        for (int i = tid; i < 8*1089; i += 256){
            int cc = i / 1089; int r = i % 1089;
            int ry = r / 33, rx = r % 33;
            int gy = 2*y0-1+ry, gx = 2*x0-1+rx;
            float v = 0.f;
            if ((unsigned)gy < (unsigned)IH && (unsigned)gx < (unsigned)IW)
                v = b2f(inN[(size_t)(c0+cc)*IH*IW + (size_t)gy*IW + gx]);
            s_in[cc][ry*34 + rx] = v;
        }
        __syncthreads();
        for (int cc = 0; cc < 8; ++cc){
            float p[3][3];
            #pragma unroll
            for (int r=0;r<3;++r)
                #pragma unroll
                for (int q=0;q<3;++q)
                    p[r][q] = s_in[cc][(2*ly+r)*34 + 2*lx+q];
            #pragma unroll
            for (int co = 0; co < COUTB; ++co){
                const float* w9 = wB + ((size_t)co*CIN + (c0+cc))*9;
                #pragma unroll
                for (int k=0;k<9;++k)
                    acc[co] += p[k/3][k%3]*w9[k];
            }
        }
    }
    int oy = y0+ly, ox = x0+lx;
    int p = oy*OW + ox;
    bool m = mask[(size_t)n*OH*OW + p] != 0;
    #pragma unroll
    for (int co=0; co<COUTB; ++co){
        float o = m ? fmaxf(acc[co],0.f)*BNS : 0.f;
        out[((size_t)n*COUT_TOT + cog*COUTB + co)*(size_t)(OH*OW) + p] = f2b(o);
    }
}

// ---------------- fused conv1a+conv1b -> fea1 ----------------
__global__ __launch_bounds__(256) void conv1ab(const float* __restrict__ image,
                                               const float* __restrict__ masks,
                                               const u8*  __restrict__ M1,
                                               const float* __restrict__ w1a,
                                               const float* __restrict__ w1b,
                                               bf16* __restrict__ fea1)
{
    const int H = 384; const int HW = H*H;
    int tY = blockIdx.x / 24, tX = blockIdx.x % 24, n = blockIdx.z;
    int y0 = tY*16, x0 = tX*16;

    __shared__ float s_inp[4][20*20];
    __shared__ u8    s_m[20*20];
    __shared__ float s_f[32*324];

    int tid = threadIdx.x;
    for (int i = tid; i < 400; i += 256){
        int ly = i/20, lxx = i%20;
        int gy = y0-2+ly, gx = x0-2+lxx;
        bool inb = ((unsigned)gy < 384u) && ((unsigned)gx < 384u);
        u8 mv = inb ? M1[(size_t)n*HW + gy*H + gx] : 0;
        s_m[i] = mv;
        float mm = (float)mv;
        int p = gy*H + gx;
        #pragma unroll
        for (int c = 0; c < 4; ++c){
            float v = 0.f;
            if (inb) v = (c < 3) ? image[((size_t)(n>>2)*3 + c)*HW + p]
                                 : masks[(size_t)n*HW + p];
            s_inp[c][i] = v*mm;
        }
    }
    __syncthreads();

    for (int ch = 0; ch < 32; ++ch){
        const float* wA = w1a + ch*36;
        for (int i = tid; i < 324; i += 256){
            int fy = i/18, fx = i%18;
            float a = 0.f;
            #pragma unroll
            for (int ci=0; ci<4; ++ci)
                #pragma unroll
                for (int k=0;k<9;++k)
                    a += s_inp[ci][(fy + k/3)*20 + fx + k%3] * wA[ci*9+k];
            float o = s_m[(fy+1)*20 + fx+1] ? fmaxf(a,0.f)*BNS : 0.f;
            s_f[ch*324 + i] = o;
        }
    }
    __syncthreads();

    int ty = tid>>4, tx = tid&15;
    float acc[32];
    #pragma unroll
    for (int c=0;c<32;++c) acc[c]=0.f;
    for (int ci=0; ci<32; ++ci){
        float p[3][3];
        #pragma unroll
        for (int ky=0;ky<3;++ky)
            #pragma unroll
            for (int kx=0;kx<3;++kx)
                p[ky][kx] = s_f[ci*324 + (ty+ky)*18 + tx+kx];
        #pragma unroll
        for (int co=0; co<32; ++co){
            const float* w9 = w1b + ((size_t)co*32+ci)*9;
            #pragma unroll
            for (int k=0;k<9;++k)
                acc[co] += p[k/3][k%3]*w9[k];
        }
    }
    int gy = y0+ty, gx = x0+tx;
    bool m = s_m[(ty+2)*20 + tx+2] != 0;
    #pragma unroll
    for (int co=0; co<32; ++co){
        float o = m ? fmaxf(acc[co],0.f)*BNS : 0.f;
        fea1[((size_t)n*32 + co)*HW + gy*H + gx] = f2b(o);
    }
}

// ---------------- fused layer4: inv4(64->64)+leaky + l4_sub(64->32)+fea2 -> u --------
// 16x16 OS2 tile; parity-class per wave; scalar weight loads; 54.6 KB LDS.
__global__ __launch_bounds__(256) void fk_l4b(const bf16* __restrict__ xs,
                                              const bf16* __restrict__ fea2,
                                              const u8*  __restrict__ M2,
                                              const float* __restrict__ w_inv,  // [64][64][9]
                                              const float* __restrict__ w_sub,  // [32][64][9]
                                              bf16* __restrict__ u_out)
{
    const int H2 = 192, HW2 = H2*H2, H4 = 96, HW4 = H4*H4;
    int tY = blockIdx.x / 12, tX = blockIdx.x % 12, n = blockIdx.z;
    int y0 = tY*16, x0 = tX*16;
    int uy0 = (y0>>1) - 1, ux0 = (x0>>1) - 1;

    __shared__ bf16 s_xs[64*100];
    __shared__ bf16 s_ul[64*324];
    __shared__ u8   s_m[324];

    int tid = threadIdx.x;
    const bf16* xN = xs + (size_t)n*64*HW4;
    for (int i = tid; i < 64*100; i += 256){
        int c = i/100, r = i%100; int ly = r/10, lxx = r%10;
        int gy = uy0+ly, gx = ux0+lxx;
        bf16 v = f2b(0.f);
        if ((unsigned)gy < 96u && (unsigned)gx < 96u) v = xN[(size_t)c*HW4 + gy*H4 + gx];
        s_xs[i] = v;
    }
    for (int i = tid; i < 324; i += 256){
        int ry = i/18, rx = i%18; int gy = y0-1+ry, gx = x0-1+rx;
        s_m[i] = ((unsigned)gy < 192u && (unsigned)gx < 192u) ? M2[(size_t)n*HW2 + gy*H2 + gx] : 0;
    }
    __syncthreads();

    // stage A: ul 18x18 x64ch; wave w handles parity class w
    int wv = tid >> 6, lane = tid & 63;
    #pragma unroll
    for (int cls = 0; cls < 4; ++cls){
        if (wv != cls) continue;
        const int pY = cls >> 1, pX = cls & 1;
        for (int rep = 0; rep < 2; ++rep){
            int idx = rep*64 + lane;
            if (idx >= 81) continue;
            int jr = idx/9, jc = idx%9;
            int ry = 2*jr + pY, rx = 2*jc + pX;
            int sidx = ry*18 + rx;
            float acc[64];
            #pragma unroll
            for (int c=0;c<64;++c) acc[c]=0.f;
            if (s_m[sidx]){
                int gY = y0-1+ry, gX = x0-1+rx;
                auto tap = [&](int iy, int ix, int wk){
                    if ((unsigned)iy >= 96u || (unsigned)ix >= 96u) return;
                    const bf16* xp = s_xs + (iy-uy0)*10 + (ix-ux0);
                    for (int ci = 0; ci < 64; ++ci){
                        float xv = b2f(xp[ci*100]);
                        const float* wp = w_inv + ci*9 + wk;
                        #pragma unroll
                        for (int co = 0; co < 64; ++co)
                            acc[co] += xv * wp[co*576];
                    }
                };
                if (cls == 0){ int iA=(gY-1)>>1, iB=(gY+1)>>1, jA=(gX-1)>>1, jB=(gX+1)>>1;
                    tap(iA,jA,8); tap(iA,jB,6); tap(iB,jA,2); tap(iB,jB,0); }
                if (cls == 1){ int iA=(gY-1)>>1, iB=(gY+1)>>1, j=gX>>1;
                    tap(iA,j,7); tap(iB,j,1); }
                if (cls == 2){ int i2=gY>>1, jA=(gX-1)>>1, jB=(gX+1)>>1;
                    tap(i2,jA,5); tap(i2,jB,3); }
                if (cls == 3){ tap(gY>>1, gX>>1, 4); }
            }
            #pragma unroll
            for (int co=0; co<64; ++co){
                float sc = acc[co]*BNS;
                s_ul[co*324 + sidx] = f2b(sc > 0.f ? sc : 0.2f*sc);
            }
        }
    }
    __syncthreads();

    // stage B: u 16x16 x32ch
    int ty = tid>>4, tx = tid&15;
    u8 m = s_m[(ty+1)*18 + tx+1];
    float acc[32];
    #pragma unroll
    for (int c=0;c<32;++c) acc[c]=0.f;
    if (m){
        for (int ci = 0; ci < 64; ++ci){
            const bf16* vp = s_ul + ci*324 + ty*18 + tx;
            float p[9];
            #pragma unroll
            for (int k=0;k<9;++k) p[k] = b2f(vp[(k/3)*18 + (k%3)]);
            #pragma unroll
            for (int co=0; co<32; ++co){
                const float* w9 = w_sub + co*576 + ci*9;
                float s = 0.f;
                #pragma unroll
                for (int k=0;k<9;++k) s += p[k]*w9[k];
                acc[co] += s;
            }
        }
    }
    int gy = y0+ty, gx = x0+tx;
    int p = gy*H2 + gx;
    #pragma unroll
    for (int co=0; co<32; ++co){
        float o = 0.f;
        if (m) o = acc[co] + b2f(fea2[((size_t)n*32 + co)*HW2 + p]);
        u_out[((size_t)n*32 + co)*HW2 + p] = f2b(o);
    }
}

// ------- fully fused back end: inv2+leaky -> l5_sub+fea1 -> r1_w1+leaky -> r1_w2 -----
// 16x16 OS1 tile, 4 in-tile stages, LDS aliased (57 KB), 4 syncs.
__global__ __launch_bounds__(256) void fk_back2(const bf16* __restrict__ u,     // [8][32][192^2]
                                                const bf16* __restrict__ fea1,  // [8][32][384^2]
                                                const u8*  __restrict__ M1,
                                                const float* __restrict__ w_inv2, // [32][32][9]
                                                const float* __restrict__ w_l5,
                                                const float* __restrict__ w_r1a,
                                                const float* __restrict__ w_r1b,  // [1][32][9]
                                                const float* __restrict__ r1_b2,
                                                float* __restrict__ out1)
{
    const int H1 = 384, HW1 = H1*H1, H2 = 192, HW2 = H2*H2;
    int tY = blockIdx.x / 24, tX = blockIdx.x % 24, n = blockIdx.z;
    int y0 = tY*16, x0 = tX*16;
    int uy0 = (y0>>1) - 2, ux0 = (x0>>1) - 2;   // u tile 12x12

    __shared__ __align__(16) char smem[57064];
    bf16* s_u  = (bf16*)smem;                 // 32*144 el (9216 B) — stage A in
    bf16* s_v  = (bf16*)smem;                 // alias: 32*400 el (25600 B) — stage B out
    bf16* s_vl = (bf16*)(smem + 25600);       // 32*484 el (30976 B) — stage A out
    bf16* s_t1 = (bf16*)(smem + 25600);       // alias — stage C out (32*324 el)
    u8*   s_m  = (u8*)(smem + 25600 + 30976); // 484 B (22x22, origin y0-3,x0-3)

    int tid = threadIdx.x;
    const bf16* uN = u + (size_t)n*32*HW2;
    for (int i = tid; i < 32*144; i += 256){
        int c = i/144, r = i%144; int ly = r/12, lxx = r%12;
        int gy = uy0+ly, gx = ux0+lxx;
        bf16 v = f2b(0.f);
        if ((unsigned)gy < 192u && (unsigned)gx < 192u) v = uN[(size_t)c*HW2 + gy*H2 + gx];
        s_u[i] = v;
    }
    for (int i = tid; i < 484; i += 256){
        int ry = i/22, rx = i%22; int gy = y0-3+ry, gx = x0-3+rx;
        s_m[i] = ((unsigned)gy < 384u && (unsigned)gx < 384u) ? M1[(size_t)n*HW1 + gy*H1 + gx] : 0;
    }
    __syncthreads();

    // ---- stage A: vl 22x22 x32 (origin y0-3) — parity class per wave ----
    int wv = tid >> 6, lane = tid & 63;
    #pragma unroll
    for (int cls = 0; cls < 4; ++cls){
        if (wv != cls) continue;
        const int pY = cls >> 1, pX = cls & 1;
        for (int rep = 0; rep < 2; ++rep){
            int idx = rep*64 + lane;
            if (idx >= 121) continue;
            int jr = idx/11, jc = idx%11;
            int ry = 2*jr + pY, rx = 2*jc + pX;
            int sidx = ry*22 + rx;
            float acc[32];
            #pragma unroll
            for (int c=0;c<32;++c) acc[c]=0.f;
            if (s_m[sidx]){
                int gY = y0-3+ry, gX = x0-3+rx;
                auto tap = [&](int iy, int ix, int wk){
                    if ((unsigned)iy >= 192u || (unsigned)ix >= 192u) return;
                    const bf16* xp = s_u + (iy-uy0)*12 + (ix-ux0);
                    for (int ci = 0; ci < 32; ++ci){
                        float xv = b2f(xp[ci*144]);
                        const float* wp = w_inv2 + ci*9 + wk;
                        #pragma unroll
                        for (int co = 0; co < 32; ++co)
                            acc[co] += xv * wp[co*288];
                    }
                };
                if (cls == 0){ int iA=(gY-1)>>1, iB=(gY+1)>>1, jA=(gX-1)>>1, jB=(gX+1)>>1;
                    tap(iA,jA,8); tap(iA,jB,6); tap(iB,jA,2); tap(iB,jB,0); }
                if (cls == 1){ int iA=(gY-1)>>1, iB=(gY+1)>>1, j=gX>>1;
                    tap(iA,j,7); tap(iB,j,1); }
                if (cls == 2){ int i2=gY>>1, jA=(gX-1)>>1, jB=(gX+1)>>1;
                    tap(i2,jA,5); tap(i2,jB,3); }
                if (cls == 3){ tap(gY>>1, gX>>1, 4); }
            }
            #pragma unroll
            for (int co=0; co<32; ++co){
                float sc = acc[co]*BNS;
                s_vl[co*484 + sidx] = f2b(sc > 0.f ? sc : 0.2f*sc);
            }
        }
    }
    __syncthreads();

    // ---- stage B: v 20x20 x32 (origin y0-2) = conv(vl,l5)*m + fea1 ----
    for (int pass = 0; pass < 2; ++pass){
        int site = pass*256 + tid;
        if (site < 400){
            int vy = site/20, vx = site%20;
            u8 m = s_m[(vy+1)*22 + vx+1];
            float acc[32];
            #pragma unroll
            for (int c=0;c<32;++c) acc[c]=0.f;
            if (m){
                for (int ci = 0; ci < 32; ++ci){
                    const bf16* vp = s_vl + ci*484 + vy*22 + vx;
                    float p[9];
                    #pragma unroll
                    for (int k=0;k<9;++k) p[k] = b2f(vp[(k/3)*22 + (k%3)]);
                    #pragma unroll
                    for (int co=0; co<32; ++co){
                        const float* w9 = w_l5 + co*288 + ci*9;
                        float s = 0.f;
                        #pragma unroll
                        for (int k=0;k<9;++k) s += p[k]*w9[k];
                        acc[co] += s;
                    }
                }
            }
            int gY = y0-2+vy, gX = x0-2+vx;
            #pragma unroll
            for (int co=0; co<32; ++co){
                float o = 0.f;
                if (m) o = acc[co] + b2f(fea1[((size_t)n*32 + co)*HW1 + gY*H1 + gX]);
                s_v[co*400 + site] = f2b(o);
            }
        }
    }
    __syncthreads();

    // ---- stage C: t1 18x18 x32 (origin y0-1) = leaky(conv(v,r1a)*BNS*m) ----
    for (int pass = 0; pass < 2; ++pass){
        int site = pass*256 + tid;
        if (site < 324){
            int qy = site/18, qx = site%18;
            u8 m = s_m[(qy+2)*22 + qx+2];
            float acc[32];
            #pragma unroll
            for (int c=0;c<32;++c) acc[c]=0.f;
            if (m){
                for (int ci = 0; ci < 32; ++ci){
                    const bf16* vp = s_v + ci*400 + qy*20 + qx;
                    float p[9];
                    #pragma unroll
                    for (int k=0;k<9;++k) p[k] = b2f(vp[(k/3)*20 + (k%3)]);
                    #pragma unroll
                    for (int co=0; co<32; ++co){
                        const float* w9 = w_r1a + co*288 + ci*9;
                        float s = 0.f;
                        #pragma unroll
                        for (int k=0;k<9;++k) s += p[k]*w9[k];
                        acc[co] += s;
                    }
                }
            }
            #pragma unroll
            for (int co=0; co<32; ++co){
                float sc = acc[co]*BNS;
                s_t1[co*324 + site] = f2b(m ? (sc > 0.f ? sc : 0.2f*sc) : 0.f);
            }
        }
    }
    __syncthreads();

    // ---- stage D: out 16x16 = m ? conv(t1,r1b)+b : -99 ----
    int ty = tid>>4, tx = tid&15;
    u8 m = s_m[(ty+3)*22 + tx+3];
    float o = -99.f;
    if (m){
        float acc = 0.f;
        for (int ci = 0; ci < 32; ++ci){
            const bf16* vp = s_t1 + ci*324 + ty*18 + tx;
            const float* w9 = w_r1b + ci*9;
            #pragma unroll
            for (int k=0;k<9;++k)
                acc += b2f(vp[(k/3)*18 + (k%3)]) * w9[k];
        }
        o = acc + r1_b2[0];
    }
    out1[(size_t)n*HW1 + (y0+ty)*H1 + (x0+tx)] = o;
}

// ---------------- launch ----------------

extern "C" void kernel_launch(void* const* d_in, const int* in_sizes, int n_in,
                              void* d_out, int out_size, void* d_ws, size_t ws_size,
                              hipStream_t stream)
{
    const float* x      = (const float*)d_in[0];
    const float* image  = (const float*)d_in[1];
    const float* masks  = (const float*)d_in[2];
    const float* roi    = (const float*)d_in[3];
    const float* w1a    = (const float*)d_in[4];
    const float* w1b    = (const float*)d_in[5];
    const float* w2a    = (const float*)d_in[6];
    const float* w2b    = (const float*)d_in[7];
    const float* w4a    = (const float*)d_in[8];
    const float* w4b    = (const float*)d_in[9];
    const float* inv4_w = (const float*)d_in[10];
    const float* l4_sub = (const float*)d_in[11];
    const float* inv2_w = (const float*)d_in[12];
    const float* l5_sub = (const float*)d_in[13];
    const float* r4_w1  = (const float*)d_in[14];
    const float* r4_w2  = (const float*)d_in[15];
    const float* r4_b2  = (const float*)d_in[16];
    const float* r1_w1  = (const float*)d_in[17];
    const float* r1_w2  = (const float*)d_in[18];
    const float* r1_b2  = (const float*)d_in[19];
    float* out = (float*)d_out;

    const int N = 8;
    const int H1 = 384, HW1 = 384*384;
    const int H2 = 192, HW2 = 192*192;
    const int H4 = 96,  HW4 = 96*96;

    char* wsp = (char*)d_ws;
    size_t off = 0;
    auto alloc = [&](size_t bytes) -> char* {
        char* p = wsp + off;
        off += (bytes + 255) & ~(size_t)255;
        return p;
    };
    bf16* FEA1 = (bf16*)alloc((size_t)N*32*HW1*2);
    u8*   M1   = (u8*)alloc((size_t)N*HW1);
    u8*   M2   = (u8*)alloc((size_t)N*HW2);
    u8*   M4   = (u8*)alloc((size_t)N*HW4);
    bf16* FEA2 = (bf16*)alloc((size_t)N*32*HW2*2);
    bf16* XS   = (bf16*)alloc((size_t)N*64*HW4*2);
    bf16* GU   = (bf16*)alloc((size_t)N*32*HW2*2);  // g, then u
    bf16* HT   = (bf16*)alloc((size_t)N*64*HW4*2);  // h, then t_leaky
    (void)ws_size; (void)in_sizes; (void)n_in; (void)out_size;

    dim3 blk(256);

    // masks
    k_mask1<<<dim3((N*HW1 + 255)/256), blk, 0, stream>>>(roi, M1, N*HW1);
    k_down<<<dim3((HW2 + 255)/256, N), blk, 0, stream>>>(M1, M2, H1, H1, H2, H2);
    k_down<<<dim3((HW4 + 255)/256, N), blk, 0, stream>>>(M2, M4, H2, H2, H4, H4);

    // front
    conv1ab<<<dim3(576, 1, N), blk, 0, stream>>>(image, masks, M1, w1a, w1b, FEA1);
    conv_s2<32,32,32><<<dim3(144, 1, N), blk, 0, stream>>>(FEA1, H1, H1, w2a, M2, GU, H2, H2, 12);
    conv_s1<32,32,32,0><<<dim3(72, 1, N), blk, 0, stream>>>(GU, H2, H2, w2b, M2, nullptr, FEA2, H2, H2, 12);
    conv_s2<32,32,64><<<dim3(36, 2, N), blk, 0, stream>>>(FEA2, H2, H2, w4a, M4, HT, H4, H4, 6);
    conv_s1<64,32,64,3><<<dim3(18, 2, N), blk, 0, stream>>>(HT, H4, H4, w4b, M4, x, XS, H4, H4, 6);

    // refine_OS4
    conv_s1<64,32,32,1><<<dim3(18, 1, N), blk, 0, stream>>>(XS, H4, H4, r4_w1, M4, nullptr, HT, H4, H4, 6);
    conv3x3_head<32><<<dim3(36, 1, N), blk, 0, stream>>>(HT, H4, H4, r4_w2, r4_b2, M4, out);

    // layer4 fused -> u
    fk_l4b<<<dim3(144, 1, N), blk, 0, stream>>>(XS, FEA2, M2, inv4_w, l4_sub, GU);

    // fully fused back end -> out1
    fk_back2<<<dim3(576, 1, N), blk, 0, stream>>>(GU, FEA1, M1, inv2_w, l5_sub, r1_w1, r1_w2, r1_b2,
                                                  out + (size_t)N*HW4);
}

// Round 6
// 3302.476 us; speedup vs baseline: 6.6556x; 2.1995x over previous
//
#include <hip/hip_runtime.h>
#include <hip/hip_bf16.h>

using bf16 = __hip_bfloat16;
typedef unsigned char u8;
typedef short bf16x8 __attribute__((ext_vector_type(8)));
typedef short bf16x4 __attribute__((ext_vector_type(4)));
typedef float f32x4 __attribute__((ext_vector_type(4)));

#define BNS 0.9999950000374997f   // 1/sqrt(1+1e-5)
#define MFMA_B16 __builtin_amdgcn_mfma_f32_16x16x32_bf16

__device__ __forceinline__ float b2f(bf16 v){ return __bfloat162float(v); }
__device__ __forceinline__ bf16 f2b(float v){ return __float2bfloat16(v); }
__device__ __forceinline__ short f2bs(float v){ bf16 h = __float2bfloat16(v); return *reinterpret_cast<short*>(&h); }
__device__ __forceinline__ float s2f(short s){ union{unsigned u; float f;} x; x.u = ((unsigned)(unsigned short)s) << 16; return x.f; }

// load 8 bf16 from LDS at 8B-aligned address (two b64 reads)
__device__ __forceinline__ bf16x8 lds8(const short* p){
    bf16x4 lo = *(const bf16x4*)(p);
    bf16x4 hi = *(const bf16x4*)(p + 4);
    bf16x8 r = {lo[0],lo[1],lo[2],lo[3],hi[0],hi[1],hi[2],hi[3]};
    return r;
}

// ---------------- mask kernels ----------------

__global__ __launch_bounds__(256) void k_mask1(const float* __restrict__ roi, u8* __restrict__ m1, int total){
    int i = blockIdx.x*256 + threadIdx.x;
    if (i < total) m1[i] = (roi[i] > 0.8f) ? 1 : 0;
}

__global__ __launch_bounds__(256) void k_down(const u8* __restrict__ mi, u8* __restrict__ mo,
                                              int IH, int IW, int OH, int OW){
    int p = blockIdx.x*256 + threadIdx.x;
    int n = blockIdx.y;
    if (p >= OH*OW) return;
    int oy = p / OW, ox = p - oy*OW;
    const u8* src = mi + (size_t)n*IH*IW;
    int v = 0;
    #pragma unroll
    for (int ky=0; ky<3; ky++){
        int iy = 2*oy + ky - 1;
        if ((unsigned)iy >= (unsigned)IH) continue;
        #pragma unroll
        for (int kx=0; kx<3; kx++){
            int ix = 2*ox + kx - 1;
            if ((unsigned)ix < (unsigned)IW) v |= src[iy*IW + ix];
        }
    }
    mo[(size_t)n*OH*OW + p] = (u8)v;
}

// ---- weight prep: {w1b, inv2, l5, r1a} [32][32][9] fp32 -> bf16 [9][32co][32ci] ----
__global__ __launch_bounds__(256) void k_wprep(const float* __restrict__ w1b,
                                               const float* __restrict__ i2,
                                               const float* __restrict__ l5,
                                               const float* __restrict__ r1a,
                                               short* __restrict__ dst){
    int a = blockIdx.y;
    const float* src = (a==0)? w1b : (a==1)? i2 : (a==2)? l5 : r1a;
    int j = blockIdx.x*256 + threadIdx.x;
    if (j < 9216){
        int co = j/288, r = j%288, ci = r/9, k = r%9;
        dst[a*9216 + k*1024 + co*32 + ci] = f2bs(src[j]);
    }
}

// ---------------- COUT=1 head (refine_OS4 second conv) ----------------
template<int CIN>
__global__ __launch_bounds__(256) void conv3x3_head(const bf16* __restrict__ in, int IH, int IW,
                                                    const float* __restrict__ w,
                                                    const float* __restrict__ wb,
                                                    const u8*   __restrict__ mask,
                                                    float* __restrict__ out)
{
    __shared__ float ws[CIN*9];
    int n = blockIdx.z;
    for (int i = threadIdx.x; i < CIN*9; i += blockDim.x) ws[i] = w[i];
    __syncthreads();

    int p = blockIdx.x*blockDim.x + threadIdx.x;
    if (p >= IH*IW) return;
    int oy = p / IW, ox = p - oy*IW;

    float acc = 0.f;
    const bf16* ibase = in + (size_t)n*CIN*IH*IW;
    for (int c = 0; c < CIN; ++c) {
        const bf16* ic = ibase + (size_t)c*IH*IW;
        const float* wc = ws + c*9;
        #pragma unroll
        for (int ky = 0; ky < 3; ++ky) {
            int iy = oy-1+ky;
            if ((unsigned)iy >= (unsigned)IH) continue;
            const bf16* irow = ic + (size_t)iy*IW;
            #pragma unroll
            for (int kx = 0; kx < 3; ++kx) {
                int ix = ox-1+kx;
                if ((unsigned)ix < (unsigned)IW)
                    acc += b2f(irow[ix]) * wc[ky*3 + kx];
            }
        }
    }
    bool m = mask[(size_t)n*IH*IW + p] != 0;
    out[(size_t)n*IH*IW + p] = m ? acc + wb[0] : -99.f;
}

// ---------------- v2 engine: stride-1 conv, tile 32x16, 2 px/thread ----------------
template<int CIN, int COUTB, int COUT_TOT, int EPI>
__global__ __launch_bounds__(256) void conv_s1(const bf16* __restrict__ in, int IH, int IW,
                                               const float* __restrict__ w,
                                               const u8* __restrict__ mask,
                                               const float* __restrict__ res32,
                                               bf16* __restrict__ out, int OH, int OW, int tilesX)
{
    const int TH=32, TW=16;
    int n = blockIdx.z, cog = blockIdx.y;
    int tY = blockIdx.x / tilesX, tX = blockIdx.x % tilesX;
    int y0 = tY*TH, x0 = tX*TW;
    const float* wB = w + (size_t)cog*COUTB*CIN*9;

    __shared__ float s_in[8][34*18];

    int tid = threadIdx.x;
    int lx = tid & 15;
    int lyb = (tid >> 4) * 2;

    float acc[2][COUTB];
    #pragma unroll
    for (int j=0;j<2;++j)
        #pragma unroll
        for (int c=0;c<COUTB;++c) acc[j][c]=0.f;

    const bf16* inN = in + (size_t)n*CIN*IH*IW;
    for (int c0 = 0; c0 < CIN; c0 += 8){
        __syncthreads();
        for (int i = tid; i < 8*612; i += 256){
            int cc = i / 612; int r = i % 612;
            int ly = r / 18, lxx = r % 18;
            int gy = y0-1+ly, gx = x0-1+lxx;
            float v = 0.f;
            if ((unsigned)gy < (unsigned)IH && (unsigned)gx < (unsigned)IW)
                v = b2f(inN[(size_t)(c0+cc)*IH*IW + (size_t)gy*IW + gx]);
            s_in[cc][r] = v;
        }
        __syncthreads();
        for (int cc = 0; cc < 8; ++cc){
            float p[4][3];
            #pragma unroll
            for (int r=0;r<4;++r)
                #pragma unroll
                for (int q=0;q<3;++q)
                    p[r][q] = s_in[cc][(lyb+r)*18 + lx+q];
            #pragma unroll
            for (int co = 0; co < COUTB; ++co){
                const float* w9 = wB + ((size_t)co*CIN + (c0+cc))*9;
                #pragma unroll
                for (int ky=0;ky<3;++ky)
                    #pragma unroll
                    for (int kx=0;kx<3;++kx){
                        float wv = w9[ky*3+kx];
                        acc[0][co] += p[ky][kx]*wv;
                        acc[1][co] += p[ky+1][kx]*wv;
                    }
            }
        }
    }
    #pragma unroll
    for (int j=0;j<2;++j){
        int oy = y0 + lyb + j, ox = x0 + lx;
        int p = oy*OW + ox;
        bool m = mask[(size_t)n*OH*OW + p] != 0;
        #pragma unroll
        for (int co=0; co<COUTB; ++co){
            float a = acc[j][co], o;
            if      (EPI == 0) o = m ? fmaxf(a,0.f)*BNS : 0.f;
            else if (EPI == 1){ float s = a*BNS; o = m ? (s>0.f ? s : 0.2f*s) : 0.f; }
            else { int cg = cog*COUTB+co;
                   o = m ? fmaxf(a,0.f)*BNS + res32[((size_t)(n>>2)*COUT_TOT + cg)*(size_t)(OH*OW) + p] : 0.f; }
            out[((size_t)n*COUT_TOT + cog*COUTB + co)*(size_t)(OH*OW) + p] = f2b(o);
        }
    }
}

// ---------------- v2 engine: stride-2 conv, tile 16x16 ----------------
template<int CIN, int COUTB, int COUT_TOT>
__global__ __launch_bounds__(256) void conv_s2(const bf16* __restrict__ in, int IH, int IW,
                                               const float* __restrict__ w,
                                               const u8* __restrict__ mask,
                                               bf16* __restrict__ out, int OH, int OW, int tilesX)
{
    int n = blockIdx.z, cog = blockIdx.y;
    int tY = blockIdx.x / tilesX, tX = blockIdx.x % tilesX;
    int y0 = tY*16, x0 = tX*16;
    const float* wB = w + (size_t)cog*COUTB*CIN*9;

    __shared__ float s_in[8][33*34];

    int tid = threadIdx.x;
    int lx = tid & 15, ly = tid >> 4;

    float acc[COUTB];
    #pragma unroll
    for (int c=0;c<COUTB;++c) acc[c]=0.f;

    const bf16* inN = in + (size_t)n*CIN*IH*IW;
    for (int c0 = 0; c0 < CIN; c0 += 8){
        __syncthreads();
        for (int i = tid; i < 8*1089; i += 256){
            int cc = i / 1089; int r = i % 1089;
            int ry = r / 33, rx = r % 33;
            int gy = 2*y0-1+ry, gx = 2*x0-1+rx;
            float v = 0.f;
            if ((unsigned)gy < (unsigned)IH && (unsigned)gx < (unsigned)IW)
                v = b2f(inN[(size_t)(c0+cc)*IH*IW + (size_t)gy*IW + gx]);
            s_in[cc][ry*34 + rx] = v;
        }
        __syncthreads();
        for (int cc = 0; cc < 8; ++cc){
            float p[3][3];
            #pragma unroll
            for (int r=0;r<3;++r)
                #pragma unroll
                for (int q=0;q<3;++q)
                    p[r][q] = s_in[cc][(2*ly+r)*34 + 2*lx+q];
            #pragma unroll
            for (int co = 0; co < COUTB; ++co){
                const float* w9 = wB + ((size_t)co*CIN + (c0+cc))*9;
                #pragma unroll
                for (int k=0;k<9;++k)
                    acc[co] += p[k/3][k%3]*w9[k];
            }
        }
    }
    int oy = y0+ly, ox = x0+lx;
    int p = oy*OW + ox;
    bool m = mask[(size_t)n*OH*OW + p] != 0;
    #pragma unroll
    for (int co=0; co<COUTB; ++co){
        float o = m ? fmaxf(acc[co],0.f)*BNS : 0.f;
        out[((size_t)n*COUT_TOT + cog*COUTB + co)*(size_t)(OH*OW) + p] = f2b(o);
    }
}

// ---------------- conv1ab v2: scalar f-stage + MFMA stage-2 -> fea1 ----------------
__global__ __launch_bounds__(256) void conv1ab2(const float* __restrict__ image,
                                                const float* __restrict__ masks,
                                                const u8*  __restrict__ M1,
                                                const float* __restrict__ w1a,    // [32][4][9]
                                                const short* __restrict__ wT1b,   // [9][32co][32ci] bf16
                                                short* __restrict__ fea1)
{
    const int H = 384; const int HW = H*H;
    int tY = blockIdx.x / 24, tX = blockIdx.x % 24, n = blockIdx.z;
    int y0 = tY*16, x0 = tX*16;

    __shared__ float s_inp[4][400];
    __shared__ u8    s_m[400];
    __shared__ __align__(16) short s_f[324*36];

    int tid = threadIdx.x;
    for (int i = tid; i < 400; i += 256){
        int ly = i/20, lxx = i%20;
        int gy = y0-2+ly, gx = x0-2+lxx;
        bool inb = ((unsigned)gy < 384u) && ((unsigned)gx < 384u);
        u8 mv = inb ? M1[(size_t)n*HW + gy*H + gx] : 0;
        s_m[i] = mv;
        float mm = (float)mv;
        int p = gy*H + gx;
        #pragma unroll
        for (int c = 0; c < 4; ++c){
            float v = 0.f;
            if (inb) v = (c < 3) ? image[((size_t)(n>>2)*3 + c)*HW + p]
                                 : masks[(size_t)n*HW + p];
            s_inp[c][i] = v*mm;
        }
    }
    __syncthreads();

    // f: 18x18 sites x 32ch -> s_f[site*36 + ch]
    for (int ch = 0; ch < 32; ++ch){
        const float* wA = w1a + ch*36;
        for (int i = tid; i < 324; i += 256){
            int fy = i/18, fx = i%18;
            float a = 0.f;
            #pragma unroll
            for (int ci=0; ci<4; ++ci)
                #pragma unroll
                for (int k=0;k<9;++k)
                    a += s_inp[ci][(fy + k/3)*20 + fx + k%3] * wA[ci*9+k];
            float o = s_m[(fy+1)*20 + fx+1] ? fmaxf(a,0.f)*BNS : 0.f;
            s_f[i*36 + ch] = f2bs(o);
        }
    }
    __syncthreads();

    // stage 2: MFMA, D[co][site]; 16 site-tiles, 2 co-groups, 9 taps
    int wv = tid >> 6, lane = tid & 63;
    int nQ = lane >> 4, nn = lane & 15;
    for (int nt = wv; nt < 16; nt += 4){
        int s = nt*16 + nn;
        int ty = s >> 4, tx = s & 15;
        f32x4 acc0 = {0,0,0,0}, acc1 = {0,0,0,0};
        #pragma unroll
        for (int ky=0; ky<3; ++ky)
            #pragma unroll
            for (int kx=0; kx<3; ++kx){
                int k = ky*3+kx;
                bf16x8 bfr = lds8(s_f + ((ty+ky)*18 + tx+kx)*36 + nQ*8);
                bf16x8 a0 = *(const bf16x8*)(wT1b + k*1024 + nn*32 + nQ*8);
                bf16x8 a1 = *(const bf16x8*)(wT1b + k*1024 + (16+nn)*32 + nQ*8);
                acc0 = MFMA_B16(a0, bfr, acc0, 0,0,0);
                acc1 = MFMA_B16(a1, bfr, acc1, 0,0,0);
            }
        u8 m = s_m[(ty+2)*20 + tx+2];
        int gy = y0+ty, gx = x0+tx;
        short* fp = fea1 + (size_t)n*32*HW + gy*H + gx;
        #pragma unroll
        for (int g=0; g<2; ++g)
            #pragma unroll
            for (int e=0; e<4; ++e){
                int co = g*16 + nQ*4 + e;
                float a = g ? acc1[e] : acc0[e];
                float o = m ? fmaxf(a,0.f)*BNS : 0.f;
                fp[(size_t)co*HW] = f2bs(o);
            }
    }
}

// ---------------- fused layer4 (unchanged scalar path) ----------------
__global__ __launch_bounds__(256) void fk_l4b(const bf16* __restrict__ xs,
                                              const bf16* __restrict__ fea2,
                                              const u8*  __restrict__ M2,
                                              const float* __restrict__ w_inv,  // [64][64][9]
                                              const float* __restrict__ w_sub,  // [32][64][9]
                                              bf16* __restrict__ u_out)
{
    const int H2 = 192, HW2 = H2*H2, H4 = 96, HW4 = H4*H4;
    int tY = blockIdx.x / 12, tX = blockIdx.x % 12, n = blockIdx.z;
    int y0 = tY*16, x0 = tX*16;
    int uy0 = (y0>>1) - 1, ux0 = (x0>>1) - 1;

    __shared__ bf16 s_xs[64*100];
    __shared__ bf16 s_ul[64*324];
    __shared__ u8   s_m[324];

    int tid = threadIdx.x;
    const bf16* xN = xs + (size_t)n*64*HW4;
    for (int i = tid; i < 64*100; i += 256){
        int c = i/100, r = i%100; int ly = r/10, lxx = r%10;
        int gy = uy0+ly, gx = ux0+lxx;
        bf16 v = f2b(0.f);
        if ((unsigned)gy < 96u && (unsigned)gx < 96u) v = xN[(size_t)c*HW4 + gy*H4 + gx];
        s_xs[i] = v;
    }
    for (int i = tid; i < 324; i += 256){
        int ry = i/18, rx = i%18; int gy = y0-1+ry, gx = x0-1+rx;
        s_m[i] = ((unsigned)gy < 192u && (unsigned)gx < 192u) ? M2[(size_t)n*HW2 + gy*H2 + gx] : 0;
    }
    __syncthreads();

    int wv = tid >> 6, lane = tid & 63;
    #pragma unroll
    for (int cls = 0; cls < 4; ++cls){
        if (wv != cls) continue;
        const int pY = cls >> 1, pX = cls & 1;
        for (int rep = 0; rep < 2; ++rep){
            int idx = rep*64 + lane;
            if (idx >= 81) continue;
            int jr = idx/9, jc = idx%9;
            int ry = 2*jr + pY, rx = 2*jc + pX;
            int sidx = ry*18 + rx;
            float acc[64];
            #pragma unroll
            for (int c=0;c<64;++c) acc[c]=0.f;
            if (s_m[sidx]){
                int gY = y0-1+ry, gX = x0-1+rx;
                auto tap = [&](int iy, int ix, int wk){
                    if ((unsigned)iy >= 96u || (unsigned)ix >= 96u) return;
                    const bf16* xp = s_xs + (iy-uy0)*10 + (ix-ux0);
                    for (int ci = 0; ci < 64; ++ci){
                        float xv = b2f(xp[ci*100]);
                        const float* wp = w_inv + ci*9 + wk;
                        #pragma unroll
                        for (int co = 0; co < 64; ++co)
                            acc[co] += xv * wp[co*576];
                    }
                };
                if (cls == 0){ int iA=(gY-1)>>1, iB=(gY+1)>>1, jA=(gX-1)>>1, jB=(gX+1)>>1;
                    tap(iA,jA,8); tap(iA,jB,6); tap(iB,jA,2); tap(iB,jB,0); }
                if (cls == 1){ int iA=(gY-1)>>1, iB=(gY+1)>>1, j=gX>>1;
                    tap(iA,j,7); tap(iB,j,1); }
                if (cls == 2){ int i2=gY>>1, jA=(gX-1)>>1, jB=(gX+1)>>1;
                    tap(i2,jA,5); tap(i2,jB,3); }
                if (cls == 3){ tap(gY>>1, gX>>1, 4); }
            }
            #pragma unroll
            for (int co=0; co<64; ++co){
                float sc = acc[co]*BNS;
                s_ul[co*324 + sidx] = f2b(sc > 0.f ? sc : 0.2f*sc);
            }
        }
    }
    __syncthreads();

    int ty = tid>>4, tx = tid&15;
    u8 m = s_m[(ty+1)*18 + tx+1];
    float acc[32];
    #pragma unroll
    for (int c=0;c<32;++c) acc[c]=0.f;
    if (m){
        for (int ci = 0; ci < 64; ++ci){
            const bf16* vp = s_ul + ci*324 + ty*18 + tx;
            float p[9];
            #pragma unroll
            for (int k=0;k<9;++k) p[k] = b2f(vp[(k/3)*18 + (k%3)]);
            #pragma unroll
            for (int co=0; co<32; ++co){
                const float* w9 = w_sub + co*576 + ci*9;
                float s = 0.f;
                #pragma unroll
                for (int k=0;k<9;++k) s += p[k]*w9[k];
                acc[co] += s;
            }
        }
    }
    int gy = y0+ty, gx = x0+tx;
    int p = gy*H2 + gx;
    #pragma unroll
    for (int co=0; co<32; ++co){
        float o = 0.f;
        if (m) o = acc[co] + b2f(fea2[((size_t)n*32 + co)*HW2 + p]);
        u_out[((size_t)n*32 + co)*HW2 + p] = f2b(o);
    }
}

// ---------------- MFMA back end: inv2 -> l5+fea1 -> r1a -> r1b ----------------
__global__ __launch_bounds__(256) void fk_back3(const short* __restrict__ u,     // [8][32][HW2] bf16
                                                const short* __restrict__ fea1,  // [8][32][HW1] bf16
                                                const u8*  __restrict__ M1,
                                                const short* __restrict__ wTi2,  // [9][32][32] bf16
                                                const short* __restrict__ wTl5,
                                                const short* __restrict__ wTr1a,
                                                const float* __restrict__ w_r1b, // [32][9] fp32
                                                const float* __restrict__ r1_b2,
                                                float* __restrict__ out1)
{
    const int H1 = 384, HW1 = H1*H1, H2 = 192, HW2 = H2*H2;
    int tY = blockIdx.x / 24, tX = blockIdx.x % 24, n = blockIdx.z;
    int y0 = tY*16, x0 = tX*16;
    int uy0 = (y0>>1) - 2, ux0 = (x0>>1) - 2;

    __shared__ __align__(16) short sP0[484*36];   // vl, then t1
    __shared__ __align__(16) short sP1[400*36];   // u (144*36), then v
    __shared__ u8 s_m[484];
    short* s_u  = sP1;
    short* s_vl = sP0;
    short* s_v  = sP1;
    short* s_t1 = sP0;

    int tid = threadIdx.x;
    const short* uN = u + (size_t)n*32*HW2;
    for (int i = tid; i < 32*144; i += 256){
        int c = i/144, r = i%144; int ly = r/12, lxx = r%12;
        int gy = uy0+ly, gx = ux0+lxx;
        short v = 0;
        if ((unsigned)gy < 192u && (unsigned)gx < 192u) v = uN[(size_t)c*HW2 + gy*H2 + gx];
        s_u[r*36 + c] = v;
    }
    for (int i = tid; i < 484; i += 256){
        int ry = i/22, rx = i%22; int gy = y0-3+ry, gx = x0-3+rx;
        s_m[i] = ((unsigned)gy < 384u && (unsigned)gx < 384u) ? M1[(size_t)n*HW1 + gy*H1 + gx] : 0;
    }
    __syncthreads();

    int wv = tid >> 6, lane = tid & 63;
    int nQ = lane >> 4, nn = lane & 15;

    // ---- stage A: vl[484][32] = m ? leaky(invconv(u)*BNS) : 0 ; per parity class ----
    for (int ui = wv; ui < 32; ui += 4){
        int cls = ui >> 3, nt = ui & 7;
        int pY = (cls >> 1) & 1, pX = cls & 1;
        int s0 = nt*16 + nn;
        int s = s0 > 120 ? 120 : s0;
        int jr = s/11, jc = s%11;
        int ry = 2*jr + pY, rx = 2*jc + pX;
        int gY = y0-3+ry, gX = x0-3+rx;

        int tiy[4], tix[4], twk[4]; int tapN;
        if (pY == 0){   // gY odd -> dy in {-1,+1}
            int iA = ((gY-1)>>1) - uy0, iB = ((gY+1)>>1) - uy0;
            if (pX == 0){
                int jA = ((gX-1)>>1) - ux0, jB = ((gX+1)>>1) - ux0;
                tiy[0]=iA; tix[0]=jA; twk[0]=8;
                tiy[1]=iA; tix[1]=jB; twk[1]=6;
                tiy[2]=iB; tix[2]=jA; twk[2]=2;
                tiy[3]=iB; tix[3]=jB; twk[3]=0; tapN=4;
            } else {
                int j = (gX>>1) - ux0;
                tiy[0]=iA; tix[0]=j; twk[0]=7;
                tiy[1]=iB; tix[1]=j; twk[1]=1; tapN=2;
            }
        } else {        // gY even -> dy = 0
            int i2 = (gY>>1) - uy0;
            if (pX == 0){
                int jA = ((gX-1)>>1) - ux0, jB = ((gX+1)>>1) - ux0;
                tiy[0]=i2; tix[0]=jA; twk[0]=5;
                tiy[1]=i2; tix[1]=jB; twk[1]=3; tapN=2;
            } else {
                tiy[0]=i2; tix[0]=(gX>>1)-ux0; twk[0]=4; tapN=1;
            }
        }

        f32x4 acc0 = {0,0,0,0}, acc1 = {0,0,0,0};
        for (int t = 0; t < tapN; ++t){
            bf16x8 bfr = lds8(s_u + (tiy[t]*12 + tix[t])*36 + nQ*8);
            bf16x8 a0 = *(const bf16x8*)(wTi2 + twk[t]*1024 + nn*32 + nQ*8);
            bf16x8 a1 = *(const bf16x8*)(wTi2 + twk[t]*1024 + (16+nn)*32 + nQ*8);
            acc0 = MFMA_B16(a0, bfr, acc0, 0,0,0);
            acc1 = MFMA_B16(a1, bfr, acc1, 0,0,0);
        }
        if (s0 <= 120){
            int sidx = ry*22 + rx;
            u8 m = s_m[sidx];
            float r[8];
            #pragma unroll
            for (int g=0; g<2; ++g)
                #pragma unroll
                for (int e=0; e<4; ++e){
                    float a = (g ? acc1[e] : acc0[e]) * BNS;
                    float o = m ? (a > 0.f ? a : 0.2f*a) : 0.f;
                    r[g*4+e] = o;
                }
            bf16x4 w0 = {f2bs(r[0]),f2bs(r[1]),f2bs(r[2]),f2bs(r[3])};
            bf16x4 w1 = {f2bs(r[4]),f2bs(r[5]),f2bs(r[6]),f2bs(r[7])};
            *(bf16x4*)(s_vl + sidx*36 + nQ*4) = w0;
            *(bf16x4*)(s_vl + sidx*36 + 16 + nQ*4) = w1;
        }
    }
    __syncthreads();

    // ---- stage B: v[400][32] = m ? conv(vl,l5) + fea1 : 0 ----
    for (int nt = wv; nt < 25; nt += 4){
        int s0 = nt*16 + nn;
        int s = s0 > 399 ? 399 : s0;
        int vy = s/20, vx = s%20;
        f32x4 acc0 = {0,0,0,0}, acc1 = {0,0,0,0};
        #pragma unroll
        for (int ky=0; ky<3; ++ky)
            #pragma unroll
            for (int kx=0; kx<3; ++kx){
                int k = ky*3+kx;
                bf16x8 bfr = lds8(s_vl + ((vy+ky)*22 + vx+kx)*36 + nQ*8);
                bf16x8 a0 = *(const bf16x8*)(wTl5 + k*1024 + nn*32 + nQ*8);
                bf16x8 a1 = *(const bf16x8*)(wTl5 + k*1024 + (16+nn)*32 + nQ*8);
                acc0 = MFMA_B16(a0, bfr, acc0, 0,0,0);
                acc1 = MFMA_B16(a1, bfr, acc1, 0,0,0);
            }
        if (s0 <= 399){
            u8 m = s_m[(vy+1)*22 + vx+1];
            int gY = y0-2+vy, gX = x0-2+vx;
            const short* f1 = fea1 + (size_t)n*32*HW1 + (size_t)gY*H1 + gX;
            float r[8];
            #pragma unroll
            for (int g=0; g<2; ++g)
                #pragma unroll
                for (int e=0; e<4; ++e){
                    int co = g*16 + nQ*4 + e;
                    float a = g ? acc1[e] : acc0[e];
                    float o = 0.f;
                    if (m) o = a + s2f(f1[(size_t)co*HW1]);
                    r[g*4+e] = o;
                }
            bf16x4 w0 = {f2bs(r[0]),f2bs(r[1]),f2bs(r[2]),f2bs(r[3])};
            bf16x4 w1 = {f2bs(r[4]),f2bs(r[5]),f2bs(r[6]),f2bs(r[7])};
            *(bf16x4*)(s_v + s*36 + nQ*4) = w0;
            *(bf16x4*)(s_v + s*36 + 16 + nQ*4) = w1;
        }
    }
    __syncthreads();

    // ---- stage C: t1[324][32] = m ? leaky(conv(v,r1a)*BNS) : 0 ----
    for (int nt = wv; nt < 21; nt += 4){
        int s0 = nt*16 + nn;
        int s = s0 > 323 ? 323 : s0;
        int qy = s/18, qx = s%18;
        f32x4 acc0 = {0,0,0,0}, acc1 = {0,0,0,0};
        #pragma unroll
        for (int ky=0; ky<3; ++ky)
            #pragma unroll
            for (int kx=0; kx<3; ++kx){
                int k = ky*3+kx;
                bf16x8 bfr = lds8(s_v + ((qy+ky)*20 + qx+kx)*36 + nQ*8);
                bf16x8 a0 = *(const bf16x8*)(wTr1a + k*1024 + nn*32 + nQ*8);
                bf16x8 a1 = *(const bf16x8*)(wTr1a + k*1024 + (16+nn)*32 + nQ*8);
                acc0 = MFMA_B16(a0, bfr, acc0, 0,0,0);
                acc1 = MFMA_B16(a1, bfr, acc1, 0,0,0);
            }
        if (s0 <= 323){
            u8 m = s_m[(qy+2)*22 + qx+2];
            float r[8];
            #pragma unroll
            for (int g=0; g<2; ++g)
                #pragma unroll
                for (int e=0; e<4; ++e){
                    float a = (g ? acc1[e] : acc0[e]) * BNS;
                    float o = m ? (a > 0.f ? a : 0.2f*a) : 0.f;
                    r[g*4+e] = o;
                }
            bf16x4 w0 = {f2bs(r[0]),f2bs(r[1]),f2bs(r[2]),f2bs(r[3])};
            bf16x4 w1 = {f2bs(r[4]),f2bs(r[5]),f2bs(r[6]),f2bs(r[7])};
            *(bf16x4*)(s_t1 + s*36 + nQ*4) = w0;
            *(bf16x4*)(s_t1 + s*36 + 16 + nQ*4) = w1;
        }
    }
    __syncthreads();

    // ---- stage D: out 16x16 = m ? conv(t1, r1b) + b : -99 ----
    int ty = tid >> 4, tx = tid & 15;
    u8 m = s_m[(ty+3)*22 + tx+3];
    float o = -99.f;
    if (m){
        float acc = 0.f;
        #pragma unroll
        for (int k = 0; k < 9; ++k){
            const short* tp = s_t1 + ((ty + k/3)*18 + tx + k%3)*36;
            for (int ci = 0; ci < 32; ++ci)
                acc += s2f(tp[ci]) * w_r1b[ci*9 + k];
        }
        o = acc + r1_b2[0];
    }
    out1[(size_t)n*HW1 + (y0+ty)*H1 + (x0+tx)] = o;
}

// ---------------- launch ----------------

extern "C" void kernel_launch(void* const* d_in, const int* in_sizes, int n_in,
                              void* d_out, int out_size, void* d_ws, size_t ws_size,
                              hipStream_t stream)
{
    const float* x      = (const float*)d_in[0];
    const float* image  = (const float*)d_in[1];
    const float* masks  = (const float*)d_in[2];
    const float* roi    = (const float*)d_in[3];
    const float* w1a    = (const float*)d_in[4];
    const float* w1b    = (const float*)d_in[5];
    const float* w2a    = (const float*)d_in[6];
    const float* w2b    = (const float*)d_in[7];
    const float* w4a    = (const float*)d_in[8];
    const float* w4b    = (const float*)d_in[9];
    const float* inv4_w = (const float*)d_in[10];
    const float* l4_sub = (const float*)d_in[11];
    const float* inv2_w = (const float*)d_in[12];
    const float* l5_sub = (const float*)d_in[13];
    const float* r4_w1  = (const float*)d_in[14];
    const float* r4_w2  = (const float*)d_in[15];
    const float* r4_b2  = (const float*)d_in[16];
    const float* r1_w1  = (const float*)d_in[17];
    const float* r1_w2  = (const float*)d_in[18];
    const float* r1_b2  = (const float*)d_in[19];
    float* out = (float*)d_out;

    const int N = 8;
    const int H1 = 384, HW1 = 384*384;
    const int H2 = 192, HW2 = 192*192;
    const int H4 = 96,  HW4 = 96*96;

    char* wsp = (char*)d_ws;
    size_t off = 0;
    auto alloc = [&](size_t bytes) -> char* {
        char* p = wsp + off;
        off += (bytes + 255) & ~(size_t)255;
        return p;
    };
    bf16* FEA1 = (bf16*)alloc((size_t)N*32*HW1*2);
    u8*   M1   = (u8*)alloc((size_t)N*HW1);
    u8*   M2   = (u8*)alloc((size_t)N*HW2);
    u8*   M4   = (u8*)alloc((size_t)N*HW4);
    bf16* FEA2 = (bf16*)alloc((size_t)N*32*HW2*2);
    bf16* XS   = (bf16*)alloc((size_t)N*64*HW4*2);
    bf16* GU   = (bf16*)alloc((size_t)N*32*HW2*2);  // g, then u
    bf16* HT   = (bf16*)alloc((size_t)N*64*HW4*2);  // h, then t_leaky
    short* WT  = (short*)alloc(4*9216*2);           // [w1bT, inv2T, l5T, r1aT]
    (void)ws_size; (void)in_sizes; (void)n_in; (void)out_size;

    short* wT1b  = WT;
    short* wTi2  = WT + 9216;
    short* wTl5  = WT + 2*9216;
    short* wTr1a = WT + 3*9216;

    dim3 blk(256);

    // masks + weight prep
    k_mask1<<<dim3((N*HW1 + 255)/256), blk, 0, stream>>>(roi, M1, N*HW1);
    k_down<<<dim3((HW2 + 255)/256, N), blk, 0, stream>>>(M1, M2, H1, H1, H2, H2);
    k_down<<<dim3((HW4 + 255)/256, N), blk, 0, stream>>>(M2, M4, H2, H2, H4, H4);
    k_wprep<<<dim3(36, 4), blk, 0, stream>>>(w1b, inv2_w, l5_sub, r1_w1, WT);

    // front
    conv1ab2<<<dim3(576, 1, N), blk, 0, stream>>>(image, masks, M1, w1a, wT1b, (short*)FEA1);
    conv_s2<32,32,32><<<dim3(144, 1, N), blk, 0, stream>>>(FEA1, H1, H1, w2a, M2, GU, H2, H2, 12);
    conv_s1<32,32,32,0><<<dim3(72, 1, N), blk, 0, stream>>>(GU, H2, H2, w2b, M2, nullptr, FEA2, H2, H2, 12);
    conv_s2<32,32,64><<<dim3(36, 2, N), blk, 0, stream>>>(FEA2, H2, H2, w4a, M4, HT, H4, H4, 6);
    conv_s1<64,32,64,3><<<dim3(18, 2, N), blk, 0, stream>>>(HT, H4, H4, w4b, M4, x, XS, H4, H4, 6);

    // refine_OS4
    conv_s1<64,32,32,1><<<dim3(18, 1, N), blk, 0, stream>>>(XS, H4, H4, r4_w1, M4, nullptr, HT, H4, H4, 6);
    conv3x3_head<32><<<dim3(36, 1, N), blk, 0, stream>>>(HT, H4, H4, r4_w2, r4_b2, M4, out);

    // layer4 fused -> u
    fk_l4b<<<dim3(144, 1, N), blk, 0, stream>>>(XS, FEA2, M2, inv4_w, l4_sub, GU);

    // MFMA back end -> out1
    fk_back3<<<dim3(576, 1, N), blk, 0, stream>>>((const short*)GU, (const short*)FEA1, M1,
                                                  wTi2, wTl5, wTr1a, r1_w2, r1_b2,
                                                  out + (size_t)N*HW4);
}

// Round 7
// 2238.867 us; speedup vs baseline: 9.8175x; 1.4751x over previous
//
#include <hip/hip_runtime.h>
#include <hip/hip_bf16.h>

using bf16 = __hip_bfloat16;
typedef unsigned char u8;
typedef short bf16x8 __attribute__((ext_vector_type(8)));
typedef short bf16x4 __attribute__((ext_vector_type(4)));
typedef float f32x4 __attribute__((ext_vector_type(4)));

#define BNS 0.9999950000374997f   // 1/sqrt(1+1e-5)
#define MFMA_B16 __builtin_amdgcn_mfma_f32_16x16x32_bf16

__device__ __forceinline__ float b2f(bf16 v){ return __bfloat162float(v); }
__device__ __forceinline__ bf16 f2b(float v){ return __float2bfloat16(v); }
__device__ __forceinline__ short f2bs(float v){ bf16 h = __float2bfloat16(v); return *reinterpret_cast<short*>(&h); }
__device__ __forceinline__ float s2f(short s){ union{unsigned u; float f;} x; x.u = ((unsigned)(unsigned short)s) << 16; return x.f; }

__device__ __forceinline__ bf16x8 lds8(const short* p){
    bf16x4 lo = *(const bf16x4*)(p);
    bf16x4 hi = *(const bf16x4*)(p + 4);
    bf16x8 r = {lo[0],lo[1],lo[2],lo[3],hi[0],hi[1],hi[2],hi[3]};
    return r;
}

// ---------------- mask kernels ----------------

__global__ __launch_bounds__(256) void k_mask1(const float* __restrict__ roi, u8* __restrict__ m1, int total){
    int i = blockIdx.x*256 + threadIdx.x;
    if (i < total) m1[i] = (roi[i] > 0.8f) ? 1 : 0;
}

__global__ __launch_bounds__(256) void k_down(const u8* __restrict__ mi, u8* __restrict__ mo,
                                              int IH, int IW, int OH, int OW){
    int p = blockIdx.x*256 + threadIdx.x;
    int n = blockIdx.y;
    if (p >= OH*OW) return;
    int oy = p / OW, ox = p - oy*OW;
    const u8* src = mi + (size_t)n*IH*IW;
    int v = 0;
    #pragma unroll
    for (int ky=0; ky<3; ky++){
        int iy = 2*oy + ky - 1;
        if ((unsigned)iy >= (unsigned)IH) continue;
        #pragma unroll
        for (int kx=0; kx<3; kx++){
            int ix = 2*ox + kx - 1;
            if ((unsigned)ix < (unsigned)IW) v |= src[iy*IW + ix];
        }
    }
    mo[(size_t)n*OH*OW + p] = (u8)v;
}

// ---- weight prep: {w1b, inv2, l5, r1a} [32][32][9] fp32 -> bf16 [9][32co][32ci] ----
__global__ __launch_bounds__(256) void k_wprep(const float* __restrict__ w1b,
                                               const float* __restrict__ i2,
                                               const float* __restrict__ l5,
                                               const float* __restrict__ r1a,
                                               short* __restrict__ dst){
    int a = blockIdx.y;
    const float* src = (a==0)? w1b : (a==1)? i2 : (a==2)? l5 : r1a;
    int j = blockIdx.x*256 + threadIdx.x;
    if (j < 9216){
        int co = j/288, r = j%288, ci = r/9, k = r%9;
        dst[a*9216 + k*1024 + co*32 + ci] = f2bs(src[j]);
    }
}

// ---- weight prep layer4: inv4 [64][64][9] -> [9][64][64]; l4_sub [32][64][9] -> [9][32][64] ----
__global__ __launch_bounds__(256) void k_wprep4(const float* __restrict__ inv4,
                                                const float* __restrict__ l4s,
                                                short* __restrict__ d_inv,   // 9*4096
                                                short* __restrict__ d_l4)    // 9*2048
{
    int j = blockIdx.x*256 + threadIdx.x;
    if (blockIdx.y == 0){
        if (j < 36864){
            int co = j/576, r = j%576, ci = r/9, k = r%9;
            d_inv[k*4096 + co*64 + ci] = f2bs(inv4[j]);
        }
    } else {
        if (j < 18432){
            int co = j/576, r = j%576, ci = r/9, k = r%9;
            d_l4[k*2048 + co*64 + ci] = f2bs(l4s[j]);
        }
    }
}

// ---------------- COUT=1 head (refine_OS4 second conv) ----------------
template<int CIN>
__global__ __launch_bounds__(256) void conv3x3_head(const bf16* __restrict__ in, int IH, int IW,
                                                    const float* __restrict__ w,
                                                    const float* __restrict__ wb,
                                                    const u8*   __restrict__ mask,
                                                    float* __restrict__ out)
{
    __shared__ float ws[CIN*9];
    int n = blockIdx.z;
    for (int i = threadIdx.x; i < CIN*9; i += blockDim.x) ws[i] = w[i];
    __syncthreads();

    int p = blockIdx.x*blockDim.x + threadIdx.x;
    if (p >= IH*IW) return;
    int oy = p / IW, ox = p - oy*IW;

    float acc = 0.f;
    const bf16* ibase = in + (size_t)n*CIN*IH*IW;
    for (int c = 0; c < CIN; ++c) {
        const bf16* ic = ibase + (size_t)c*IH*IW;
        const float* wc = ws + c*9;
        #pragma unroll
        for (int ky = 0; ky < 3; ++ky) {
            int iy = oy-1+ky;
            if ((unsigned)iy >= (unsigned)IH) continue;
            const bf16* irow = ic + (size_t)iy*IW;
            #pragma unroll
            for (int kx = 0; kx < 3; ++kx) {
                int ix = ox-1+kx;
                if ((unsigned)ix < (unsigned)IW)
                    acc += b2f(irow[ix]) * wc[ky*3 + kx];
            }
        }
    }
    bool m = mask[(size_t)n*IH*IW + p] != 0;
    out[(size_t)n*IH*IW + p] = m ? acc + wb[0] : -99.f;
}

// ---------------- v2 engine: stride-1 conv, tile 32x16, 2 px/thread ----------------
template<int CIN, int COUTB, int COUT_TOT, int EPI>
__global__ __launch_bounds__(256) void conv_s1(const bf16* __restrict__ in, int IH, int IW,
                                               const float* __restrict__ w,
                                               const u8* __restrict__ mask,
                                               const float* __restrict__ res32,
                                               bf16* __restrict__ out, int OH, int OW, int tilesX)
{
    const int TH=32, TW=16;
    int n = blockIdx.z, cog = blockIdx.y;
    int tY = blockIdx.x / tilesX, tX = blockIdx.x % tilesX;
    int y0 = tY*TH, x0 = tX*TW;
    const float* wB = w + (size_t)cog*COUTB*CIN*9;

    __shared__ float s_in[8][34*18];

    int tid = threadIdx.x;
    int lx = tid & 15;
    int lyb = (tid >> 4) * 2;

    float acc[2][COUTB];
    #pragma unroll
    for (int j=0;j<2;++j)
        #pragma unroll
        for (int c=0;c<COUTB;++c) acc[j][c]=0.f;

    const bf16* inN = in + (size_t)n*CIN*IH*IW;
    for (int c0 = 0; c0 < CIN; c0 += 8){
        __syncthreads();
        for (int i = tid; i < 8*612; i += 256){
            int cc = i / 612; int r = i % 612;
            int ly = r / 18, lxx = r % 18;
            int gy = y0-1+ly, gx = x0-1+lxx;
            float v = 0.f;
            if ((unsigned)gy < (unsigned)IH && (unsigned)gx < (unsigned)IW)
                v = b2f(inN[(size_t)(c0+cc)*IH*IW + (size_t)gy*IW + gx]);
            s_in[cc][r] = v;
        }
        __syncthreads();
        for (int cc = 0; cc < 8; ++cc){
            float p[4][3];
            #pragma unroll
            for (int r=0;r<4;++r)
                #pragma unroll
                for (int q=0;q<3;++q)
                    p[r][q] = s_in[cc][(lyb+r)*18 + lx+q];
            #pragma unroll
            for (int co = 0; co < COUTB; ++co){
                const float* w9 = wB + ((size_t)co*CIN + (c0+cc))*9;
                #pragma unroll
                for (int ky=0;ky<3;++ky)
                    #pragma unroll
                    for (int kx=0;kx<3;++kx){
                        float wv = w9[ky*3+kx];
                        acc[0][co] += p[ky][kx]*wv;
                        acc[1][co] += p[ky+1][kx]*wv;
                    }
            }
        }
    }
    #pragma unroll
    for (int j=0;j<2;++j){
        int oy = y0 + lyb + j, ox = x0 + lx;
        int p = oy*OW + ox;
        bool m = mask[(size_t)n*OH*OW + p] != 0;
        #pragma unroll
        for (int co=0; co<COUTB; ++co){
            float a = acc[j][co], o;
            if      (EPI == 0) o = m ? fmaxf(a,0.f)*BNS : 0.f;
            else if (EPI == 1){ float s = a*BNS; o = m ? (s>0.f ? s : 0.2f*s) : 0.f; }
            else { int cg = cog*COUTB+co;
                   o = m ? fmaxf(a,0.f)*BNS + res32[((size_t)(n>>2)*COUT_TOT + cg)*(size_t)(OH*OW) + p] : 0.f; }
            out[((size_t)n*COUT_TOT + cog*COUTB + co)*(size_t)(OH*OW) + p] = f2b(o);
        }
    }
}

// ---------------- v2 engine: stride-2 conv, tile 16x16 ----------------
template<int CIN, int COUTB, int COUT_TOT>
__global__ __launch_bounds__(256) void conv_s2(const bf16* __restrict__ in, int IH, int IW,
                                               const float* __restrict__ w,
                                               const u8* __restrict__ mask,
                                               bf16* __restrict__ out, int OH, int OW, int tilesX)
{
    int n = blockIdx.z, cog = blockIdx.y;
    int tY = blockIdx.x / tilesX, tX = blockIdx.x % tilesX;
    int y0 = tY*16, x0 = tX*16;
    const float* wB = w + (size_t)cog*COUTB*CIN*9;

    __shared__ float s_in[8][33*34];

    int tid = threadIdx.x;
    int lx = tid & 15, ly = tid >> 4;

    float acc[COUTB];
    #pragma unroll
    for (int c=0;c<COUTB;++c) acc[c]=0.f;

    const bf16* inN = in + (size_t)n*CIN*IH*IW;
    for (int c0 = 0; c0 < CIN; c0 += 8){
        __syncthreads();
        for (int i = tid; i < 8*1089; i += 256){
            int cc = i / 1089; int r = i % 1089;
            int ry = r / 33, rx = r % 33;
            int gy = 2*y0-1+ry, gx = 2*x0-1+rx;
            float v = 0.f;
            if ((unsigned)gy < (unsigned)IH && (unsigned)gx < (unsigned)IW)
                v = b2f(inN[(size_t)(c0+cc)*IH*IW + (size_t)gy*IW + gx]);
            s_in[cc][ry*34 + rx] = v;
        }
        __syncthreads();
        for (int cc = 0; cc < 8; ++cc){
            float p[3][3];
            #pragma unroll
            for (int r=0;r<3;++r)
                #pragma unroll
                for (int q=0;q<3;++q)
                    p[r][q] = s_in[cc][(2*ly+r)*34 + 2*lx+q];
            #pragma unroll
            for (int co = 0; co < COUTB; ++co){
                const float* w9 = wB + ((size_t)co*CIN + (c0+cc))*9;
                #pragma unroll
                for (int k=0;k<9;++k)
                    acc[co] += p[k/3][k%3]*w9[k];
            }
        }
    }
    int oy = y0+ly, ox = x0+lx;
    int p = oy*OW + ox;
    bool m = mask[(size_t)n*OH*OW + p] != 0;
    #pragma unroll
    for (int co=0; co<COUTB; ++co){
        float o = m ? fmaxf(acc[co],0.f)*BNS : 0.f;
        out[((size_t)n*COUT_TOT + cog*COUTB + co)*(size_t)(OH*OW) + p] = f2b(o);
    }
}

// ---------------- conv1ab v2: scalar f-stage + MFMA stage-2 -> fea1 ----------------
__global__ __launch_bounds__(256) void conv1ab2(const float* __restrict__ image,
                                                const float* __restrict__ masks,
                                                const u8*  __restrict__ M1,
                                                const float* __restrict__ w1a,    // [32][4][9]
                                                const short* __restrict__ wT1b,   // [9][32co][32ci] bf16
                                                short* __restrict__ fea1)
{
    const int H = 384; const int HW = H*H;
    int tY = blockIdx.x / 24, tX = blockIdx.x % 24, n = blockIdx.z;
    int y0 = tY*16, x0 = tX*16;

    __shared__ float s_inp[4][400];
    __shared__ u8    s_m[400];
    __shared__ __align__(16) short s_f[324*36];

    int tid = threadIdx.x;
    for (int i = tid; i < 400; i += 256){
        int ly = i/20, lxx = i%20;
        int gy = y0-2+ly, gx = x0-2+lxx;
        bool inb = ((unsigned)gy < 384u) && ((unsigned)gx < 384u);
        u8 mv = inb ? M1[(size_t)n*HW + gy*H + gx] : 0;
        s_m[i] = mv;
        float mm = (float)mv;
        int p = gy*H + gx;
        #pragma unroll
        for (int c = 0; c < 4; ++c){
            float v = 0.f;
            if (inb) v = (c < 3) ? image[((size_t)(n>>2)*3 + c)*HW + p]
                                 : masks[(size_t)n*HW + p];
            s_inp[c][i] = v*mm;
        }
    }
    __syncthreads();

    for (int ch = 0; ch < 32; ++ch){
        const float* wA = w1a + ch*36;
        for (int i = tid; i < 324; i += 256){
            int fy = i/18, fx = i%18;
            float a = 0.f;
            #pragma unroll
            for (int ci=0; ci<4; ++ci)
                #pragma unroll
                for (int k=0;k<9;++k)
                    a += s_inp[ci][(fy + k/3)*20 + fx + k%3] * wA[ci*9+k];
            float o = s_m[(fy+1)*20 + fx+1] ? fmaxf(a,0.f)*BNS : 0.f;
            s_f[i*36 + ch] = f2bs(o);
        }
    }
    __syncthreads();

    int wv = tid >> 6, lane = tid & 63;
    int nQ = lane >> 4, nn = lane & 15;
    for (int nt = wv; nt < 16; nt += 4){
        int s = nt*16 + nn;
        int ty = s >> 4, tx = s & 15;
        f32x4 acc0 = {0,0,0,0}, acc1 = {0,0,0,0};
        #pragma unroll
        for (int ky=0; ky<3; ++ky)
            #pragma unroll
            for (int kx=0; kx<3; ++kx){
                int k = ky*3+kx;
                bf16x8 bfr = lds8(s_f + ((ty+ky)*18 + tx+kx)*36 + nQ*8);
                bf16x8 a0 = *(const bf16x8*)(wT1b + k*1024 + nn*32 + nQ*8);
                bf16x8 a1 = *(const bf16x8*)(wT1b + k*1024 + (16+nn)*32 + nQ*8);
                acc0 = MFMA_B16(a0, bfr, acc0, 0,0,0);
                acc1 = MFMA_B16(a1, bfr, acc1, 0,0,0);
            }
        u8 m = s_m[(ty+2)*20 + tx+2];
        int gy = y0+ty, gx = x0+tx;
        short* fp = fea1 + (size_t)n*32*HW + gy*H + gx;
        #pragma unroll
        for (int g=0; g<2; ++g)
            #pragma unroll
            for (int e=0; e<4; ++e){
                int co = g*16 + nQ*4 + e;
                float a = g ? acc1[e] : acc0[e];
                float o = m ? fmaxf(a,0.f)*BNS : 0.f;
                fp[(size_t)co*HW] = f2bs(o);
            }
    }
}

// ---------------- MFMA layer4: inv4(64->64)+leaky + l4_sub(64->32)+fea2 -> u ----------
// K=64 as two K=32 halves; tiles [site][36] per half (stride-36 pattern proven in fk_back3)
__global__ __launch_bounds__(256) void fk_l4c(const short* __restrict__ xs,    // [8][64][HW4] bf16
                                              const short* __restrict__ fea2,  // [8][32][HW2] bf16
                                              const u8*  __restrict__ M2,
                                              const short* __restrict__ wTi4,  // [9][64co][64ci]
                                              const short* __restrict__ wTl4,  // [9][32co][64ci]
                                              short* __restrict__ u_out)       // [8][32][HW2] bf16
{
    const int H2 = 192, HW2 = H2*H2, H4 = 96, HW4 = H4*H4;
    int tY = blockIdx.x / 12, tX = blockIdx.x % 12, n = blockIdx.z;
    int y0 = tY*16, x0 = tX*16;
    int uy0 = (y0>>1) - 1, ux0 = (x0>>1) - 1;

    __shared__ __align__(16) short s_xs[2*100*36];   // halves: ci 0-31, 32-63
    __shared__ __align__(16) short s_ul[2*324*36];
    __shared__ u8 s_m[324];

    int tid = threadIdx.x;
    const short* xN = xs + (size_t)n*64*HW4;
    for (int i = tid; i < 64*100; i += 256){
        int c = i/100, r = i%100; int ly = r/10, lxx = r%10;
        int gy = uy0+ly, gx = ux0+lxx;
        short v = 0;
        if ((unsigned)gy < 96u && (unsigned)gx < 96u) v = xN[(size_t)c*HW4 + gy*H4 + gx];
        s_xs[(c>>5)*3600 + r*36 + (c&31)] = v;
    }
    for (int i = tid; i < 324; i += 256){
        int ry = i/18, rx = i%18; int gy = y0-1+ry, gx = x0-1+rx;
        s_m[i] = ((unsigned)gy < 192u && (unsigned)gx < 192u) ? M2[(size_t)n*HW2 + gy*H2 + gx] : 0;
    }
    __syncthreads();

    int wv = tid >> 6, lane = tid & 63;
    int nQ = lane >> 4, nn = lane & 15;

    // ---- stage A: ul[324][64] = m ? leaky(invconv(xs)*BNS) : 0 ----
    for (int ui = wv; ui < 24; ui += 4){
        int cls = ui/6, nt = ui%6;
        int pY = cls >> 1, pX = cls & 1;
        int s0 = nt*16 + nn;
        int s = s0 > 80 ? 80 : s0;
        int jr = s/9, jc = s%9;
        int ry = 2*jr + pY, rx = 2*jc + pX;
        int gY = y0-1+ry, gX = x0-1+rx;

        int tiy[4], tix[4], twk[4]; int tapN;
        if (pY == 0){   // gY odd -> dy in {-1,+1}
            int iA = ((gY-1)>>1) - uy0, iB = ((gY+1)>>1) - uy0;
            if (pX == 0){
                int jA = ((gX-1)>>1) - ux0, jB = ((gX+1)>>1) - ux0;
                tiy[0]=iA; tix[0]=jA; twk[0]=8;
                tiy[1]=iA; tix[1]=jB; twk[1]=6;
                tiy[2]=iB; tix[2]=jA; twk[2]=2;
                tiy[3]=iB; tix[3]=jB; twk[3]=0; tapN=4;
            } else {
                int j = (gX>>1) - ux0;
                tiy[0]=iA; tix[0]=j; twk[0]=7;
                tiy[1]=iB; tix[1]=j; twk[1]=1; tapN=2;
            }
        } else {        // gY even -> dy = 0
            int i2 = (gY>>1) - uy0;
            if (pX == 0){
                int jA = ((gX-1)>>1) - ux0, jB = ((gX+1)>>1) - ux0;
                tiy[0]=i2; tix[0]=jA; twk[0]=5;
                tiy[1]=i2; tix[1]=jB; twk[1]=3; tapN=2;
            } else {
                tiy[0]=i2; tix[0]=(gX>>1)-ux0; twk[0]=4; tapN=1;
            }
        }

        f32x4 acc[4];
        #pragma unroll
        for (int g=0; g<4; ++g) acc[g] = (f32x4){0,0,0,0};
        for (int t = 0; t < tapN; ++t){
            int off = (tiy[t]*10 + tix[t])*36 + nQ*8;
            bf16x8 xlo = lds8(s_xs + off);
            bf16x8 xhi = lds8(s_xs + 3600 + off);
            const short* wk = wTi4 + twk[t]*4096;
            #pragma unroll
            for (int g=0; g<4; ++g){
                bf16x8 alo = *(const bf16x8*)(wk + (g*16+nn)*64 + nQ*8);
                bf16x8 ahi = *(const bf16x8*)(wk + (g*16+nn)*64 + 32 + nQ*8);
                acc[g] = MFMA_B16(alo, xlo, acc[g], 0,0,0);
                acc[g] = MFMA_B16(ahi, xhi, acc[g], 0,0,0);
            }
        }
        if (s0 <= 80){
            int sidx = ry*18 + rx;
            u8 m = s_m[sidx];
            #pragma unroll
            for (int g=0; g<4; ++g){
                float r[4];
                #pragma unroll
                for (int e=0; e<4; ++e){
                    float a = acc[g][e]*BNS;
                    r[e] = m ? (a > 0.f ? a : 0.2f*a) : 0.f;
                }
                bf16x4 w4 = {f2bs(r[0]),f2bs(r[1]),f2bs(r[2]),f2bs(r[3])};
                *(bf16x4*)(s_ul + (g>>1)*11664 + sidx*36 + (g&1)*16 + nQ*4) = w4;
            }
        }
    }
    __syncthreads();

    // ---- stage B: u 16x16 x32 = m ? conv(ul, l4_sub) + fea2 : 0 ----
    for (int nt = wv; nt < 16; nt += 4){
        int ty = nt, tx = nn;
        f32x4 acc0 = {0,0,0,0}, acc1 = {0,0,0,0};
        #pragma unroll
        for (int ky=0; ky<3; ++ky)
            #pragma unroll
            for (int kx=0; kx<3; ++kx){
                int k = ky*3+kx;
                int off = ((ty+ky)*18 + tx+kx)*36 + nQ*8;
                bf16x8 vlo = lds8(s_ul + off);
                bf16x8 vhi = lds8(s_ul + 11664 + off);
                const short* wk = wTl4 + k*2048;
                bf16x8 a0lo = *(const bf16x8*)(wk + nn*64 + nQ*8);
                bf16x8 a0hi = *(const bf16x8*)(wk + nn*64 + 32 + nQ*8);
                bf16x8 a1lo = *(const bf16x8*)(wk + (16+nn)*64 + nQ*8);
                bf16x8 a1hi = *(const bf16x8*)(wk + (16+nn)*64 + 32 + nQ*8);
                acc0 = MFMA_B16(a0lo, vlo, acc0, 0,0,0);
                acc0 = MFMA_B16(a0hi, vhi, acc0, 0,0,0);
                acc1 = MFMA_B16(a1lo, vlo, acc1, 0,0,0);
                acc1 = MFMA_B16(a1hi, vhi, acc1, 0,0,0);
            }
        int gy = y0+ty, gx = x0+tx;
        int p = gy*H2 + gx;
        u8 m = s_m[(ty+1)*18 + tx+1];
        const short* f2p = fea2 + (size_t)n*32*HW2 + p;
        short* up = u_out + (size_t)n*32*HW2 + p;
        #pragma unroll
        for (int g=0; g<2; ++g)
            #pragma unroll
            for (int e=0; e<4; ++e){
                int co = g*16 + nQ*4 + e;
                float a = g ? acc1[e] : acc0[e];
                float o = m ? a + s2f(f2p[(size_t)co*HW2]) : 0.f;
                up[(size_t)co*HW2] = f2bs(o);
            }
    }
}

// ---------------- MFMA back end: inv2 -> l5+fea1 -> r1a -> r1b ----------------
__global__ __launch_bounds__(256) void fk_back3(const short* __restrict__ u,
                                                const short* __restrict__ fea1,
                                                const u8*  __restrict__ M1,
                                                const short* __restrict__ wTi2,
                                                const short* __restrict__ wTl5,
                                                const short* __restrict__ wTr1a,
                                                const float* __restrict__ w_r1b,
                                                const float* __restrict__ r1_b2,
                                                float* __restrict__ out1)
{
    const int H1 = 384, HW1 = H1*H1, H2 = 192, HW2 = H2*H2;
    int tY = blockIdx.x / 24, tX = blockIdx.x % 24, n = blockIdx.z;
    int y0 = tY*16, x0 = tX*16;
    int uy0 = (y0>>1) - 2, ux0 = (x0>>1) - 2;

    __shared__ __align__(16) short sP0[484*36];
    __shared__ __align__(16) short sP1[400*36];
    __shared__ u8 s_m[484];
    short* s_u  = sP1;
    short* s_vl = sP0;
    short* s_v  = sP1;
    short* s_t1 = sP0;

    int tid = threadIdx.x;
    const short* uN = u + (size_t)n*32*HW2;
    for (int i = tid; i < 32*144; i += 256){
        int c = i/144, r = i%144; int ly = r/12, lxx = r%12;
        int gy = uy0+ly, gx = ux0+lxx;
        short v = 0;
        if ((unsigned)gy < 192u && (unsigned)gx < 192u) v = uN[(size_t)c*HW2 + gy*H2 + gx];
        s_u[r*36 + c] = v;
    }
    for (int i = tid; i < 484; i += 256){
        int ry = i/22, rx = i%22; int gy = y0-3+ry, gx = x0-3+rx;
        s_m[i] = ((unsigned)gy < 384u && (unsigned)gx < 384u) ? M1[(size_t)n*HW1 + gy*H1 + gx] : 0;
    }
    __syncthreads();

    int wv = tid >> 6, lane = tid & 63;
    int nQ = lane >> 4, nn = lane & 15;

    // ---- stage A: vl[484][32] ----
    for (int ui = wv; ui < 32; ui += 4){
        int cls = ui >> 3, nt = ui & 7;
        int pY = (cls >> 1) & 1, pX = cls & 1;
        int s0 = nt*16 + nn;
        int s = s0 > 120 ? 120 : s0;
        int jr = s/11, jc = s%11;
        int ry = 2*jr + pY, rx = 2*jc + pX;
        int gY = y0-3+ry, gX = x0-3+rx;

        int tiy[4], tix[4], twk[4]; int tapN;
        if (pY == 0){
            int iA = ((gY-1)>>1) - uy0, iB = ((gY+1)>>1) - uy0;
            if (pX == 0){
                int jA = ((gX-1)>>1) - ux0, jB = ((gX+1)>>1) - ux0;
                tiy[0]=iA; tix[0]=jA; twk[0]=8;
                tiy[1]=iA; tix[1]=jB; twk[1]=6;
                tiy[2]=iB; tix[2]=jA; twk[2]=2;
                tiy[3]=iB; tix[3]=jB; twk[3]=0; tapN=4;
            } else {
                int j = (gX>>1) - ux0;
                tiy[0]=iA; tix[0]=j; twk[0]=7;
                tiy[1]=iB; tix[1]=j; twk[1]=1; tapN=2;
            }
        } else {
            int i2 = (gY>>1) - uy0;
            if (pX == 0){
                int jA = ((gX-1)>>1) - ux0, jB = ((gX+1)>>1) - ux0;
                tiy[0]=i2; tix[0]=jA; twk[0]=5;
                tiy[1]=i2; tix[1]=jB; twk[1]=3; tapN=2;
            } else {
                tiy[0]=i2; tix[0]=(gX>>1)-ux0; twk[0]=4; tapN=1;
            }
        }

        f32x4 acc0 = {0,0,0,0}, acc1 = {0,0,0,0};
        for (int t = 0; t < tapN; ++t){
            bf16x8 bfr = lds8(s_u + (tiy[t]*12 + tix[t])*36 + nQ*8);
            bf16x8 a0 = *(const bf16x8*)(wTi2 + twk[t]*1024 + nn*32 + nQ*8);
            bf16x8 a1 = *(const bf16x8*)(wTi2 + twk[t]*1024 + (16+nn)*32 + nQ*8);
            acc0 = MFMA_B16(a0, bfr, acc0, 0,0,0);
            acc1 = MFMA_B16(a1, bfr, acc1, 0,0,0);
        }
        if (s0 <= 120){
            int sidx = ry*22 + rx;
            u8 m = s_m[sidx];
            float r[8];
            #pragma unroll
            for (int g=0; g<2; ++g)
                #pragma unroll
                for (int e=0; e<4; ++e){
                    float a = (g ? acc1[e] : acc0[e]) * BNS;
                    r[g*4+e] = m ? (a > 0.f ? a : 0.2f*a) : 0.f;
                }
            bf16x4 w0 = {f2bs(r[0]),f2bs(r[1]),f2bs(r[2]),f2bs(r[3])};
            bf16x4 w1 = {f2bs(r[4]),f2bs(r[5]),f2bs(r[6]),f2bs(r[7])};
            *(bf16x4*)(s_vl + sidx*36 + nQ*4) = w0;
            *(bf16x4*)(s_vl + sidx*36 + 16 + nQ*4) = w1;
        }
    }
    __syncthreads();

    // ---- stage B: v[400][32] ----
    for (int nt = wv; nt < 25; nt += 4){
        int s0 = nt*16 + nn;
        int s = s0 > 399 ? 399 : s0;
        int vy = s/20, vx = s%20;
        f32x4 acc0 = {0,0,0,0}, acc1 = {0,0,0,0};
        #pragma unroll
        for (int ky=0; ky<3; ++ky)
            #pragma unroll
            for (int kx=0; kx<3; ++kx){
                int k = ky*3+kx;
                bf16x8 bfr = lds8(s_vl + ((vy+ky)*22 + vx+kx)*36 + nQ*8);
                bf16x8 a0 = *(const bf16x8*)(wTl5 + k*1024 + nn*32 + nQ*8);
                bf16x8 a1 = *(const bf16x8*)(wTl5 + k*1024 + (16+nn)*32 + nQ*8);
                acc0 = MFMA_B16(a0, bfr, acc0, 0,0,0);
                acc1 = MFMA_B16(a1, bfr, acc1, 0,0,0);
            }
        if (s0 <= 399){
            u8 m = s_m[(vy+1)*22 + vx+1];
            int gY = y0-2+vy, gX = x0-2+vx;
            const short* f1 = fea1 + (size_t)n*32*HW1 + (size_t)gY*H1 + gX;
            float r[8];
            #pragma unroll
            for (int g=0; g<2; ++g)
                #pragma unroll
                for (int e=0; e<4; ++e){
                    int co = g*16 + nQ*4 + e;
                    float a = g ? acc1[e] : acc0[e];
                    r[g*4+e] = m ? a + s2f(f1[(size_t)co*HW1]) : 0.f;
                }
            bf16x4 w0 = {f2bs(r[0]),f2bs(r[1]),f2bs(r[2]),f2bs(r[3])};
            bf16x4 w1 = {f2bs(r[4]),f2bs(r[5]),f2bs(r[6]),f2bs(r[7])};
            *(bf16x4*)(s_v + s*36 + nQ*4) = w0;
            *(bf16x4*)(s_v + s*36 + 16 + nQ*4) = w1;
        }
    }
    __syncthreads();

    // ---- stage C: t1[324][32] ----
    for (int nt = wv; nt < 21; nt += 4){
        int s0 = nt*16 + nn;
        int s = s0 > 323 ? 323 : s0;
        int qy = s/18, qx = s%18;
        f32x4 acc0 = {0,0,0,0}, acc1 = {0,0,0,0};
        #pragma unroll
        for (int ky=0; ky<3; ++ky)
            #pragma unroll
            for (int kx=0; kx<3; ++kx){
                int k = ky*3+kx;
                bf16x8 bfr = lds8(s_v + ((qy+ky)*20 + qx+kx)*36 + nQ*8);
                bf16x8 a0 = *(const bf16x8*)(wTr1a + k*1024 + nn*32 + nQ*8);
                bf16x8 a1 = *(const bf16x8*)(wTr1a + k*1024 + (16+nn)*32 + nQ*8);
                acc0 = MFMA_B16(a0, bfr, acc0, 0,0,0);
                acc1 = MFMA_B16(a1, bfr, acc1, 0,0,0);
            }
        if (s0 <= 323){
            u8 m = s_m[(qy+2)*22 + qx+2];
            float r[8];
            #pragma unroll
            for (int g=0; g<2; ++g)
                #pragma unroll
                for (int e=0; e<4; ++e){
                    float a = (g ? acc1[e] : acc0[e]) * BNS;
                    r[g*4+e] = m ? (a > 0.f ? a : 0.2f*a) : 0.f;
                }
            bf16x4 w0 = {f2bs(r[0]),f2bs(r[1]),f2bs(r[2]),f2bs(r[3])};
            bf16x4 w1 = {f2bs(r[4]),f2bs(r[5]),f2bs(r[6]),f2bs(r[7])};
            *(bf16x4*)(s_t1 + s*36 + nQ*4) = w0;
            *(bf16x4*)(s_t1 + s*36 + 16 + nQ*4) = w1;
        }
    }
    __syncthreads();

    // ---- stage D ----
    int ty = tid >> 4, tx = tid & 15;
    u8 m = s_m[(ty+3)*22 + tx+3];
    float o = -99.f;
    if (m){
        float acc = 0.f;
        #pragma unroll
        for (int k = 0; k < 9; ++k){
            const short* tp = s_t1 + ((ty + k/3)*18 + tx + k%3)*36;
            for (int ci = 0; ci < 32; ++ci)
                acc += s2f(tp[ci]) * w_r1b[ci*9 + k];
        }
        o = acc + r1_b2[0];
    }
    out1[(size_t)n*HW1 + (y0+ty)*H1 + (x0+tx)] = o;
}

// ---------------- launch ----------------

extern "C" void kernel_launch(void* const* d_in, const int* in_sizes, int n_in,
                              void* d_out, int out_size, void* d_ws, size_t ws_size,
                              hipStream_t stream)
{
    const float* x      = (const float*)d_in[0];
    const float* image  = (const float*)d_in[1];
    const float* masks  = (const float*)d_in[2];
    const float* roi    = (const float*)d_in[3];
    const float* w1a    = (const float*)d_in[4];
    const float* w1b    = (const float*)d_in[5];
    const float* w2a    = (const float*)d_in[6];
    const float* w2b    = (const float*)d_in[7];
    const float* w4a    = (const float*)d_in[8];
    const float* w4b    = (const float*)d_in[9];
    const float* inv4_w = (const float*)d_in[10];
    const float* l4_sub = (const float*)d_in[11];
    const float* inv2_w = (const float*)d_in[12];
    const float* l5_sub = (const float*)d_in[13];
    const float* r4_w1  = (const float*)d_in[14];
    const float* r4_w2  = (const float*)d_in[15];
    const float* r4_b2  = (const float*)d_in[16];
    const float* r1_w1  = (const float*)d_in[17];
    const float* r1_w2  = (const float*)d_in[18];
    const float* r1_b2  = (const float*)d_in[19];
    float* out = (float*)d_out;

    const int N = 8;
    const int H1 = 384, HW1 = 384*384;
    const int H2 = 192, HW2 = 192*192;
    const int H4 = 96,  HW4 = 96*96;

    char* wsp = (char*)d_ws;
    size_t off = 0;
    auto alloc = [&](size_t bytes) -> char* {
        char* p = wsp + off;
        off += (bytes + 255) & ~(size_t)255;
        return p;
    };
    bf16* FEA1 = (bf16*)alloc((size_t)N*32*HW1*2);
    u8*   M1   = (u8*)alloc((size_t)N*HW1);
    u8*   M2   = (u8*)alloc((size_t)N*HW2);
    u8*   M4   = (u8*)alloc((size_t)N*HW4);
    bf16* FEA2 = (bf16*)alloc((size_t)N*32*HW2*2);
    bf16* XS   = (bf16*)alloc((size_t)N*64*HW4*2);
    bf16* GU   = (bf16*)alloc((size_t)N*32*HW2*2);  // g, then u
    bf16* HT   = (bf16*)alloc((size_t)N*64*HW4*2);  // h, then t_leaky
    short* WT  = (short*)alloc(4*9216*2);           // [w1bT, inv2T, l5T, r1aT]
    short* WT4i = (short*)alloc((size_t)9*4096*2);  // inv4T
    short* WT4l = (short*)alloc((size_t)9*2048*2);  // l4_subT
    (void)ws_size; (void)in_sizes; (void)n_in; (void)out_size;

    short* wT1b  = WT;
    short* wTi2  = WT + 9216;
    short* wTl5  = WT + 2*9216;
    short* wTr1a = WT + 3*9216;

    dim3 blk(256);

    // masks + weight prep
    k_mask1<<<dim3((N*HW1 + 255)/256), blk, 0, stream>>>(roi, M1, N*HW1);
    k_down<<<dim3((HW2 + 255)/256, N), blk, 0, stream>>>(M1, M2, H1, H1, H2, H2);
    k_down<<<dim3((HW4 + 255)/256, N), blk, 0, stream>>>(M2, M4, H2, H2, H4, H4);
    k_wprep<<<dim3(36, 4), blk, 0, stream>>>(w1b, inv2_w, l5_sub, r1_w1, WT);
    k_wprep4<<<dim3(144, 2), blk, 0, stream>>>(inv4_w, l4_sub, WT4i, WT4l);

    // front
    conv1ab2<<<dim3(576, 1, N), blk, 0, stream>>>(image, masks, M1, w1a, wT1b, (short*)FEA1);
    conv_s2<32,32,32><<<dim3(144, 1, N), blk, 0, stream>>>(FEA1, H1, H1, w2a, M2, GU, H2, H2, 12);
    conv_s1<32,32,32,0><<<dim3(72, 1, N), blk, 0, stream>>>(GU, H2, H2, w2b, M2, nullptr, FEA2, H2, H2, 12);
    conv_s2<32,32,64><<<dim3(36, 2, N), blk, 0, stream>>>(FEA2, H2, H2, w4a, M4, HT, H4, H4, 6);
    conv_s1<64,32,64,3><<<dim3(18, 2, N), blk, 0, stream>>>(HT, H4, H4, w4b, M4, x, XS, H4, H4, 6);

    // refine_OS4
    conv_s1<64,32,32,1><<<dim3(18, 1, N), blk, 0, stream>>>(XS, H4, H4, r4_w1, M4, nullptr, HT, H4, H4, 6);
    conv3x3_head<32><<<dim3(36, 1, N), blk, 0, stream>>>(HT, H4, H4, r4_w2, r4_b2, M4, out);

    // layer4 fused (MFMA) -> u
    fk_l4c<<<dim3(144, 1, N), blk, 0, stream>>>((const short*)XS, (const short*)FEA2, M2,
                                                WT4i, WT4l, (short*)GU);

    // MFMA back end -> out1
    fk_back3<<<dim3(576, 1, N), blk, 0, stream>>>((const short*)GU, (const short*)FEA1, M1,
                                                  wTi2, wTl5, wTr1a, r1_w2, r1_b2,
                                                  out + (size_t)N*HW4);
}

// Round 8
// 1567.716 us; speedup vs baseline: 14.0204x; 1.4281x over previous
//
#include <hip/hip_runtime.h>
#include <hip/hip_bf16.h>

using bf16 = __hip_bfloat16;
typedef unsigned char u8;
typedef short bf16x8 __attribute__((ext_vector_type(8)));
typedef short bf16x4 __attribute__((ext_vector_type(4)));
typedef float f32x4 __attribute__((ext_vector_type(4)));

#define BNS 0.9999950000374997f   // 1/sqrt(1+1e-5)
#define MFMA_B16 __builtin_amdgcn_mfma_f32_16x16x32_bf16

__device__ __forceinline__ float b2f(bf16 v){ return __bfloat162float(v); }
__device__ __forceinline__ bf16 f2b(float v){ return __float2bfloat16(v); }
__device__ __forceinline__ short f2bs(float v){ bf16 h = __float2bfloat16(v); return *reinterpret_cast<short*>(&h); }
__device__ __forceinline__ float s2f(short s){ union{unsigned u; float f;} x; x.u = ((unsigned)(unsigned short)s) << 16; return x.f; }

__device__ __forceinline__ bf16x8 lds8(const short* p){
    bf16x4 lo = *(const bf16x4*)(p);
    bf16x4 hi = *(const bf16x4*)(p + 4);
    bf16x8 r = {lo[0],lo[1],lo[2],lo[3],hi[0],hi[1],hi[2],hi[3]};
    return r;
}

// ---------------- mask kernels ----------------

__global__ __launch_bounds__(256) void k_mask1(const float* __restrict__ roi, u8* __restrict__ m1, int total){
    int i = blockIdx.x*256 + threadIdx.x;
    if (i < total) m1[i] = (roi[i] > 0.8f) ? 1 : 0;
}

__global__ __launch_bounds__(256) void k_down(const u8* __restrict__ mi, u8* __restrict__ mo,
                                              int IH, int IW, int OH, int OW){
    int p = blockIdx.x*256 + threadIdx.x;
    int n = blockIdx.y;
    if (p >= OH*OW) return;
    int oy = p / OW, ox = p - oy*OW;
    const u8* src = mi + (size_t)n*IH*IW;
    int v = 0;
    #pragma unroll
    for (int ky=0; ky<3; ky++){
        int iy = 2*oy + ky - 1;
        if ((unsigned)iy >= (unsigned)IH) continue;
        #pragma unroll
        for (int kx=0; kx<3; kx++){
            int ix = 2*ox + kx - 1;
            if ((unsigned)ix < (unsigned)IW) v |= src[iy*IW + ix];
        }
    }
    mo[(size_t)n*OH*OW + p] = (u8)v;
}

// ---- weight prep: 5 arrays [32][32][9] fp32 -> bf16 [9][32co][32ci] ----
__global__ __launch_bounds__(256) void k_wprep(const float* __restrict__ w1b,
                                               const float* __restrict__ i2,
                                               const float* __restrict__ l5,
                                               const float* __restrict__ r1a,
                                               const float* __restrict__ w2b,
                                               short* __restrict__ dst){
    int a = blockIdx.y;
    const float* src = (a==0)? w1b : (a==1)? i2 : (a==2)? l5 : (a==3)? r1a : w2b;
    int j = blockIdx.x*256 + threadIdx.x;
    if (j < 9216){
        int co = j/288, r = j%288, ci = r/9, k = r%9;
        dst[a*9216 + k*1024 + co*32 + ci] = f2bs(src[j]);
    }
}

// ---- weight prep 64-ci: inv4 [64][64][9]->[9][64][64]@0; w4b same @36864;
//      l4_sub [32][64][9]->[9][32][64]@73728; r4_w1 same @92160 ----
__global__ __launch_bounds__(256) void k_wprep4(const float* __restrict__ inv4,
                                                const float* __restrict__ w4b,
                                                const float* __restrict__ l4s,
                                                const float* __restrict__ r4w1,
                                                short* __restrict__ dst)
{
    int a = blockIdx.y;
    int j = blockIdx.x*256 + threadIdx.x;
    if (a < 2){
        if (j < 36864){
            int co = j/576, r = j%576, ci = r/9, k = r%9;
            const float* s = a ? w4b : inv4;
            dst[a*36864 + k*4096 + co*64 + ci] = f2bs(s[j]);
        }
    } else {
        if (j < 18432){
            int co = j/576, r = j%576, ci = r/9, k = r%9;
            const float* s = (a==2) ? l4s : r4w1;
            dst[73728 + (a-2)*18432 + k*2048 + co*64 + ci] = f2bs(s[j]);
        }
    }
}

// ---------------- COUT=1 head (refine_OS4 second conv) ----------------
template<int CIN>
__global__ __launch_bounds__(256) void conv3x3_head(const bf16* __restrict__ in, int IH, int IW,
                                                    const float* __restrict__ w,
                                                    const float* __restrict__ wb,
                                                    const u8*   __restrict__ mask,
                                                    float* __restrict__ out)
{
    __shared__ float ws[CIN*9];
    int n = blockIdx.z;
    for (int i = threadIdx.x; i < CIN*9; i += blockDim.x) ws[i] = w[i];
    __syncthreads();

    int p = blockIdx.x*blockDim.x + threadIdx.x;
    if (p >= IH*IW) return;
    int oy = p / IW, ox = p - oy*IW;

    float acc = 0.f;
    const bf16* ibase = in + (size_t)n*CIN*IH*IW;
    for (int c = 0; c < CIN; ++c) {
        const bf16* ic = ibase + (size_t)c*IH*IW;
        const float* wc = ws + c*9;
        #pragma unroll
        for (int ky = 0; ky < 3; ++ky) {
            int iy = oy-1+ky;
            if ((unsigned)iy >= (unsigned)IH) continue;
            const bf16* irow = ic + (size_t)iy*IW;
            #pragma unroll
            for (int kx = 0; kx < 3; ++kx) {
                int ix = ox-1+kx;
                if ((unsigned)ix < (unsigned)IW)
                    acc += b2f(irow[ix]) * wc[ky*3 + kx];
            }
        }
    }
    bool m = mask[(size_t)n*IH*IW + p] != 0;
    out[(size_t)n*IH*IW + p] = m ? acc + wb[0] : -99.f;
}

// ---------------- scalar stride-2 conv (w2a, w4a) ----------------
template<int CIN, int COUTB, int COUT_TOT>
__global__ __launch_bounds__(256) void conv_s2(const bf16* __restrict__ in, int IH, int IW,
                                               const float* __restrict__ w,
                                               const u8* __restrict__ mask,
                                               bf16* __restrict__ out, int OH, int OW, int tilesX)
{
    int n = blockIdx.z, cog = blockIdx.y;
    int tY = blockIdx.x / tilesX, tX = blockIdx.x % tilesX;
    int y0 = tY*16, x0 = tX*16;
    const float* wB = w + (size_t)cog*COUTB*CIN*9;

    __shared__ float s_in[8][33*34];

    int tid = threadIdx.x;
    int lx = tid & 15, ly = tid >> 4;

    float acc[COUTB];
    #pragma unroll
    for (int c=0;c<COUTB;++c) acc[c]=0.f;

    const bf16* inN = in + (size_t)n*CIN*IH*IW;
    for (int c0 = 0; c0 < CIN; c0 += 8){
        __syncthreads();
        for (int i = tid; i < 8*1089; i += 256){
            int cc = i / 1089; int r = i % 1089;
            int ry = r / 33, rx = r % 33;
            int gy = 2*y0-1+ry, gx = 2*x0-1+rx;
            float v = 0.f;
            if ((unsigned)gy < (unsigned)IH && (unsigned)gx < (unsigned)IW)
                v = b2f(inN[(size_t)(c0+cc)*IH*IW + (size_t)gy*IW + gx]);
            s_in[cc][ry*34 + rx] = v;
        }
        __syncthreads();
        for (int cc = 0; cc < 8; ++cc){
            float p[3][3];
            #pragma unroll
            for (int r=0;r<3;++r)
                #pragma unroll
                for (int q=0;q<3;++q)
                    p[r][q] = s_in[cc][(2*ly+r)*34 + 2*lx+q];
            #pragma unroll
            for (int co = 0; co < COUTB; ++co){
                const float* w9 = wB + ((size_t)co*CIN + (c0+cc))*9;
                #pragma unroll
                for (int k=0;k<9;++k)
                    acc[co] += p[k/3][k%3]*w9[k];
            }
        }
    }
    int oy = y0+ly, ox = x0+lx;
    int p = oy*OW + ox;
    bool m = mask[(size_t)n*OH*OW + p] != 0;
    #pragma unroll
    for (int co=0; co<COUTB; ++co){
        float o = m ? fmaxf(acc[co],0.f)*BNS : 0.f;
        out[((size_t)n*COUT_TOT + cog*COUTB + co)*(size_t)(OH*OW) + p] = f2b(o);
    }
}

// ---------------- generic MFMA stride-1 conv ----------------
// in bf16 [N][CIN][H][H]; wT bf16 [9][COUT][CIN]; out bf16 [N][COUT][H][H]
// EPI: 0 m?relu*BNS | 1 m?leaky(a*BNS) | 3 m?relu*BNS + res32[(n>>2)] : 0
template<int CIN, int COUT, int EPI>
__global__ __launch_bounds__(256) void mconv_s1(const short* __restrict__ in, int H,
                                                const short* __restrict__ wT,
                                                const u8* __restrict__ mask,
                                                const float* __restrict__ res32,
                                                short* __restrict__ out, int tilesX)
{
    const int HW = H*H;
    const int HV = CIN/32, G = COUT/16;
    int tY = blockIdx.x / tilesX, tX = blockIdx.x % tilesX, n = blockIdx.z;
    int y0 = tY*16, x0 = tX*16;

    __shared__ __align__(16) short s_in[HV*11664];
    __shared__ u8 s_m[256];

    int tid = threadIdx.x;
    const short* inN = in + (size_t)n*CIN*HW;
    for (int i = tid; i < CIN*324; i += 256){
        int c = i/324, r = i%324;
        int ry = r/18, rx = r%18;
        int gy = y0-1+ry, gx = x0-1+rx;
        short v = 0;
        if ((unsigned)gy < (unsigned)H && (unsigned)gx < (unsigned)H)
            v = inN[(size_t)c*HW + gy*H + gx];
        s_in[(c>>5)*11664 + r*36 + (c&31)] = v;
    }
    for (int i = tid; i < 256; i += 256){
        int ty = i>>4, tx = i&15;
        s_m[i] = mask[(size_t)n*HW + (y0+ty)*H + x0+tx];
    }
    __syncthreads();

    int wv = tid >> 6, lane = tid & 63;
    int nQ = lane >> 4, nn = lane & 15;

    bf16x8 wa0[9], wa1[9];
    if constexpr (CIN == 32 && COUT == 32){
        #pragma unroll
        for (int k=0;k<9;++k){
            wa0[k] = *(const bf16x8*)(wT + k*1024 + nn*32 + nQ*8);
            wa1[k] = *(const bf16x8*)(wT + k*1024 + (16+nn)*32 + nQ*8);
        }
    }

    for (int nt = wv; nt < 16; nt += 4){
        int ty = nt, tx = nn;
        f32x4 acc[G];
        #pragma unroll
        for (int g=0;g<G;++g) acc[g] = (f32x4){0,0,0,0};
        #pragma unroll
        for (int ky=0; ky<3; ++ky)
            #pragma unroll
            for (int kx=0; kx<3; ++kx){
                const int k = ky*3+kx;
                #pragma unroll
                for (int h=0; h<HV; ++h){
                    bf16x8 bfr = lds8(s_in + h*11664 + ((ty+ky)*18 + tx+kx)*36 + nQ*8);
                    #pragma unroll
                    for (int g=0; g<G; ++g){
                        bf16x8 a;
                        if constexpr (CIN == 32 && COUT == 32) a = g ? wa1[k] : wa0[k];
                        else a = *(const bf16x8*)(wT + k*COUT*CIN + (g*16+nn)*CIN + h*32 + nQ*8);
                        acc[g] = MFMA_B16(a, bfr, acc[g], 0,0,0);
                    }
                }
            }
        int p = (y0+ty)*H + x0+tx;
        u8 m = s_m[nt*16 + nn];
        short* op = out + (size_t)n*COUT*HW + p;
        #pragma unroll
        for (int g=0; g<G; ++g)
            #pragma unroll
            for (int e=0; e<4; ++e){
                int co = g*16 + nQ*4 + e;
                float a = acc[g][e], o;
                if      (EPI == 0) o = m ? fmaxf(a,0.f)*BNS : 0.f;
                else if (EPI == 1){ float s = a*BNS; o = m ? (s>0.f ? s : 0.2f*s) : 0.f; }
                else o = m ? fmaxf(a,0.f)*BNS + res32[((size_t)(n>>2)*COUT + co)*(size_t)HW + p] : 0.f;
                op[(size_t)co*HW] = f2bs(o);
            }
    }
}

// ---------------- conv1ab v3: scalar f-stage + MFMA stage-2 (A-frags preloaded) ----------
__global__ __launch_bounds__(256) void conv1ab2(const float* __restrict__ image,
                                                const float* __restrict__ masks,
                                                const u8*  __restrict__ M1,
                                                const float* __restrict__ w1a,
                                                const short* __restrict__ wT1b,
                                                short* __restrict__ fea1)
{
    const int H = 384; const int HW = H*H;
    int tY = blockIdx.x / 24, tX = blockIdx.x % 24, n = blockIdx.z;
    int y0 = tY*16, x0 = tX*16;

    __shared__ float s_inp[4][400];
    __shared__ u8    s_m[400];
    __shared__ __align__(16) short s_f[324*36];

    int tid = threadIdx.x;
    for (int i = tid; i < 400; i += 256){
        int ly = i/20, lxx = i%20;
        int gy = y0-2+ly, gx = x0-2+lxx;
        bool inb = ((unsigned)gy < 384u) && ((unsigned)gx < 384u);
        u8 mv = inb ? M1[(size_t)n*HW + gy*H + gx] : 0;
        s_m[i] = mv;
        float mm = (float)mv;
        int p = gy*H + gx;
        #pragma unroll
        for (int c = 0; c < 4; ++c){
            float v = 0.f;
            if (inb) v = (c < 3) ? image[((size_t)(n>>2)*3 + c)*HW + p]
                                 : masks[(size_t)n*HW + p];
            s_inp[c][i] = v*mm;
        }
    }
    __syncthreads();

    for (int ch = 0; ch < 32; ++ch){
        const float* wA = w1a + ch*36;
        for (int i = tid; i < 324; i += 256){
            int fy = i/18, fx = i%18;
            float a = 0.f;
            #pragma unroll
            for (int ci=0; ci<4; ++ci)
                #pragma unroll
                for (int k=0;k<9;++k)
                    a += s_inp[ci][(fy + k/3)*20 + fx + k%3] * wA[ci*9+k];
            float o = s_m[(fy+1)*20 + fx+1] ? fmaxf(a,0.f)*BNS : 0.f;
            s_f[i*36 + ch] = f2bs(o);
        }
    }
    __syncthreads();

    int wv = tid >> 6, lane = tid & 63;
    int nQ = lane >> 4, nn = lane & 15;

    bf16x8 wa0[9], wa1[9];
    #pragma unroll
    for (int k=0;k<9;++k){
        wa0[k] = *(const bf16x8*)(wT1b + k*1024 + nn*32 + nQ*8);
        wa1[k] = *(const bf16x8*)(wT1b + k*1024 + (16+nn)*32 + nQ*8);
    }

    for (int nt = wv; nt < 16; nt += 4){
        int s = nt*16 + nn;
        int ty = s >> 4, tx = s & 15;
        f32x4 acc0 = {0,0,0,0}, acc1 = {0,0,0,0};
        #pragma unroll
        for (int ky=0; ky<3; ++ky)
            #pragma unroll
            for (int kx=0; kx<3; ++kx){
                const int k = ky*3+kx;
                bf16x8 bfr = lds8(s_f + ((ty+ky)*18 + tx+kx)*36 + nQ*8);
                acc0 = MFMA_B16(wa0[k], bfr, acc0, 0,0,0);
                acc1 = MFMA_B16(wa1[k], bfr, acc1, 0,0,0);
            }
        u8 m = s_m[(ty+2)*20 + tx+2];
        int gy = y0+ty, gx = x0+tx;
        short* fp = fea1 + (size_t)n*32*HW + gy*H + gx;
        #pragma unroll
        for (int g=0; g<2; ++g)
            #pragma unroll
            for (int e=0; e<4; ++e){
                int co = g*16 + nQ*4 + e;
                float a = g ? acc1[e] : acc0[e];
                float o = m ? fmaxf(a,0.f)*BNS : 0.f;
                fp[(size_t)co*HW] = f2bs(o);
            }
    }
}

// ---------------- MFMA layer4 (unchanged from passing round 7) ----------------
__global__ __launch_bounds__(256) void fk_l4c(const short* __restrict__ xs,
                                              const short* __restrict__ fea2,
                                              const u8*  __restrict__ M2,
                                              const short* __restrict__ wTi4,
                                              const short* __restrict__ wTl4,
                                              short* __restrict__ u_out)
{
    const int H2 = 192, HW2 = H2*H2, H4 = 96, HW4 = H4*H4;
    int tY = blockIdx.x / 12, tX = blockIdx.x % 12, n = blockIdx.z;
    int y0 = tY*16, x0 = tX*16;
    int uy0 = (y0>>1) - 1, ux0 = (x0>>1) - 1;

    __shared__ __align__(16) short s_xs[2*100*36];
    __shared__ __align__(16) short s_ul[2*324*36];
    __shared__ u8 s_m[324];

    int tid = threadIdx.x;
    const short* xN = xs + (size_t)n*64*HW4;
    for (int i = tid; i < 64*100; i += 256){
        int c = i/100, r = i%100; int ly = r/10, lxx = r%10;
        int gy = uy0+ly, gx = ux0+lxx;
        short v = 0;
        if ((unsigned)gy < 96u && (unsigned)gx < 96u) v = xN[(size_t)c*HW4 + gy*H4 + gx];
        s_xs[(c>>5)*3600 + r*36 + (c&31)] = v;
    }
    for (int i = tid; i < 324; i += 256){
        int ry = i/18, rx = i%18; int gy = y0-1+ry, gx = x0-1+rx;
        s_m[i] = ((unsigned)gy < 192u && (unsigned)gx < 192u) ? M2[(size_t)n*HW2 + gy*H2 + gx] : 0;
    }
    __syncthreads();

    int wv = tid >> 6, lane = tid & 63;
    int nQ = lane >> 4, nn = lane & 15;

    for (int ui = wv; ui < 24; ui += 4){
        int cls = ui/6, nt = ui%6;
        int pY = cls >> 1, pX = cls & 1;
        int s0 = nt*16 + nn;
        int s = s0 > 80 ? 80 : s0;
        int jr = s/9, jc = s%9;
        int ry = 2*jr + pY, rx = 2*jc + pX;
        int gY = y0-1+ry, gX = x0-1+rx;

        int tiy[4], tix[4], twk[4]; int tapN;
        if (pY == 0){
            int iA = ((gY-1)>>1) - uy0, iB = ((gY+1)>>1) - uy0;
            if (pX == 0){
                int jA = ((gX-1)>>1) - ux0, jB = ((gX+1)>>1) - ux0;
                tiy[0]=iA; tix[0]=jA; twk[0]=8;
                tiy[1]=iA; tix[1]=jB; twk[1]=6;
                tiy[2]=iB; tix[2]=jA; twk[2]=2;
                tiy[3]=iB; tix[3]=jB; twk[3]=0; tapN=4;
            } else {
                int j = (gX>>1) - ux0;
                tiy[0]=iA; tix[0]=j; twk[0]=7;
                tiy[1]=iB; tix[1]=j; twk[1]=1; tapN=2;
            }
        } else {
            int i2 = (gY>>1) - uy0;
            if (pX == 0){
                int jA = ((gX-1)>>1) - ux0, jB = ((gX+1)>>1) - ux0;
                tiy[0]=i2; tix[0]=jA; twk[0]=5;
                tiy[1]=i2; tix[1]=jB; twk[1]=3; tapN=2;
            } else {
                tiy[0]=i2; tix[0]=(gX>>1)-ux0; twk[0]=4; tapN=1;
            }
        }

        f32x4 acc[4];
        #pragma unroll
        for (int g=0; g<4; ++g) acc[g] = (f32x4){0,0,0,0};
        for (int t = 0; t < tapN; ++t){
            int off = (tiy[t]*10 + tix[t])*36 + nQ*8;
            bf16x8 xlo = lds8(s_xs + off);
            bf16x8 xhi = lds8(s_xs + 3600 + off);
            const short* wk = wTi4 + twk[t]*4096;
            #pragma unroll
            for (int g=0; g<4; ++g){
                bf16x8 alo = *(const bf16x8*)(wk + (g*16+nn)*64 + nQ*8);
                bf16x8 ahi = *(const bf16x8*)(wk + (g*16+nn)*64 + 32 + nQ*8);
                acc[g] = MFMA_B16(alo, xlo, acc[g], 0,0,0);
                acc[g] = MFMA_B16(ahi, xhi, acc[g], 0,0,0);
            }
        }
        if (s0 <= 80){
            int sidx = ry*18 + rx;
            u8 m = s_m[sidx];
            #pragma unroll
            for (int g=0; g<4; ++g){
                float r[4];
                #pragma unroll
                for (int e=0; e<4; ++e){
                    float a = acc[g][e]*BNS;
                    r[e] = m ? (a > 0.f ? a : 0.2f*a) : 0.f;
                }
                bf16x4 w4 = {f2bs(r[0]),f2bs(r[1]),f2bs(r[2]),f2bs(r[3])};
                *(bf16x4*)(s_ul + (g>>1)*11664 + sidx*36 + (g&1)*16 + nQ*4) = w4;
            }
        }
    }
    __syncthreads();

    for (int nt = wv; nt < 16; nt += 4){
        int ty = nt, tx = nn;
        f32x4 acc0 = {0,0,0,0}, acc1 = {0,0,0,0};
        #pragma unroll
        for (int ky=0; ky<3; ++ky)
            #pragma unroll
            for (int kx=0; kx<3; ++kx){
                int k = ky*3+kx;
                int off = ((ty+ky)*18 + tx+kx)*36 + nQ*8;
                bf16x8 vlo = lds8(s_ul + off);
                bf16x8 vhi = lds8(s_ul + 11664 + off);
                const short* wk = wTl4 + k*2048;
                bf16x8 a0lo = *(const bf16x8*)(wk + nn*64 + nQ*8);
                bf16x8 a0hi = *(const bf16x8*)(wk + nn*64 + 32 + nQ*8);
                bf16x8 a1lo = *(const bf16x8*)(wk + (16+nn)*64 + nQ*8);
                bf16x8 a1hi = *(const bf16x8*)(wk + (16+nn)*64 + 32 + nQ*8);
                acc0 = MFMA_B16(a0lo, vlo, acc0, 0,0,0);
                acc0 = MFMA_B16(a0hi, vhi, acc0, 0,0,0);
                acc1 = MFMA_B16(a1lo, vlo, acc1, 0,0,0);
                acc1 = MFMA_B16(a1hi, vhi, acc1, 0,0,0);
            }
        int gy = y0+ty, gx = x0+tx;
        int p = gy*H2 + gx;
        u8 m = s_m[(ty+1)*18 + tx+1];
        const short* f2p = fea2 + (size_t)n*32*HW2 + p;
        short* up = u_out + (size_t)n*32*HW2 + p;
        #pragma unroll
        for (int g=0; g<2; ++g)
            #pragma unroll
            for (int e=0; e<4; ++e){
                int co = g*16 + nQ*4 + e;
                float a = g ? acc1[e] : acc0[e];
                float o = m ? a + s2f(f2p[(size_t)co*HW2]) : 0.f;
                up[(size_t)co*HW2] = f2bs(o);
            }
    }
}

// ---------------- MFMA back end v4: A-frags preloaded in registers ----------------
__global__ __launch_bounds__(256) void fk_back4(const short* __restrict__ u,
                                                const short* __restrict__ fea1,
                                                const u8*  __restrict__ M1,
                                                const short* __restrict__ wTi2,
                                                const short* __restrict__ wTl5,
                                                const short* __restrict__ wTr1a,
                                                const float* __restrict__ w_r1b,
                                                const float* __restrict__ r1_b2,
                                                float* __restrict__ out1)
{
    const int H1 = 384, HW1 = H1*H1, H2 = 192, HW2 = H2*H2;
    int tY = blockIdx.x / 24, tX = blockIdx.x % 24, n = blockIdx.z;
    int y0 = tY*16, x0 = tX*16;
    int uy0 = (y0>>1) - 2, ux0 = (x0>>1) - 2;

    __shared__ __align__(16) short sP0[484*36];
    __shared__ __align__(16) short sP1[400*36];
    __shared__ u8 s_m[484];
    short* s_u  = sP1;
    short* s_vl = sP0;
    short* s_v  = sP1;
    short* s_t1 = sP0;

    int tid = threadIdx.x;
    const short* uN = u + (size_t)n*32*HW2;
    for (int i = tid; i < 32*144; i += 256){
        int c = i/144, r = i%144; int ly = r/12, lxx = r%12;
        int gy = uy0+ly, gx = ux0+lxx;
        short v = 0;
        if ((unsigned)gy < 192u && (unsigned)gx < 192u) v = uN[(size_t)c*HW2 + gy*H2 + gx];
        s_u[r*36 + c] = v;
    }
    for (int i = tid; i < 484; i += 256){
        int ry = i/22, rx = i%22; int gy = y0-3+ry, gx = x0-3+rx;
        s_m[i] = ((unsigned)gy < 384u && (unsigned)gx < 384u) ? M1[(size_t)n*HW1 + gy*H1 + gx] : 0;
    }
    __syncthreads();

    int wv = tid >> 6, lane = tid & 63;
    int nQ = lane >> 4, nn = lane & 15;

    // ---- stage A: vl[484][32]; cls unrolled, frags preloaded per class ----
    #pragma unroll
    for (int cls = 0; cls < 4; ++cls){
        const int pY = cls >> 1, pX = cls & 1;
        const int WKc[4][4] = {{8,6,2,0},{7,1,0,0},{5,3,0,0},{4,0,0,0}};
        const int TAPN = (cls==0) ? 4 : (cls==3) ? 1 : 2;
        bf16x8 wf0[4], wf1[4];
        #pragma unroll
        for (int t=0; t<TAPN; ++t){
            wf0[t] = *(const bf16x8*)(wTi2 + WKc[cls][t]*1024 + nn*32 + nQ*8);
            wf1[t] = *(const bf16x8*)(wTi2 + WKc[cls][t]*1024 + (16+nn)*32 + nQ*8);
        }
        #pragma unroll
        for (int rep = 0; rep < 2; ++rep){
            int nt = rep*4 + wv;
            int s0 = nt*16 + nn;
            int s = s0 > 120 ? 120 : s0;
            int jr = s/11, jc = s%11;
            int ry = 2*jr + pY, rx = 2*jc + pX;
            int gY = y0-3+ry, gX = x0-3+rx;

            int offs[4];
            if (cls == 0){
                int iA = ((gY-1)>>1)-uy0, iB = ((gY+1)>>1)-uy0;
                int jA = ((gX-1)>>1)-ux0, jB = ((gX+1)>>1)-ux0;
                offs[0]=iA*12+jA; offs[1]=iA*12+jB; offs[2]=iB*12+jA; offs[3]=iB*12+jB;
            } else if (cls == 1){
                int iA = ((gY-1)>>1)-uy0, iB = ((gY+1)>>1)-uy0, j = (gX>>1)-ux0;
                offs[0]=iA*12+j; offs[1]=iB*12+j;
            } else if (cls == 2){
                int i2 = (gY>>1)-uy0, jA = ((gX-1)>>1)-ux0, jB = ((gX+1)>>1)-ux0;
                offs[0]=i2*12+jA; offs[1]=i2*12+jB;
            } else {
                offs[0]=((gY>>1)-uy0)*12 + (gX>>1)-ux0;
            }

            f32x4 acc0 = {0,0,0,0}, acc1 = {0,0,0,0};
            #pragma unroll
            for (int t = 0; t < TAPN; ++t){
                bf16x8 bfr = lds8(s_u + offs[t]*36 + nQ*8);
                acc0 = MFMA_B16(wf0[t], bfr, acc0, 0,0,0);
                acc1 = MFMA_B16(wf1[t], bfr, acc1, 0,0,0);
            }
            if (s0 <= 120){
                int sidx = ry*22 + rx;
                u8 m = s_m[sidx];
                float r[8];
                #pragma unroll
                for (int g=0; g<2; ++g)
                    #pragma unroll
                    for (int e=0; e<4; ++e){
                        float a = (g ? acc1[e] : acc0[e]) * BNS;
                        r[g*4+e] = m ? (a > 0.f ? a : 0.2f*a) : 0.f;
                    }
                bf16x4 w0 = {f2bs(r[0]),f2bs(r[1]),f2bs(r[2]),f2bs(r[3])};
                bf16x4 w1 = {f2bs(r[4]),f2bs(r[5]),f2bs(r[6]),f2bs(r[7])};
                *(bf16x4*)(s_vl + sidx*36 + nQ*4) = w0;
                *(bf16x4*)(s_vl + sidx*36 + 16 + nQ*4) = w1;
            }
        }
    }
    __syncthreads();

    // ---- stage B: v[400][32] = m ? conv(vl,l5) + fea1 : 0 ----
    {
        bf16x8 wb0[9], wb1[9];
        #pragma unroll
        for (int k=0;k<9;++k){
            wb0[k] = *(const bf16x8*)(wTl5 + k*1024 + nn*32 + nQ*8);
            wb1[k] = *(const bf16x8*)(wTl5 + k*1024 + (16+nn)*32 + nQ*8);
        }
        for (int nt = wv; nt < 25; nt += 4){
            int s0 = nt*16 + nn;
            int s = s0 > 399 ? 399 : s0;
            int vy = s/20, vx = s%20;
            f32x4 acc0 = {0,0,0,0}, acc1 = {0,0,0,0};
            #pragma unroll
            for (int ky=0; ky<3; ++ky)
                #pragma unroll
                for (int kx=0; kx<3; ++kx){
                    const int k = ky*3+kx;
                    bf16x8 bfr = lds8(s_vl + ((vy+ky)*22 + vx+kx)*36 + nQ*8);
                    acc0 = MFMA_B16(wb0[k], bfr, acc0, 0,0,0);
                    acc1 = MFMA_B16(wb1[k], bfr, acc1, 0,0,0);
                }
            if (s0 <= 399){
                u8 m = s_m[(vy+1)*22 + vx+1];
                int gY = y0-2+vy, gX = x0-2+vx;
                const short* f1 = fea1 + (size_t)n*32*HW1 + (size_t)gY*H1 + gX;
                float r[8];
                #pragma unroll
                for (int g=0; g<2; ++g)
                    #pragma unroll
                    for (int e=0; e<4; ++e){
                        int co = g*16 + nQ*4 + e;
                        float a = g ? acc1[e] : acc0[e];
                        r[g*4+e] = m ? a + s2f(f1[(size_t)co*HW1]) : 0.f;
                    }
                bf16x4 w0 = {f2bs(r[0]),f2bs(r[1]),f2bs(r[2]),f2bs(r[3])};
                bf16x4 w1 = {f2bs(r[4]),f2bs(r[5]),f2bs(r[6]),f2bs(r[7])};
                *(bf16x4*)(s_v + s*36 + nQ*4) = w0;
                *(bf16x4*)(s_v + s*36 + 16 + nQ*4) = w1;
            }
        }
    }
    __syncthreads();

    // ---- stage C: t1[324][32] = m ? leaky(conv(v,r1a)*BNS) : 0 ----
    {
        bf16x8 wc0[9], wc1[9];
        #pragma unroll
        for (int k=0;k<9;++k){
            wc0[k] = *(const bf16x8*)(wTr1a + k*1024 + nn*32 + nQ*8);
            wc1[k] = *(const bf16x8*)(wTr1a + k*1024 + (16+nn)*32 + nQ*8);
        }
        for (int nt = wv; nt < 21; nt += 4){
            int s0 = nt*16 + nn;
            int s = s0 > 323 ? 323 : s0;
            int qy = s/18, qx = s%18;
            f32x4 acc0 = {0,0,0,0}, acc1 = {0,0,0,0};
            #pragma unroll
            for (int ky=0; ky<3; ++ky)
                #pragma unroll
                for (int kx=0; kx<3; ++kx){
                    const int k = ky*3+kx;
                    bf16x8 bfr = lds8(s_v + ((qy+ky)*20 + qx+kx)*36 + nQ*8);
                    acc0 = MFMA_B16(wc0[k], bfr, acc0, 0,0,0);
                    acc1 = MFMA_B16(wc1[k], bfr, acc1, 0,0,0);
                }
            if (s0 <= 323){
                u8 m = s_m[(qy+2)*22 + qx+2];
                float r[8];
                #pragma unroll
                for (int g=0; g<2; ++g)
                    #pragma unroll
                    for (int e=0; e<4; ++e){
                        float a = (g ? acc1[e] : acc0[e]) * BNS;
                        r[g*4+e] = m ? (a > 0.f ? a : 0.2f*a) : 0.f;
                    }
                bf16x4 w0 = {f2bs(r[0]),f2bs(r[1]),f2bs(r[2]),f2bs(r[3])};
                bf16x4 w1 = {f2bs(r[4]),f2bs(r[5]),f2bs(r[6]),f2bs(r[7])};
                *(bf16x4*)(s_t1 + s*36 + nQ*4) = w0;
                *(bf16x4*)(s_t1 + s*36 + 16 + nQ*4) = w1;
            }
        }
    }
    __syncthreads();

    // ---- stage D ----
    int ty = tid >> 4, tx = tid & 15;
    u8 m = s_m[(ty+3)*22 + tx+3];
    float o = -99.f;
    if (m){
        float acc = 0.f;
        #pragma unroll
        for (int k = 0; k < 9; ++k){
            const short* tp = s_t1 + ((ty + k/3)*18 + tx + k%3)*36;
            for (int ci = 0; ci < 32; ++ci)
                acc += s2f(tp[ci]) * w_r1b[ci*9 + k];
        }
        o = acc + r1_b2[0];
    }
    out1[(size_t)n*HW1 + (y0+ty)*H1 + (x0+tx)] = o;
}

// ---------------- launch ----------------

extern "C" void kernel_launch(void* const* d_in, const int* in_sizes, int n_in,
                              void* d_out, int out_size, void* d_ws, size_t ws_size,
                              hipStream_t stream)
{
    const float* x      = (const float*)d_in[0];
    const float* image  = (const float*)d_in[1];
    const float* masks  = (const float*)d_in[2];
    const float* roi    = (const float*)d_in[3];
    const float* w1a    = (const float*)d_in[4];
    const float* w1b    = (const float*)d_in[5];
    const float* w2a    = (const float*)d_in[6];
    const float* w2b    = (const float*)d_in[7];
    const float* w4a    = (const float*)d_in[8];
    const float* w4b    = (const float*)d_in[9];
    const float* inv4_w = (const float*)d_in[10];
    const float* l4_sub = (const float*)d_in[11];
    const float* inv2_w = (const float*)d_in[12];
    const float* l5_sub = (const float*)d_in[13];
    const float* r4_w1  = (const float*)d_in[14];
    const float* r4_w2  = (const float*)d_in[15];
    const float* r4_b2  = (const float*)d_in[16];
    const float* r1_w1  = (const float*)d_in[17];
    const float* r1_w2  = (const float*)d_in[18];
    const float* r1_b2  = (const float*)d_in[19];
    float* out = (float*)d_out;

    const int N = 8;
    const int H1 = 384, HW1 = 384*384;
    const int H2 = 192, HW2 = 192*192;
    const int H4 = 96,  HW4 = 96*96;

    char* wsp = (char*)d_ws;
    size_t off = 0;
    auto alloc = [&](size_t bytes) -> char* {
        char* p = wsp + off;
        off += (bytes + 255) & ~(size_t)255;
        return p;
    };
    bf16* FEA1 = (bf16*)alloc((size_t)N*32*HW1*2);
    u8*   M1   = (u8*)alloc((size_t)N*HW1);
    u8*   M2   = (u8*)alloc((size_t)N*HW2);
    u8*   M4   = (u8*)alloc((size_t)N*HW4);
    bf16* FEA2 = (bf16*)alloc((size_t)N*32*HW2*2);
    bf16* XS   = (bf16*)alloc((size_t)N*64*HW4*2);
    bf16* GU   = (bf16*)alloc((size_t)N*32*HW2*2);  // g, then u
    bf16* HT   = (bf16*)alloc((size_t)N*64*HW4*2);  // h, then t_leaky
    short* WT  = (short*)alloc(5*9216*2);           // [w1bT, inv2T, l5T, r1aT, w2bT]
    short* WT4 = (short*)alloc((size_t)110592*2);   // [inv4T, w4bT, l4sT, r4w1T]
    (void)ws_size; (void)in_sizes; (void)n_in; (void)out_size;

    short* wT1b  = WT;
    short* wTi2  = WT + 9216;
    short* wTl5  = WT + 2*9216;
    short* wTr1a = WT + 3*9216;
    short* wT2b  = WT + 4*9216;
    short* wTi4  = WT4;
    short* wT4b  = WT4 + 36864;
    short* wTl4  = WT4 + 73728;
    short* wTr4a = WT4 + 92160;

    dim3 blk(256);

    // masks + weight prep
    k_mask1<<<dim3((N*HW1 + 255)/256), blk, 0, stream>>>(roi, M1, N*HW1);
    k_down<<<dim3((HW2 + 255)/256, N), blk, 0, stream>>>(M1, M2, H1, H1, H2, H2);
    k_down<<<dim3((HW4 + 255)/256, N), blk, 0, stream>>>(M2, M4, H2, H2, H4, H4);
    k_wprep<<<dim3(36, 5), blk, 0, stream>>>(w1b, inv2_w, l5_sub, r1_w1, w2b, WT);
    k_wprep4<<<dim3(144, 4), blk, 0, stream>>>(inv4_w, w4b, l4_sub, r4_w1, WT4);

    // front
    conv1ab2<<<dim3(576, 1, N), blk, 0, stream>>>(image, masks, M1, w1a, wT1b, (short*)FEA1);
    conv_s2<32,32,32><<<dim3(144, 1, N), blk, 0, stream>>>(FEA1, H1, H1, w2a, M2, GU, H2, H2, 12);
    mconv_s1<32,32,0><<<dim3(144, 1, N), blk, 0, stream>>>((const short*)GU, H2, wT2b, M2, nullptr, (short*)FEA2, 12);
    conv_s2<32,32,64><<<dim3(36, 2, N), blk, 0, stream>>>(FEA2, H2, H2, w4a, M4, HT, H4, H4, 6);
    mconv_s1<64,64,3><<<dim3(36, 1, N), blk, 0, stream>>>((const short*)HT, H4, wT4b, M4, x, (short*)XS, 6);

    // refine_OS4
    mconv_s1<64,32,1><<<dim3(36, 1, N), blk, 0, stream>>>((const short*)XS, H4, wTr4a, M4, nullptr, (short*)HT, 6);
    conv3x3_head<32><<<dim3(36, 1, N), blk, 0, stream>>>(HT, H4, H4, r4_w2, r4_b2, M4, out);

    // layer4 fused (MFMA) -> u
    fk_l4c<<<dim3(144, 1, N), blk, 0, stream>>>((const short*)XS, (const short*)FEA2, M2,
                                                wTi4, wTl4, (short*)GU);

    // MFMA back end -> out1
    fk_back4<<<dim3(576, 1, N), blk, 0, stream>>>((const short*)GU, (const short*)FEA1, M1,
                                                  wTi2, wTl5, wTr1a, r1_w2, r1_b2,
                                                  out + (size_t)N*HW4);
}

// Round 9
// 1133.463 us; speedup vs baseline: 19.3919x; 1.3831x over previous
//
#include <hip/hip_runtime.h>
#include <hip/hip_bf16.h>

using bf16 = __hip_bfloat16;
typedef unsigned char u8;
typedef short bf16x8 __attribute__((ext_vector_type(8)));
typedef short bf16x4 __attribute__((ext_vector_type(4)));
typedef float f32x4 __attribute__((ext_vector_type(4)));

#define BNS 0.9999950000374997f   // 1/sqrt(1+1e-5)
#define MFMA_B16 __builtin_amdgcn_mfma_f32_16x16x32_bf16

__device__ __forceinline__ float b2f(bf16 v){ return __bfloat162float(v); }
__device__ __forceinline__ short f2bs(float v){ bf16 h = __float2bfloat16(v); return *reinterpret_cast<short*>(&h); }
__device__ __forceinline__ float s2f(short s){ union{unsigned u; float f;} x; x.u = ((unsigned)(unsigned short)s) << 16; return x.f; }

__device__ __forceinline__ bf16x8 lds8(const short* p){
    bf16x4 lo = *(const bf16x4*)(p);
    bf16x4 hi = *(const bf16x4*)(p + 4);
    bf16x8 r = {lo[0],lo[1],lo[2],lo[3],hi[0],hi[1],hi[2],hi[3]};
    return r;
}

// ---------------- mask kernels ----------------

__global__ __launch_bounds__(256) void k_mask1(const float* __restrict__ roi, u8* __restrict__ m1, int total){
    int i = blockIdx.x*256 + threadIdx.x;
    if (i < total) m1[i] = (roi[i] > 0.8f) ? 1 : 0;
}

__global__ __launch_bounds__(256) void k_down(const u8* __restrict__ mi, u8* __restrict__ mo,
                                              int IH, int IW, int OH, int OW){
    int p = blockIdx.x*256 + threadIdx.x;
    int n = blockIdx.y;
    if (p >= OH*OW) return;
    int oy = p / OW, ox = p - oy*OW;
    const u8* src = mi + (size_t)n*IH*IW;
    int v = 0;
    #pragma unroll
    for (int ky=0; ky<3; ky++){
        int iy = 2*oy + ky - 1;
        if ((unsigned)iy >= (unsigned)IH) continue;
        #pragma unroll
        for (int kx=0; kx<3; kx++){
            int ix = 2*ox + kx - 1;
            if ((unsigned)ix < (unsigned)IW) v |= src[iy*IW + ix];
        }
    }
    mo[(size_t)n*OH*OW + p] = (u8)v;
}

// ---- weight prep: 6 arrays [32][32][9] fp32 -> bf16 [9][32co][32ci] ----
__global__ __launch_bounds__(256) void k_wprep(const float* __restrict__ w1b,
                                               const float* __restrict__ i2,
                                               const float* __restrict__ l5,
                                               const float* __restrict__ r1a,
                                               const float* __restrict__ w2b,
                                               const float* __restrict__ w2a,
                                               short* __restrict__ dst){
    int a = blockIdx.y;
    const float* src = (a==0)? w1b : (a==1)? i2 : (a==2)? l5 : (a==3)? r1a : (a==4)? w2b : w2a;
    int j = blockIdx.x*256 + threadIdx.x;
    if (j < 9216){
        int co = j/288, r = j%288, ci = r/9, k = r%9;
        dst[a*9216 + k*1024 + co*32 + ci] = f2bs(src[j]);
    }
}

// ---- weight prep 64-wide: inv4 @0 [9][64][64]; w4b @36864 same;
//      l4_sub @73728 [9][32][64]; r4_w1 @92160 same; w4a @110592 [9][64co][32ci] ----
__global__ __launch_bounds__(256) void k_wprep4(const float* __restrict__ inv4,
                                                const float* __restrict__ w4b,
                                                const float* __restrict__ l4s,
                                                const float* __restrict__ r4w1,
                                                const float* __restrict__ w4a,
                                                short* __restrict__ dst)
{
    int a = blockIdx.y;
    int j = blockIdx.x*256 + threadIdx.x;
    if (a < 2){
        if (j < 36864){
            int co = j/576, r = j%576, ci = r/9, k = r%9;
            const float* s = a ? w4b : inv4;
            dst[a*36864 + k*4096 + co*64 + ci] = f2bs(s[j]);
        }
    } else if (a < 4){
        if (j < 18432){
            int co = j/576, r = j%576, ci = r/9, k = r%9;
            const float* s = (a==2) ? l4s : r4w1;
            dst[73728 + (a-2)*18432 + k*2048 + co*64 + ci] = f2bs(s[j]);
        }
    } else {
        if (j < 18432){
            int co = j/288, r = j%288, ci = r/9, k = r%9;
            dst[110592 + k*2048 + co*32 + ci] = f2bs(w4a[j]);
        }
    }
}

// ---- w1a im2col prep: [32co][4ci][9k] -> [2Kh][32co][32kq], K=ci*9+k, zero-pad 36..63 ----
__global__ __launch_bounds__(256) void k_wprep1a(const float* __restrict__ w1a, short* __restrict__ dst){
    int j = blockIdx.x*256 + threadIdx.x;
    if (j < 2048){
        int h = j >> 10, r = j & 1023, co = r >> 5, kq = r & 31;
        int q = h*32 + kq;
        dst[j] = (q < 36) ? f2bs(w1a[co*36 + q]) : 0;
    }
}

// ---------------- COUT=1 head (refine_OS4 second conv) ----------------
template<int CIN>
__global__ __launch_bounds__(256) void conv3x3_head(const bf16* __restrict__ in, int IH, int IW,
                                                    const float* __restrict__ w,
                                                    const float* __restrict__ wb,
                                                    const u8*   __restrict__ mask,
                                                    float* __restrict__ out)
{
    __shared__ float ws[CIN*9];
    int n = blockIdx.z;
    for (int i = threadIdx.x; i < CIN*9; i += blockDim.x) ws[i] = w[i];
    __syncthreads();

    int p = blockIdx.x*blockDim.x + threadIdx.x;
    if (p >= IH*IW) return;
    int oy = p / IW, ox = p - oy*IW;

    float acc = 0.f;
    const bf16* ibase = in + (size_t)n*CIN*IH*IW;
    for (int c = 0; c < CIN; ++c) {
        const bf16* ic = ibase + (size_t)c*IH*IW;
        const float* wc = ws + c*9;
        #pragma unroll
        for (int ky = 0; ky < 3; ++ky) {
            int iy = oy-1+ky;
            if ((unsigned)iy >= (unsigned)IH) continue;
            const bf16* irow = ic + (size_t)iy*IW;
            #pragma unroll
            for (int kx = 0; kx < 3; ++kx) {
                int ix = ox-1+kx;
                if ((unsigned)ix < (unsigned)IW)
                    acc += b2f(irow[ix]) * wc[ky*3 + kx];
            }
        }
    }
    bool m = mask[(size_t)n*IH*IW + p] != 0;
    out[(size_t)n*IH*IW + p] = m ? acc + wb[0] : -99.f;
}

// ---------------- generic MFMA stride-1 conv (unchanged, proven) ----------------
template<int CIN, int COUT, int EPI>
__global__ __launch_bounds__(256) void mconv_s1(const short* __restrict__ in, int H,
                                                const short* __restrict__ wT,
                                                const u8* __restrict__ mask,
                                                const float* __restrict__ res32,
                                                short* __restrict__ out, int tilesX)
{
    const int HW = H*H;
    const int HV = CIN/32, G = COUT/16;
    int tY = blockIdx.x / tilesX, tX = blockIdx.x % tilesX, n = blockIdx.z;
    int y0 = tY*16, x0 = tX*16;

    __shared__ __align__(16) short s_in[HV*11664];
    __shared__ u8 s_m[256];

    int tid = threadIdx.x;
    const short* inN = in + (size_t)n*CIN*HW;
    for (int i = tid; i < CIN*324; i += 256){
        int c = i/324, r = i%324;
        int ry = r/18, rx = r%18;
        int gy = y0-1+ry, gx = x0-1+rx;
        short v = 0;
        if ((unsigned)gy < (unsigned)H && (unsigned)gx < (unsigned)H)
            v = inN[(size_t)c*HW + gy*H + gx];
        s_in[(c>>5)*11664 + r*36 + (c&31)] = v;
    }
    for (int i = tid; i < 256; i += 256){
        int ty = i>>4, tx = i&15;
        s_m[i] = mask[(size_t)n*HW + (y0+ty)*H + x0+tx];
    }
    __syncthreads();

    int wv = tid >> 6, lane = tid & 63;
    int nQ = lane >> 4, nn = lane & 15;

    bf16x8 wa0[9], wa1[9];
    if constexpr (CIN == 32 && COUT == 32){
        #pragma unroll
        for (int k=0;k<9;++k){
            wa0[k] = *(const bf16x8*)(wT + k*1024 + nn*32 + nQ*8);
            wa1[k] = *(const bf16x8*)(wT + k*1024 + (16+nn)*32 + nQ*8);
        }
    }

    for (int nt = wv; nt < 16; nt += 4){
        int ty = nt, tx = nn;
        f32x4 acc[G];
        #pragma unroll
        for (int g=0;g<G;++g) acc[g] = (f32x4){0,0,0,0};
        #pragma unroll
        for (int ky=0; ky<3; ++ky)
            #pragma unroll
            for (int kx=0; kx<3; ++kx){
                const int k = ky*3+kx;
                #pragma unroll
                for (int h=0; h<HV; ++h){
                    bf16x8 bfr = lds8(s_in + h*11664 + ((ty+ky)*18 + tx+kx)*36 + nQ*8);
                    #pragma unroll
                    for (int g=0; g<G; ++g){
                        bf16x8 a;
                        if constexpr (CIN == 32 && COUT == 32) a = g ? wa1[k] : wa0[k];
                        else a = *(const bf16x8*)(wT + k*COUT*CIN + (g*16+nn)*CIN + h*32 + nQ*8);
                        acc[g] = MFMA_B16(a, bfr, acc[g], 0,0,0);
                    }
                }
            }
        int p = (y0+ty)*H + x0+tx;
        u8 m = s_m[nt*16 + nn];
        short* op = out + (size_t)n*COUT*HW + p;
        #pragma unroll
        for (int g=0; g<G; ++g)
            #pragma unroll
            for (int e=0; e<4; ++e){
                int co = g*16 + nQ*4 + e;
                float a = acc[g][e], o;
                if      (EPI == 0) o = m ? fmaxf(a,0.f)*BNS : 0.f;
                else if (EPI == 1){ float s = a*BNS; o = m ? (s>0.f ? s : 0.2f*s) : 0.f; }
                else o = m ? fmaxf(a,0.f)*BNS + res32[((size_t)(n>>2)*COUT + co)*(size_t)HW + p] : 0.f;
                op[(size_t)co*HW] = f2bs(o);
            }
    }
}

// ---------------- MFMA stride-2 conv: tile 8(y) x 16(x), CIN=32 ----------------
template<int COUT>
__global__ __launch_bounds__(256) void mconv_s2m(const short* __restrict__ in, int IH,
                                                 const short* __restrict__ wT,   // [9][COUT][32]
                                                 const u8* __restrict__ mask,
                                                 short* __restrict__ out, int OH, int tilesX)
{
    const int IHW = IH*IH, OHW = OH*OH, G = COUT/16;
    int tY = blockIdx.x / tilesX, tX = blockIdx.x % tilesX, n = blockIdx.z;
    int y0 = tY*8, x0 = tX*16;

    __shared__ __align__(16) short s_in[561*36];   // 17x33 input sites x 32ci
    __shared__ u8 s_m[128];

    int tid = threadIdx.x;
    const short* inN = in + (size_t)n*32*IHW;
    for (int i = tid; i < 32*561; i += 256){
        int c = i/561, r = i%561;
        int ry = r/33, rx = r%33;
        int gy = 2*y0-1+ry, gx = 2*x0-1+rx;
        short v = 0;
        if ((unsigned)gy < (unsigned)IH && (unsigned)gx < (unsigned)IH)
            v = inN[(size_t)c*IHW + gy*IH + gx];
        s_in[r*36 + c] = v;
    }
    for (int i = tid; i < 128; i += 256){
        int ty = i>>4, tx = i&15;
        s_m[i] = mask[(size_t)n*OHW + (y0+ty)*OH + x0+tx];
    }
    __syncthreads();

    int wv = tid >> 6, lane = tid & 63;
    int nQ = lane >> 4, nn = lane & 15;

    for (int nt = wv; nt < 8; nt += 4){
        int ty = nt, tx = nn;
        f32x4 acc[G];
        #pragma unroll
        for (int g=0;g<G;++g) acc[g] = (f32x4){0,0,0,0};
        #pragma unroll
        for (int ky=0; ky<3; ++ky)
            #pragma unroll
            for (int kx=0; kx<3; ++kx){
                const int k = ky*3+kx;
                bf16x8 bfr = lds8(s_in + ((2*ty+ky)*33 + 2*tx+kx)*36 + nQ*8);
                #pragma unroll
                for (int g=0; g<G; ++g){
                    bf16x8 a = *(const bf16x8*)(wT + k*COUT*32 + (g*16+nn)*32 + nQ*8);
                    acc[g] = MFMA_B16(a, bfr, acc[g], 0,0,0);
                }
            }
        int p = (y0+ty)*OH + x0+tx;
        u8 m = s_m[nt*16 + nn];
        short* op = out + (size_t)n*COUT*OHW + p;
        #pragma unroll
        for (int g=0; g<G; ++g)
            #pragma unroll
            for (int e=0; e<4; ++e){
                int co = g*16 + nQ*4 + e;
                float o = m ? fmaxf(acc[g][e],0.f)*BNS : 0.f;
                op[(size_t)co*OHW] = f2bs(o);
            }
    }
}

// ---------------- conv1ab v4: im2col MFMA f-stage + MFMA stage-2; tile 16x8 ----------
__global__ __launch_bounds__(256) void conv1ab3(const float* __restrict__ image,
                                                const float* __restrict__ masks,
                                                const u8*  __restrict__ M1,
                                                const short* __restrict__ wT1a,   // [2][32co][32K]
                                                const short* __restrict__ wT1b,   // [9][32co][32ci]
                                                short* __restrict__ fea1)
{
    const int H = 384; const int HW = H*H;
    int tY = blockIdx.x / 48, tX = blockIdx.x % 48, n = blockIdx.z;
    int y0 = tY*16, x0 = tX*8;

    __shared__ float s_inp[4][240];               // 20 rows x 12 cols, masked fp32
    __shared__ u8    s_m[240];
    __shared__ __align__(16) short s_ic[180*72];  // im2col [180 f-sites][64K pad72]; later aliased by s_f[180*36]
    short* s_f = s_ic;

    int tid = threadIdx.x;
    for (int i = tid; i < 240; i += 256){
        int ly = i/12, lxx = i%12;
        int gy = y0-2+ly, gx = x0-2+lxx;
        bool inb = ((unsigned)gy < 384u) && ((unsigned)gx < 384u);
        u8 mv = inb ? M1[(size_t)n*HW + gy*H + gx] : 0;
        s_m[i] = mv;
        float mm = (float)mv;
        int p = gy*H + gx;
        #pragma unroll
        for (int c = 0; c < 4; ++c){
            float v = 0.f;
            if (inb) v = (c < 3) ? image[((size_t)(n>>2)*3 + c)*HW + p]
                                 : masks[(size_t)n*HW + p];
            s_inp[c][i] = v*mm;
        }
    }
    __syncthreads();

    // im2col build: f sites 18x10 (origin y0-1,x0-1); site=fy*10+fx; K=ci*9+k, pad to 64
    for (int i = tid; i < 180*64; i += 256){
        int site = i >> 6, q = i & 63;
        short v = 0;
        if (q < 36){
            int ci = q/9, k = q - ci*9, ky = k/3, kx = k - ky*3;
            int fy = site/10, fx = site - fy*10;
            v = f2bs(s_inp[ci][(fy+ky)*12 + fx+kx]);
        }
        s_ic[site*72 + q] = v;
    }
    __syncthreads();

    int wv = tid >> 6, lane = tid & 63;
    int nQ = lane >> 4, nn = lane & 15;

    // f-MFMA: 12 units of 16 sites (180, cap 179); results held in regs
    f32x4 fr[3][2];
    {
        bf16x8 fa0[2], fa1[2];
        #pragma unroll
        for (int h=0;h<2;++h){
            fa0[h] = *(const bf16x8*)(wT1a + h*1024 + nn*32 + nQ*8);
            fa1[h] = *(const bf16x8*)(wT1a + h*1024 + (16+nn)*32 + nQ*8);
        }
        #pragma unroll
        for (int u=0; u<3; ++u){
            int nt = u*4 + wv;
            int s0 = nt*16 + nn;
            int s = s0 > 179 ? 179 : s0;
            f32x4 a0 = {0,0,0,0}, a1 = {0,0,0,0};
            #pragma unroll
            for (int h=0;h<2;++h){
                bf16x8 bfr = lds8(s_ic + s*72 + h*32 + nQ*8);
                a0 = MFMA_B16(fa0[h], bfr, a0, 0,0,0);
                a1 = MFMA_B16(fa1[h], bfr, a1, 0,0,0);
            }
            fr[u][0] = a0; fr[u][1] = a1;
        }
    }
    __syncthreads();   // all im2col reads done; region now reused as s_f

    #pragma unroll
    for (int u=0; u<3; ++u){
        int nt = u*4 + wv;
        int s0 = nt*16 + nn;
        if (s0 <= 179){
            int fy = s0/10, fx = s0 - fy*10;
            u8 m = s_m[(fy+1)*12 + fx+1];
            #pragma unroll
            for (int g=0; g<2; ++g){
                float r[4];
                #pragma unroll
                for (int e=0; e<4; ++e){
                    float a = fr[u][g][e];
                    r[e] = m ? fmaxf(a,0.f)*BNS : 0.f;
                }
                bf16x4 w4 = {f2bs(r[0]),f2bs(r[1]),f2bs(r[2]),f2bs(r[3])};
                *(bf16x4*)(s_f + s0*36 + g*16 + nQ*4) = w4;
            }
        }
    }
    __syncthreads();

    // stage 2: fea1 16x8 = 128 sites, 8 units
    bf16x8 wa0[9], wa1[9];
    #pragma unroll
    for (int k=0;k<9;++k){
        wa0[k] = *(const bf16x8*)(wT1b + k*1024 + nn*32 + nQ*8);
        wa1[k] = *(const bf16x8*)(wT1b + k*1024 + (16+nn)*32 + nQ*8);
    }
    for (int nt = wv; nt < 8; nt += 4){
        int s0 = nt*16 + nn;
        int ty = s0 >> 3, tx = s0 & 7;
        f32x4 acc0 = {0,0,0,0}, acc1 = {0,0,0,0};
        #pragma unroll
        for (int ky=0; ky<3; ++ky)
            #pragma unroll
            for (int kx=0; kx<3; ++kx){
                const int k = ky*3+kx;
                bf16x8 bfr = lds8(s_f + ((ty+ky)*10 + tx+kx)*36 + nQ*8);
                acc0 = MFMA_B16(wa0[k], bfr, acc0, 0,0,0);
                acc1 = MFMA_B16(wa1[k], bfr, acc1, 0,0,0);
            }
        u8 m = s_m[(ty+2)*12 + tx+2];
        short* fp = fea1 + (size_t)n*32*HW + (y0+ty)*H + x0+tx;
        #pragma unroll
        for (int g=0; g<2; ++g)
            #pragma unroll
            for (int e=0; e<4; ++e){
                int co = g*16 + nQ*4 + e;
                float a = g ? acc1[e] : acc0[e];
                float o = m ? fmaxf(a,0.f)*BNS : 0.f;
                fp[(size_t)co*HW] = f2bs(o);
            }
    }
}

// ---------------- MFMA layer4 (unchanged, proven) ----------------
__global__ __launch_bounds__(256) void fk_l4c(const short* __restrict__ xs,
                                              const short* __restrict__ fea2,
                                              const u8*  __restrict__ M2,
                                              const short* __restrict__ wTi4,
                                              const short* __restrict__ wTl4,
                                              short* __restrict__ u_out)
{
    const int H2 = 192, HW2 = H2*H2, H4 = 96, HW4 = H4*H4;
    int tY = blockIdx.x / 12, tX = blockIdx.x % 12, n = blockIdx.z;
    int y0 = tY*16, x0 = tX*16;
    int uy0 = (y0>>1) - 1, ux0 = (x0>>1) - 1;

    __shared__ __align__(16) short s_xs[2*100*36];
    __shared__ __align__(16) short s_ul[2*324*36];
    __shared__ u8 s_m[324];

    int tid = threadIdx.x;
    const short* xN = xs + (size_t)n*64*HW4;
    for (int i = tid; i < 64*100; i += 256){
        int c = i/100, r = i%100; int ly = r/10, lxx = r%10;
        int gy = uy0+ly, gx = ux0+lxx;
        short v = 0;
        if ((unsigned)gy < 96u && (unsigned)gx < 96u) v = xN[(size_t)c*HW4 + gy*H4 + gx];
        s_xs[(c>>5)*3600 + r*36 + (c&31)] = v;
    }
    for (int i = tid; i < 324; i += 256){
        int ry = i/18, rx = i%18; int gy = y0-1+ry, gx = x0-1+rx;
        s_m[i] = ((unsigned)gy < 192u && (unsigned)gx < 192u) ? M2[(size_t)n*HW2 + gy*H2 + gx] : 0;
    }
    __syncthreads();

    int wv = tid >> 6, lane = tid & 63;
    int nQ = lane >> 4, nn = lane & 15;

    for (int ui = wv; ui < 24; ui += 4){
        int cls = ui/6, nt = ui%6;
        int pY = cls >> 1, pX = cls & 1;
        int s0 = nt*16 + nn;
        int s = s0 > 80 ? 80 : s0;
        int jr = s/9, jc = s%9;
        int ry = 2*jr + pY, rx = 2*jc + pX;
        int gY = y0-1+ry, gX = x0-1+rx;

        int tiy[4], tix[4], twk[4]; int tapN;
        if (pY == 0){
            int iA = ((gY-1)>>1) - uy0, iB = ((gY+1)>>1) - uy0;
            if (pX == 0){
                int jA = ((gX-1)>>1) - ux0, jB = ((gX+1)>>1) - ux0;
                tiy[0]=iA; tix[0]=jA; twk[0]=8;
                tiy[1]=iA; tix[1]=jB; twk[1]=6;
                tiy[2]=iB; tix[2]=jA; twk[2]=2;
                tiy[3]=iB; tix[3]=jB; twk[3]=0; tapN=4;
            } else {
                int j = (gX>>1) - ux0;
                tiy[0]=iA; tix[0]=j; twk[0]=7;
                tiy[1]=iB; tix[1]=j; twk[1]=1; tapN=2;
            }
        } else {
            int i2 = (gY>>1) - uy0;
            if (pX == 0){
                int jA = ((gX-1)>>1) - ux0, jB = ((gX+1)>>1) - ux0;
                tiy[0]=i2; tix[0]=jA; twk[0]=5;
                tiy[1]=i2; tix[1]=jB; twk[1]=3; tapN=2;
            } else {
                tiy[0]=i2; tix[0]=(gX>>1)-ux0; twk[0]=4; tapN=1;
            }
        }

        f32x4 acc[4];
        #pragma unroll
        for (int g=0; g<4; ++g) acc[g] = (f32x4){0,0,0,0};
        for (int t = 0; t < tapN; ++t){
            int off = (tiy[t]*10 + tix[t])*36 + nQ*8;
            bf16x8 xlo = lds8(s_xs + off);
            bf16x8 xhi = lds8(s_xs + 3600 + off);
            const short* wk = wTi4 + twk[t]*4096;
            #pragma unroll
            for (int g=0; g<4; ++g){
                bf16x8 alo = *(const bf16x8*)(wk + (g*16+nn)*64 + nQ*8);
                bf16x8 ahi = *(const bf16x8*)(wk + (g*16+nn)*64 + 32 + nQ*8);
                acc[g] = MFMA_B16(alo, xlo, acc[g], 0,0,0);
                acc[g] = MFMA_B16(ahi, xhi, acc[g], 0,0,0);
            }
        }
        if (s0 <= 80){
            int sidx = ry*18 + rx;
            u8 m = s_m[sidx];
            #pragma unroll
            for (int g=0; g<4; ++g){
                float r[4];
                #pragma unroll
                for (int e=0; e<4; ++e){
                    float a = acc[g][e]*BNS;
                    r[e] = m ? (a > 0.f ? a : 0.2f*a) : 0.f;
                }
                bf16x4 w4 = {f2bs(r[0]),f2bs(r[1]),f2bs(r[2]),f2bs(r[3])};
                *(bf16x4*)(s_ul + (g>>1)*11664 + sidx*36 + (g&1)*16 + nQ*4) = w4;
            }
        }
    }
    __syncthreads();

    for (int nt = wv; nt < 16; nt += 4){
        int ty = nt, tx = nn;
        f32x4 acc0 = {0,0,0,0}, acc1 = {0,0,0,0};
        #pragma unroll
        for (int ky=0; ky<3; ++ky)
            #pragma unroll
            for (int kx=0; kx<3; ++kx){
                int k = ky*3+kx;
                int off = ((ty+ky)*18 + tx+kx)*36 + nQ*8;
                bf16x8 vlo = lds8(s_ul + off);
                bf16x8 vhi = lds8(s_ul + 11664 + off);
                const short* wk = wTl4 + k*2048;
                bf16x8 a0lo = *(const bf16x8*)(wk + nn*64 + nQ*8);
                bf16x8 a0hi = *(const bf16x8*)(wk + nn*64 + 32 + nQ*8);
                bf16x8 a1lo = *(const bf16x8*)(wk + (16+nn)*64 + nQ*8);
                bf16x8 a1hi = *(const bf16x8*)(wk + (16+nn)*64 + 32 + nQ*8);
                acc0 = MFMA_B16(a0lo, vlo, acc0, 0,0,0);
                acc0 = MFMA_B16(a0hi, vhi, acc0, 0,0,0);
                acc1 = MFMA_B16(a1lo, vlo, acc1, 0,0,0);
                acc1 = MFMA_B16(a1hi, vhi, acc1, 0,0,0);
            }
        int gy = y0+ty, gx = x0+tx;
        int p = gy*H2 + gx;
        u8 m = s_m[(ty+1)*18 + tx+1];
        const short* f2p = fea2 + (size_t)n*32*HW2 + p;
        short* up = u_out + (size_t)n*32*HW2 + p;
        #pragma unroll
        for (int g=0; g<2; ++g)
            #pragma unroll
            for (int e=0; e<4; ++e){
                int co = g*16 + nQ*4 + e;
                float a = g ? acc1[e] : acc0[e];
                float o = m ? a + s2f(f2p[(size_t)co*HW2]) : 0.f;
                up[(size_t)co*HW2] = f2bs(o);
            }
    }
}

// ---------------- MFMA back end v5: 16x8 tile for 4 blocks/CU ----------------
__global__ __launch_bounds__(256) void fk_back5(const short* __restrict__ u,
                                                const short* __restrict__ fea1,
                                                const u8*  __restrict__ M1,
                                                const short* __restrict__ wTi2,
                                                const short* __restrict__ wTl5,
                                                const short* __restrict__ wTr1a,
                                                const float* __restrict__ w_r1b,
                                                const float* __restrict__ r1_b2,
                                                float* __restrict__ out1)
{
    const int H1 = 384, HW1 = H1*H1, H2 = 192, HW2 = H2*H2;
    int tY = blockIdx.x / 48, tX = blockIdx.x % 48, n = blockIdx.z;
    int y0 = tY*16, x0 = tX*8;
    int uy0 = (y0>>1) - 2, ux0 = (x0>>1) - 2;   // u tile 12 rows x 8 cols

    __shared__ __align__(16) short sP0[308*36];   // vl 22x14, later t1 18x10
    __shared__ __align__(16) short sP1[240*36];   // u 12x8 (96), later v 20x12 (240)
    __shared__ u8 s_m[308];                       // 22x14, origin (y0-3, x0-3)
    short* s_u  = sP1;
    short* s_vl = sP0;
    short* s_v  = sP1;
    short* s_t1 = sP0;

    int tid = threadIdx.x;
    const short* uN = u + (size_t)n*32*HW2;
    for (int i = tid; i < 32*96; i += 256){
        int c = i/96, r = i%96; int ly = r>>3, lxx = r&7;
        int gy = uy0+ly, gx = ux0+lxx;
        short v = 0;
        if ((unsigned)gy < 192u && (unsigned)gx < 192u) v = uN[(size_t)c*HW2 + gy*H2 + gx];
        s_u[r*36 + c] = v;
    }
    for (int i = tid; i < 308; i += 256){
        int ry = i/14, rx = i%14; int gy = y0-3+ry, gx = x0-3+rx;
        s_m[i] = ((unsigned)gy < 384u && (unsigned)gx < 384u) ? M1[(size_t)n*HW1 + gy*H1 + gx] : 0;
    }
    __syncthreads();

    int wv = tid >> 6, lane = tid & 63;
    int nQ = lane >> 4, nn = lane & 15;

    // ---- stage A: vl[308][32]; 4 classes x 77 sites (11 rows x 7 cols) = 20 units ----
    for (int ui = wv; ui < 20; ui += 4){
        int cls = ui/5, nt = ui%5;
        int pY = cls >> 1, pX = cls & 1;
        int s0 = nt*16 + nn;
        int s = s0 > 76 ? 76 : s0;
        int jr = s/7, jc = s%7;
        int ry = 2*jr + pY, rx = 2*jc + pX;
        int gY = y0-3+ry, gX = x0-3+rx;

        int tiy[4], tix[4], twk[4]; int tapN;
        if (pY == 0){   // gY odd
            int iA = ((gY-1)>>1) - uy0, iB = ((gY+1)>>1) - uy0;
            if (pX == 0){
                int jA = ((gX-1)>>1) - ux0, jB = ((gX+1)>>1) - ux0;
                tiy[0]=iA; tix[0]=jA; twk[0]=8;
                tiy[1]=iA; tix[1]=jB; twk[1]=6;
                tiy[2]=iB; tix[2]=jA; twk[2]=2;
                tiy[3]=iB; tix[3]=jB; twk[3]=0; tapN=4;
            } else {
                int j = (gX>>1) - ux0;
                tiy[0]=iA; tix[0]=j; twk[0]=7;
                tiy[1]=iB; tix[1]=j; twk[1]=1; tapN=2;
            }
        } else {        // gY even
            int i2 = (gY>>1) - uy0;
            if (pX == 0){
                int jA = ((gX-1)>>1) - ux0, jB = ((gX+1)>>1) - ux0;
                tiy[0]=i2; tix[0]=jA; twk[0]=5;
                tiy[1]=i2; tix[1]=jB; twk[1]=3; tapN=2;
            } else {
                tiy[0]=i2; tix[0]=(gX>>1)-ux0; twk[0]=4; tapN=1;
            }
        }

        f32x4 acc0 = {0,0,0,0}, acc1 = {0,0,0,0};
        for (int t = 0; t < tapN; ++t){
            bf16x8 bfr = lds8(s_u + (tiy[t]*8 + tix[t])*36 + nQ*8);
            bf16x8 a0 = *(const bf16x8*)(wTi2 + twk[t]*1024 + nn*32 + nQ*8);
            bf16x8 a1 = *(const bf16x8*)(wTi2 + twk[t]*1024 + (16+nn)*32 + nQ*8);
            acc0 = MFMA_B16(a0, bfr, acc0, 0,0,0);
            acc1 = MFMA_B16(a1, bfr, acc1, 0,0,0);
        }
        if (s0 <= 76){
            int sidx = ry*14 + rx;
            u8 m = s_m[sidx];
            float r[8];
            #pragma unroll
            for (int g=0; g<2; ++g)
                #pragma unroll
                for (int e=0; e<4; ++e){
                    float a = (g ? acc1[e] : acc0[e]) * BNS;
                    r[g*4+e] = m ? (a > 0.f ? a : 0.2f*a) : 0.f;
                }
            bf16x4 w0 = {f2bs(r[0]),f2bs(r[1]),f2bs(r[2]),f2bs(r[3])};
            bf16x4 w1 = {f2bs(r[4]),f2bs(r[5]),f2bs(r[6]),f2bs(r[7])};
            *(bf16x4*)(s_vl + sidx*36 + nQ*4) = w0;
            *(bf16x4*)(s_vl + sidx*36 + 16 + nQ*4) = w1;
        }
    }
    __syncthreads();

    // ---- stage B: v[240][32] (20 rows x 12 cols, origin y0-2,x0-2) ----
    {
        bf16x8 wb0[9], wb1[9];
        #pragma unroll
        for (int k=0;k<9;++k){
            wb0[k] = *(const bf16x8*)(wTl5 + k*1024 + nn*32 + nQ*8);
            wb1[k] = *(const bf16x8*)(wTl5 + k*1024 + (16+nn)*32 + nQ*8);
        }
        for (int nt = wv; nt < 15; nt += 4){
            int s0 = nt*16 + nn;
            int vy = s0/12, vx = s0%12;
            f32x4 acc0 = {0,0,0,0}, acc1 = {0,0,0,0};
            #pragma unroll
            for (int ky=0; ky<3; ++ky)
                #pragma unroll
                for (int kx=0; kx<3; ++kx){
                    const int k = ky*3+kx;
                    bf16x8 bfr = lds8(s_vl + ((vy+ky)*14 + vx+kx)*36 + nQ*8);
                    acc0 = MFMA_B16(wb0[k], bfr, acc0, 0,0,0);
                    acc1 = MFMA_B16(wb1[k], bfr, acc1, 0,0,0);
                }
            u8 m = s_m[(vy+1)*14 + vx+1];
            int gY = y0-2+vy, gX = x0-2+vx;
            const short* f1 = fea1 + (size_t)n*32*HW1 + (size_t)gY*H1 + gX;
            float r[8];
            #pragma unroll
            for (int g=0; g<2; ++g)
                #pragma unroll
                for (int e=0; e<4; ++e){
                    int co = g*16 + nQ*4 + e;
                    float a = g ? acc1[e] : acc0[e];
                    r[g*4+e] = m ? a + s2f(f1[(size_t)co*HW1]) : 0.f;
                }
            bf16x4 w0 = {f2bs(r[0]),f2bs(r[1]),f2bs(r[2]),f2bs(r[3])};
            bf16x4 w1 = {f2bs(r[4]),f2bs(r[5]),f2bs(r[6]),f2bs(r[7])};
            *(bf16x4*)(s_v + s0*36 + nQ*4) = w0;
            *(bf16x4*)(s_v + s0*36 + 16 + nQ*4) = w1;
        }
    }
    __syncthreads();

    // ---- stage C: t1[180][32] (18 rows x 10 cols, origin y0-1,x0-1) ----
    {
        bf16x8 wc0[9], wc1[9];
        #pragma unroll
        for (int k=0;k<9;++k){
            wc0[k] = *(const bf16x8*)(wTr1a + k*1024 + nn*32 + nQ*8);
            wc1[k] = *(const bf16x8*)(wTr1a + k*1024 + (16+nn)*32 + nQ*8);
        }
        for (int nt = wv; nt < 12; nt += 4){
            int s0 = nt*16 + nn;
            int s = s0 > 179 ? 179 : s0;
            int qy = s/10, qx = s%10;
            f32x4 acc0 = {0,0,0,0}, acc1 = {0,0,0,0};
            #pragma unroll
            for (int ky=0; ky<3; ++ky)
                #pragma unroll
                for (int kx=0; kx<3; ++kx){
                    const int k = ky*3+kx;
                    bf16x8 bfr = lds8(s_v + ((qy+ky)*12 + qx+kx)*36 + nQ*8);
                    acc0 = MFMA_B16(wc0[k], bfr, acc0, 0,0,0);
                    acc1 = MFMA_B16(wc1[k], bfr, acc1, 0,0,0);
                }
            if (s0 <= 179){
                u8 m = s_m[(qy+2)*14 + qx+2];
                float r[8];
                #pragma unroll
                for (int g=0; g<2; ++g)
                    #pragma unroll
                    for (int e=0; e<4; ++e){
                        float a = (g ? acc1[e] : acc0[e]) * BNS;
                        r[g*4+e] = m ? (a > 0.f ? a : 0.2f*a) : 0.f;
                    }
                bf16x4 w0 = {f2bs(r[0]),f2bs(r[1]),f2bs(r[2]),f2bs(r[3])};
                bf16x4 w1 = {f2bs(r[4]),f2bs(r[5]),f2bs(r[6]),f2bs(r[7])};
                *(bf16x4*)(s_t1 + s*36 + nQ*4) = w0;
                *(bf16x4*)(s_t1 + s*36 + 16 + nQ*4) = w1;
            }
        }
    }
    __syncthreads();

    // ---- stage D: out 16x8 ----
    if (tid < 128){
        int ty = tid >> 3, tx = tid & 7;
        u8 m = s_m[(ty+3)*14 + tx+3];
        float o = -99.f;
        if (m){
            float acc = 0.f;
            #pragma unroll
            for (int k = 0; k < 9; ++k){
                const short* tp = s_t1 + ((ty + k/3)*10 + tx + k%3)*36;
                for (int ci = 0; ci < 32; ++ci)
                    acc += s2f(tp[ci]) * w_r1b[ci*9 + k];
            }
            o = acc + r1_b2[0];
        }
        out1[(size_t)n*HW1 + (y0+ty)*H1 + (x0+tx)] = o;
    }
}

// ---------------- launch ----------------

extern "C" void kernel_launch(void* const* d_in, const int* in_sizes, int n_in,
                              void* d_out, int out_size, void* d_ws, size_t ws_size,
                              hipStream_t stream)
{
    const float* x      = (const float*)d_in[0];
    const float* image  = (const float*)d_in[1];
    const float* masks  = (const float*)d_in[2];
    const float* roi    = (const float*)d_in[3];
    const float* w1a    = (const float*)d_in[4];
    const float* w1b    = (const float*)d_in[5];
    const float* w2a    = (const float*)d_in[6];
    const float* w2b    = (const float*)d_in[7];
    const float* w4a    = (const float*)d_in[8];
    const float* w4b    = (const float*)d_in[9];
    const float* inv4_w = (const float*)d_in[10];
    const float* l4_sub = (const float*)d_in[11];
    const float* inv2_w = (const float*)d_in[12];
    const float* l5_sub = (const float*)d_in[13];
    const float* r4_w1  = (const float*)d_in[14];
    const float* r4_w2  = (const float*)d_in[15];
    const float* r4_b2  = (const float*)d_in[16];
    const float* r1_w1  = (const float*)d_in[17];
    const float* r1_w2  = (const float*)d_in[18];
    const float* r1_b2  = (const float*)d_in[19];
    float* out = (float*)d_out;

    const int N = 8;
    const int H1 = 384, HW1 = 384*384;
    const int H2 = 192, HW2 = 192*192;
    const int H4 = 96,  HW4 = 96*96;

    char* wsp = (char*)d_ws;
    size_t off = 0;
    auto alloc = [&](size_t bytes) -> char* {
        char* p = wsp + off;
        off += (bytes + 255) & ~(size_t)255;
        return p;
    };
    bf16* FEA1 = (bf16*)alloc((size_t)N*32*HW1*2);
    u8*   M1   = (u8*)alloc((size_t)N*HW1);
    u8*   M2   = (u8*)alloc((size_t)N*HW2);
    u8*   M4   = (u8*)alloc((size_t)N*HW4);
    bf16* FEA2 = (bf16*)alloc((size_t)N*32*HW2*2);
    bf16* XS   = (bf16*)alloc((size_t)N*64*HW4*2);
    bf16* GU   = (bf16*)alloc((size_t)N*32*HW2*2);  // g, then u
    bf16* HT   = (bf16*)alloc((size_t)N*64*HW4*2);  // h, then t_leaky
    short* WT   = (short*)alloc(6*9216*2);          // [w1bT, inv2T, l5T, r1aT, w2bT, w2aT]
    short* WT4  = (short*)alloc((size_t)129024*2);  // [inv4T, w4bT, l4sT, r4w1T, w4aT]
    short* WT1a = (short*)alloc(2048*2);
    (void)ws_size; (void)in_sizes; (void)n_in; (void)out_size;

    short* wT1b  = WT;
    short* wTi2  = WT + 9216;
    short* wTl5  = WT + 2*9216;
    short* wTr1a = WT + 3*9216;
    short* wT2b  = WT + 4*9216;
    short* wT2a  = WT + 5*9216;
    short* wTi4  = WT4;
    short* wT4b  = WT4 + 36864;
    short* wTl4  = WT4 + 73728;
    short* wTr4a = WT4 + 92160;
    short* wT4a  = WT4 + 110592;

    dim3 blk(256);

    // masks + weight prep
    k_mask1<<<dim3((N*HW1 + 255)/256), blk, 0, stream>>>(roi, M1, N*HW1);
    k_down<<<dim3((HW2 + 255)/256, N), blk, 0, stream>>>(M1, M2, H1, H1, H2, H2);
    k_down<<<dim3((HW4 + 255)/256, N), blk, 0, stream>>>(M2, M4, H2, H2, H4, H4);
    k_wprep<<<dim3(36, 6), blk, 0, stream>>>(w1b, inv2_w, l5_sub, r1_w1, w2b, w2a, WT);
    k_wprep4<<<dim3(144, 5), blk, 0, stream>>>(inv4_w, w4b, l4_sub, r4_w1, w4a, WT4);
    k_wprep1a<<<dim3(8), blk, 0, stream>>>(w1a, WT1a);

    // front
    conv1ab3<<<dim3(1152, 1, N), blk, 0, stream>>>(image, masks, M1, WT1a, wT1b, (short*)FEA1);
    mconv_s2m<32><<<dim3(288, 1, N), blk, 0, stream>>>((const short*)FEA1, H1, wT2a, M2, (short*)GU, H2, 12);
    mconv_s1<32,32,0><<<dim3(144, 1, N), blk, 0, stream>>>((const short*)GU, H2, wT2b, M2, nullptr, (short*)FEA2, 12);
    mconv_s2m<64><<<dim3(72, 1, N), blk, 0, stream>>>((const short*)FEA2, H2, wT4a, M4, (short*)HT, H4, 6);
    mconv_s1<64,64,3><<<dim3(36, 1, N), blk, 0, stream>>>((const short*)HT, H4, wT4b, M4, x, (short*)XS, 6);

    // refine_OS4
    mconv_s1<64,32,1><<<dim3(36, 1, N), blk, 0, stream>>>((const short*)XS, H4, wTr4a, M4, nullptr, (short*)HT, 6);
    conv3x3_head<32><<<dim3(36, 1, N), blk, 0, stream>>>(HT, H4, H4, r4_w2, r4_b2, M4, out);

    // layer4 fused (MFMA) -> u
    fk_l4c<<<dim3(144, 1, N), blk, 0, stream>>>((const short*)XS, (const short*)FEA2, M2,
                                                wTi4, wTl4, (short*)GU);

    // MFMA back end -> out1 (16x8 tile, 4 blocks/CU)
    fk_back5<<<dim3(1152, 1, N), blk, 0, stream>>>((const short*)GU, (const short*)FEA1, M1,
                                                   wTi2, wTl5, wTr1a, r1_w2, r1_b2,
                                                   out + (size_t)N*HW4);
}

// Round 10
// 1045.309 us; speedup vs baseline: 21.0273x; 1.0843x over previous
//
#include <hip/hip_runtime.h>
#include <hip/hip_bf16.h>

using bf16 = __hip_bfloat16;
typedef unsigned char u8;
typedef short bf16x8 __attribute__((ext_vector_type(8)));
typedef short bf16x4 __attribute__((ext_vector_type(4)));
typedef float f32x4 __attribute__((ext_vector_type(4)));

#define BNS 0.9999950000374997f   // 1/sqrt(1+1e-5)
#define MFMA_B16 __builtin_amdgcn_mfma_f32_16x16x32_bf16

__device__ __forceinline__ float b2f(bf16 v){ return __bfloat162float(v); }
__device__ __forceinline__ short f2bs(float v){ bf16 h = __float2bfloat16(v); return *reinterpret_cast<short*>(&h); }
__device__ __forceinline__ float s2f(short s){ union{unsigned u; float f;} x; x.u = ((unsigned)(unsigned short)s) << 16; return x.f; }

__device__ __forceinline__ bf16x8 lds8(const short* p){
    bf16x4 lo = *(const bf16x4*)(p);
    bf16x4 hi = *(const bf16x4*)(p + 4);
    bf16x8 r = {lo[0],lo[1],lo[2],lo[3],hi[0],hi[1],hi[2],hi[3]};
    return r;
}

// ---------------- mask kernels ----------------

__global__ __launch_bounds__(256) void k_mask1(const float* __restrict__ roi, u8* __restrict__ m1, int total){
    int i = blockIdx.x*256 + threadIdx.x;
    if (i < total) m1[i] = (roi[i] > 0.8f) ? 1 : 0;
}

__global__ __launch_bounds__(256) void k_down(const u8* __restrict__ mi, u8* __restrict__ mo,
                                              int IH, int IW, int OH, int OW){
    int p = blockIdx.x*256 + threadIdx.x;
    int n = blockIdx.y;
    if (p >= OH*OW) return;
    int oy = p / OW, ox = p - oy*OW;
    const u8* src = mi + (size_t)n*IH*IW;
    int v = 0;
    #pragma unroll
    for (int ky=0; ky<3; ky++){
        int iy = 2*oy + ky - 1;
        if ((unsigned)iy >= (unsigned)IH) continue;
        #pragma unroll
        for (int kx=0; kx<3; kx++){
            int ix = 2*ox + kx - 1;
            if ((unsigned)ix < (unsigned)IW) v |= src[iy*IW + ix];
        }
    }
    mo[(size_t)n*OH*OW + p] = (u8)v;
}

// ---- weight prep: 6 arrays [32][32][9] fp32 -> bf16 [9][32co][32ci] ----
__global__ __launch_bounds__(256) void k_wprep(const float* __restrict__ w1b,
                                               const float* __restrict__ i2,
                                               const float* __restrict__ l5,
                                               const float* __restrict__ r1a,
                                               const float* __restrict__ w2b,
                                               const float* __restrict__ w2a,
                                               short* __restrict__ dst){
    int a = blockIdx.y;
    const float* src = (a==0)? w1b : (a==1)? i2 : (a==2)? l5 : (a==3)? r1a : (a==4)? w2b : w2a;
    int j = blockIdx.x*256 + threadIdx.x;
    if (j < 9216){
        int co = j/288, r = j%288, ci = r/9, k = r%9;
        dst[a*9216 + k*1024 + co*32 + ci] = f2bs(src[j]);
    }
}

// ---- weight prep 64-wide ----
__global__ __launch_bounds__(256) void k_wprep4(const float* __restrict__ inv4,
                                                const float* __restrict__ w4b,
                                                const float* __restrict__ l4s,
                                                const float* __restrict__ r4w1,
                                                const float* __restrict__ w4a,
                                                short* __restrict__ dst)
{
    int a = blockIdx.y;
    int j = blockIdx.x*256 + threadIdx.x;
    if (a < 2){
        if (j < 36864){
            int co = j/576, r = j%576, ci = r/9, k = r%9;
            const float* s = a ? w4b : inv4;
            dst[a*36864 + k*4096 + co*64 + ci] = f2bs(s[j]);
        }
    } else if (a < 4){
        if (j < 18432){
            int co = j/576, r = j%576, ci = r/9, k = r%9;
            const float* s = (a==2) ? l4s : r4w1;
            dst[73728 + (a-2)*18432 + k*2048 + co*64 + ci] = f2bs(s[j]);
        }
    } else {
        if (j < 18432){
            int co = j/288, r = j%288, ci = r/9, k = r%9;
            dst[110592 + k*2048 + co*32 + ci] = f2bs(w4a[j]);
        }
    }
}

// ---- misc prep: a=0 w1a im2col [2Kh][32co][32kq]; a=1/2 head weights [9][16co][32ci],
//      co row 0 = w[ci*9+k], rows 1..15 zero ----
__global__ __launch_bounds__(256) void k_wprep_misc(const float* __restrict__ w1a,
                                                    const float* __restrict__ r1w2,
                                                    const float* __restrict__ r4w2,
                                                    short* __restrict__ d1a,
                                                    short* __restrict__ dh){
    int a = blockIdx.y;
    int j = blockIdx.x*256 + threadIdx.x;
    if (a == 0){
        if (j < 2048){
            int h = j >> 10, r = j & 1023, co = r >> 5, kq = r & 31;
            int q = h*32 + kq;
            d1a[j] = (q < 36) ? f2bs(w1a[co*36 + q]) : 0;
        }
    } else {
        if (j < 4608){
            int k = j/512, r = j%512, co = r/32, ci = r%32;
            const float* s = (a==1) ? r1w2 : r4w2;
            dh[(a-1)*4608 + j] = (co == 0) ? f2bs(s[ci*9 + k]) : 0;
        }
    }
}

// ---------------- generic MFMA stride-1 conv (proven) ----------------
template<int CIN, int COUT, int EPI>
__global__ __launch_bounds__(256) void mconv_s1(const short* __restrict__ in, int H,
                                                const short* __restrict__ wT,
                                                const u8* __restrict__ mask,
                                                const float* __restrict__ res32,
                                                short* __restrict__ out, int tilesX)
{
    const int HW = H*H;
    const int HV = CIN/32, G = COUT/16;
    int tY = blockIdx.x / tilesX, tX = blockIdx.x % tilesX, n = blockIdx.z;
    int y0 = tY*16, x0 = tX*16;

    __shared__ __align__(16) short s_in[HV*11664];
    __shared__ u8 s_m[256];

    int tid = threadIdx.x;
    const short* inN = in + (size_t)n*CIN*HW;
    for (int i = tid; i < CIN*324; i += 256){
        int c = i/324, r = i%324;
        int ry = r/18, rx = r%18;
        int gy = y0-1+ry, gx = x0-1+rx;
        short v = 0;
        if ((unsigned)gy < (unsigned)H && (unsigned)gx < (unsigned)H)
            v = inN[(size_t)c*HW + gy*H + gx];
        s_in[(c>>5)*11664 + r*36 + (c&31)] = v;
    }
    for (int i = tid; i < 256; i += 256){
        int ty = i>>4, tx = i&15;
        s_m[i] = mask[(size_t)n*HW + (y0+ty)*H + x0+tx];
    }
    __syncthreads();

    int wv = tid >> 6, lane = tid & 63;
    int nQ = lane >> 4, nn = lane & 15;

    bf16x8 wa0[9], wa1[9];
    if constexpr (CIN == 32 && COUT == 32){
        #pragma unroll
        for (int k=0;k<9;++k){
            wa0[k] = *(const bf16x8*)(wT + k*1024 + nn*32 + nQ*8);
            wa1[k] = *(const bf16x8*)(wT + k*1024 + (16+nn)*32 + nQ*8);
        }
    }

    for (int nt = wv; nt < 16; nt += 4){
        int ty = nt, tx = nn;
        f32x4 acc[G];
        #pragma unroll
        for (int g=0;g<G;++g) acc[g] = (f32x4){0,0,0,0};
        #pragma unroll
        for (int ky=0; ky<3; ++ky)
            #pragma unroll
            for (int kx=0; kx<3; ++kx){
                const int k = ky*3+kx;
                #pragma unroll
                for (int h=0; h<HV; ++h){
                    bf16x8 bfr = lds8(s_in + h*11664 + ((ty+ky)*18 + tx+kx)*36 + nQ*8);
                    #pragma unroll
                    for (int g=0; g<G; ++g){
                        bf16x8 a;
                        if constexpr (CIN == 32 && COUT == 32) a = g ? wa1[k] : wa0[k];
                        else a = *(const bf16x8*)(wT + k*COUT*CIN + (g*16+nn)*CIN + h*32 + nQ*8);
                        acc[g] = MFMA_B16(a, bfr, acc[g], 0,0,0);
                    }
                }
            }
        int p = (y0+ty)*H + x0+tx;
        u8 m = s_m[nt*16 + nn];
        short* op = out + (size_t)n*COUT*HW + p;
        #pragma unroll
        for (int g=0; g<G; ++g)
            #pragma unroll
            for (int e=0; e<4; ++e){
                int co = g*16 + nQ*4 + e;
                float a = acc[g][e], o;
                if      (EPI == 0) o = m ? fmaxf(a,0.f)*BNS : 0.f;
                else if (EPI == 1){ float s = a*BNS; o = m ? (s>0.f ? s : 0.2f*s) : 0.f; }
                else o = m ? fmaxf(a,0.f)*BNS + res32[((size_t)(n>>2)*COUT + co)*(size_t)HW + p] : 0.f;
                op[(size_t)co*HW] = f2bs(o);
            }
    }
}

// ---------------- MFMA COUT=1 head: conv + bias, -99 off-mask, fp32 out ----------------
__global__ __launch_bounds__(256) void mconv_head32(const short* __restrict__ in, int H,
                                                    const short* __restrict__ wTh,  // [9][16][32]
                                                    const float* __restrict__ bias,
                                                    const u8* __restrict__ mask,
                                                    float* __restrict__ out, int tilesX)
{
    const int HW = H*H;
    int tY = blockIdx.x / tilesX, tX = blockIdx.x % tilesX, n = blockIdx.z;
    int y0 = tY*16, x0 = tX*16;

    __shared__ __align__(16) short s_in[11664];
    __shared__ u8 s_m[256];

    int tid = threadIdx.x;
    const short* inN = in + (size_t)n*32*HW;
    for (int i = tid; i < 32*324; i += 256){
        int c = i/324, r = i%324;
        int ry = r/18, rx = r%18;
        int gy = y0-1+ry, gx = x0-1+rx;
        short v = 0;
        if ((unsigned)gy < (unsigned)H && (unsigned)gx < (unsigned)H)
            v = inN[(size_t)c*HW + gy*H + gx];
        s_in[r*36 + c] = v;
    }
    for (int i = tid; i < 256; i += 256){
        int ty = i>>4, tx = i&15;
        s_m[i] = mask[(size_t)n*HW + (y0+ty)*H + x0+tx];
    }
    __syncthreads();

    int wv = tid >> 6, lane = tid & 63;
    int nQ = lane >> 4, nn = lane & 15;
    float bb = bias[0];

    for (int nt = wv; nt < 16; nt += 4){
        int ty = nt, tx = nn;
        f32x4 acc = {0,0,0,0};
        #pragma unroll
        for (int ky=0; ky<3; ++ky)
            #pragma unroll
            for (int kx=0; kx<3; ++kx){
                const int k = ky*3+kx;
                bf16x8 bfr = lds8(s_in + ((ty+ky)*18 + tx+kx)*36 + nQ*8);
                bf16x8 aw = *(const bf16x8*)(wTh + k*512 + nn*32 + nQ*8);
                acc = MFMA_B16(aw, bfr, acc, 0,0,0);
            }
        if (nQ == 0){
            u8 m = s_m[nt*16 + nn];
            int p = (y0+ty)*H + x0+tx;
            out[(size_t)n*HW + p] = m ? acc[0] + bb : -99.f;
        }
    }
}

// ---------------- MFMA stride-2 conv: tile 8(y) x 16(x), CIN=32 ----------------
template<int COUT>
__global__ __launch_bounds__(256) void mconv_s2m(const short* __restrict__ in, int IH,
                                                 const short* __restrict__ wT,   // [9][COUT][32]
                                                 const u8* __restrict__ mask,
                                                 short* __restrict__ out, int OH, int tilesX)
{
    const int IHW = IH*IH, OHW = OH*OH, G = COUT/16;
    int tY = blockIdx.x / tilesX, tX = blockIdx.x % tilesX, n = blockIdx.z;
    int y0 = tY*8, x0 = tX*16;

    __shared__ __align__(16) short s_in[561*36];
    __shared__ u8 s_m[128];

    int tid = threadIdx.x;
    const short* inN = in + (size_t)n*32*IHW;
    for (int i = tid; i < 32*561; i += 256){
        int c = i/561, r = i%561;
        int ry = r/33, rx = r%33;
        int gy = 2*y0-1+ry, gx = 2*x0-1+rx;
        short v = 0;
        if ((unsigned)gy < (unsigned)IH && (unsigned)gx < (unsigned)IH)
            v = inN[(size_t)c*IHW + gy*IH + gx];
        s_in[r*36 + c] = v;
    }
    for (int i = tid; i < 128; i += 256){
        int ty = i>>4, tx = i&15;
        s_m[i] = mask[(size_t)n*OHW + (y0+ty)*OH + x0+tx];
    }
    __syncthreads();

    int wv = tid >> 6, lane = tid & 63;
    int nQ = lane >> 4, nn = lane & 15;

    for (int nt = wv; nt < 8; nt += 4){
        int ty = nt, tx = nn;
        f32x4 acc[G];
        #pragma unroll
        for (int g=0;g<G;++g) acc[g] = (f32x4){0,0,0,0};
        #pragma unroll
        for (int ky=0; ky<3; ++ky)
            #pragma unroll
            for (int kx=0; kx<3; ++kx){
                const int k = ky*3+kx;
                bf16x8 bfr = lds8(s_in + ((2*ty+ky)*33 + 2*tx+kx)*36 + nQ*8);
                #pragma unroll
                for (int g=0; g<G; ++g){
                    bf16x8 a = *(const bf16x8*)(wT + k*COUT*32 + (g*16+nn)*32 + nQ*8);
                    acc[g] = MFMA_B16(a, bfr, acc[g], 0,0,0);
                }
            }
        int p = (y0+ty)*OH + x0+tx;
        u8 m = s_m[nt*16 + nn];
        short* op = out + (size_t)n*COUT*OHW + p;
        #pragma unroll
        for (int g=0; g<G; ++g)
            #pragma unroll
            for (int e=0; e<4; ++e){
                int co = g*16 + nQ*4 + e;
                float o = m ? fmaxf(acc[g][e],0.f)*BNS : 0.f;
                op[(size_t)co*OHW] = f2bs(o);
            }
    }
}

// ---------------- conv1ab v4: im2col MFMA f-stage + MFMA stage-2; tile 16x8 ----------
__global__ __launch_bounds__(256) void conv1ab3(const float* __restrict__ image,
                                                const float* __restrict__ masks,
                                                const u8*  __restrict__ M1,
                                                const short* __restrict__ wT1a,   // [2][32co][32K]
                                                const short* __restrict__ wT1b,   // [9][32co][32ci]
                                                short* __restrict__ fea1)
{
    const int H = 384; const int HW = H*H;
    int tY = blockIdx.x / 48, tX = blockIdx.x % 48, n = blockIdx.z;
    int y0 = tY*16, x0 = tX*8;

    __shared__ float s_inp[4][240];
    __shared__ u8    s_m[240];
    __shared__ __align__(16) short s_ic[180*72];
    short* s_f = s_ic;

    int tid = threadIdx.x;
    for (int i = tid; i < 240; i += 256){
        int ly = i/12, lxx = i%12;
        int gy = y0-2+ly, gx = x0-2+lxx;
        bool inb = ((unsigned)gy < 384u) && ((unsigned)gx < 384u);
        u8 mv = inb ? M1[(size_t)n*HW + gy*H + gx] : 0;
        s_m[i] = mv;
        float mm = (float)mv;
        int p = gy*H + gx;
        #pragma unroll
        for (int c = 0; c < 4; ++c){
            float v = 0.f;
            if (inb) v = (c < 3) ? image[((size_t)(n>>2)*3 + c)*HW + p]
                                 : masks[(size_t)n*HW + p];
            s_inp[c][i] = v*mm;
        }
    }
    __syncthreads();

    for (int i = tid; i < 180*64; i += 256){
        int site = i >> 6, q = i & 63;
        short v = 0;
        if (q < 36){
            int ci = q/9, k = q - ci*9, ky = k/3, kx = k - ky*3;
            int fy = site/10, fx = site - fy*10;
            v = f2bs(s_inp[ci][(fy+ky)*12 + fx+kx]);
        }
        s_ic[site*72 + q] = v;
    }
    __syncthreads();

    int wv = tid >> 6, lane = tid & 63;
    int nQ = lane >> 4, nn = lane & 15;

    f32x4 fr[3][2];
    {
        bf16x8 fa0[2], fa1[2];
        #pragma unroll
        for (int h=0;h<2;++h){
            fa0[h] = *(const bf16x8*)(wT1a + h*1024 + nn*32 + nQ*8);
            fa1[h] = *(const bf16x8*)(wT1a + h*1024 + (16+nn)*32 + nQ*8);
        }
        #pragma unroll
        for (int u=0; u<3; ++u){
            int nt = u*4 + wv;
            int s0 = nt*16 + nn;
            int s = s0 > 179 ? 179 : s0;
            f32x4 a0 = {0,0,0,0}, a1 = {0,0,0,0};
            #pragma unroll
            for (int h=0;h<2;++h){
                bf16x8 bfr = lds8(s_ic + s*72 + h*32 + nQ*8);
                a0 = MFMA_B16(fa0[h], bfr, a0, 0,0,0);
                a1 = MFMA_B16(fa1[h], bfr, a1, 0,0,0);
            }
            fr[u][0] = a0; fr[u][1] = a1;
        }
    }
    __syncthreads();

    #pragma unroll
    for (int u=0; u<3; ++u){
        int nt = u*4 + wv;
        int s0 = nt*16 + nn;
        if (s0 <= 179){
            int fy = s0/10, fx = s0 - fy*10;
            u8 m = s_m[(fy+1)*12 + fx+1];
            #pragma unroll
            for (int g=0; g<2; ++g){
                float r[4];
                #pragma unroll
                for (int e=0; e<4; ++e){
                    float a = fr[u][g][e];
                    r[e] = m ? fmaxf(a,0.f)*BNS : 0.f;
                }
                bf16x4 w4 = {f2bs(r[0]),f2bs(r[1]),f2bs(r[2]),f2bs(r[3])};
                *(bf16x4*)(s_f + s0*36 + g*16 + nQ*4) = w4;
            }
        }
    }
    __syncthreads();

    bf16x8 wa0[9], wa1[9];
    #pragma unroll
    for (int k=0;k<9;++k){
        wa0[k] = *(const bf16x8*)(wT1b + k*1024 + nn*32 + nQ*8);
        wa1[k] = *(const bf16x8*)(wT1b + k*1024 + (16+nn)*32 + nQ*8);
    }
    for (int nt = wv; nt < 8; nt += 4){
        int s0 = nt*16 + nn;
        int ty = s0 >> 3, tx = s0 & 7;
        f32x4 acc0 = {0,0,0,0}, acc1 = {0,0,0,0};
        #pragma unroll
        for (int ky=0; ky<3; ++ky)
            #pragma unroll
            for (int kx=0; kx<3; ++kx){
                const int k = ky*3+kx;
                bf16x8 bfr = lds8(s_f + ((ty+ky)*10 + tx+kx)*36 + nQ*8);
                acc0 = MFMA_B16(wa0[k], bfr, acc0, 0,0,0);
                acc1 = MFMA_B16(wa1[k], bfr, acc1, 0,0,0);
            }
        u8 m = s_m[(ty+2)*12 + tx+2];
        short* fp = fea1 + (size_t)n*32*HW + (y0+ty)*H + x0+tx;
        #pragma unroll
        for (int g=0; g<2; ++g)
            #pragma unroll
            for (int e=0; e<4; ++e){
                int co = g*16 + nQ*4 + e;
                float a = g ? acc1[e] : acc0[e];
                float o = m ? fmaxf(a,0.f)*BNS : 0.f;
                fp[(size_t)co*HW] = f2bs(o);
            }
    }
}

// ---------------- MFMA layer4 (proven) ----------------
__global__ __launch_bounds__(256) void fk_l4c(const short* __restrict__ xs,
                                              const short* __restrict__ fea2,
                                              const u8*  __restrict__ M2,
                                              const short* __restrict__ wTi4,
                                              const short* __restrict__ wTl4,
                                              short* __restrict__ u_out)
{
    const int H2 = 192, HW2 = H2*H2, H4 = 96, HW4 = H4*H4;
    int tY = blockIdx.x / 12, tX = blockIdx.x % 12, n = blockIdx.z;
    int y0 = tY*16, x0 = tX*16;
    int uy0 = (y0>>1) - 1, ux0 = (x0>>1) - 1;

    __shared__ __align__(16) short s_xs[2*100*36];
    __shared__ __align__(16) short s_ul[2*324*36];
    __shared__ u8 s_m[324];

    int tid = threadIdx.x;
    const short* xN = xs + (size_t)n*64*HW4;
    for (int i = tid; i < 64*100; i += 256){
        int c = i/100, r = i%100; int ly = r/10, lxx = r%10;
        int gy = uy0+ly, gx = ux0+lxx;
        short v = 0;
        if ((unsigned)gy < 96u && (unsigned)gx < 96u) v = xN[(size_t)c*HW4 + gy*H4 + gx];
        s_xs[(c>>5)*3600 + r*36 + (c&31)] = v;
    }
    for (int i = tid; i < 324; i += 256){
        int ry = i/18, rx = i%18; int gy = y0-1+ry, gx = x0-1+rx;
        s_m[i] = ((unsigned)gy < 192u && (unsigned)gx < 192u) ? M2[(size_t)n*HW2 + gy*H2 + gx] : 0;
    }
    __syncthreads();

    int wv = tid >> 6, lane = tid & 63;
    int nQ = lane >> 4, nn = lane & 15;

    for (int ui = wv; ui < 24; ui += 4){
        int cls = ui/6, nt = ui%6;
        int pY = cls >> 1, pX = cls & 1;
        int s0 = nt*16 + nn;
        int s = s0 > 80 ? 80 : s0;
        int jr = s/9, jc = s%9;
        int ry = 2*jr + pY, rx = 2*jc + pX;
        int gY = y0-1+ry, gX = x0-1+rx;

        int tiy[4], tix[4], twk[4]; int tapN;
        if (pY == 0){
            int iA = ((gY-1)>>1) - uy0, iB = ((gY+1)>>1) - uy0;
            if (pX == 0){
                int jA = ((gX-1)>>1) - ux0, jB = ((gX+1)>>1) - ux0;
                tiy[0]=iA; tix[0]=jA; twk[0]=8;
                tiy[1]=iA; tix[1]=jB; twk[1]=6;
                tiy[2]=iB; tix[2]=jA; twk[2]=2;
                tiy[3]=iB; tix[3]=jB; twk[3]=0; tapN=4;
            } else {
                int j = (gX>>1) - ux0;
                tiy[0]=iA; tix[0]=j; twk[0]=7;
                tiy[1]=iB; tix[1]=j; twk[1]=1; tapN=2;
            }
        } else {
            int i2 = (gY>>1) - uy0;
            if (pX == 0){
                int jA = ((gX-1)>>1) - ux0, jB = ((gX+1)>>1) - ux0;
                tiy[0]=i2; tix[0]=jA; twk[0]=5;
                tiy[1]=i2; tix[1]=jB; twk[1]=3; tapN=2;
            } else {
                tiy[0]=i2; tix[0]=(gX>>1)-ux0; twk[0]=4; tapN=1;
            }
        }

        f32x4 acc[4];
        #pragma unroll
        for (int g=0; g<4; ++g) acc[g] = (f32x4){0,0,0,0};
        for (int t = 0; t < tapN; ++t){
            int off = (tiy[t]*10 + tix[t])*36 + nQ*8;
            bf16x8 xlo = lds8(s_xs + off);
            bf16x8 xhi = lds8(s_xs + 3600 + off);
            const short* wk = wTi4 + twk[t]*4096;
            #pragma unroll
            for (int g=0; g<4; ++g){
                bf16x8 alo = *(const bf16x8*)(wk + (g*16+nn)*64 + nQ*8);
                bf16x8 ahi = *(const bf16x8*)(wk + (g*16+nn)*64 + 32 + nQ*8);
                acc[g] = MFMA_B16(alo, xlo, acc[g], 0,0,0);
                acc[g] = MFMA_B16(ahi, xhi, acc[g], 0,0,0);
            }
        }
        if (s0 <= 80){
            int sidx = ry*18 + rx;
            u8 m = s_m[sidx];
            #pragma unroll
            for (int g=0; g<4; ++g){
                float r[4];
                #pragma unroll
                for (int e=0; e<4; ++e){
                    float a = acc[g][e]*BNS;
                    r[e] = m ? (a > 0.f ? a : 0.2f*a) : 0.f;
                }
                bf16x4 w4 = {f2bs(r[0]),f2bs(r[1]),f2bs(r[2]),f2bs(r[3])};
                *(bf16x4*)(s_ul + (g>>1)*11664 + sidx*36 + (g&1)*16 + nQ*4) = w4;
            }
        }
    }
    __syncthreads();

    for (int nt = wv; nt < 16; nt += 4){
        int ty = nt, tx = nn;
        f32x4 acc0 = {0,0,0,0}, acc1 = {0,0,0,0};
        #pragma unroll
        for (int ky=0; ky<3; ++ky)
            #pragma unroll
            for (int kx=0; kx<3; ++kx){
                int k = ky*3+kx;
                int off = ((ty+ky)*18 + tx+kx)*36 + nQ*8;
                bf16x8 vlo = lds8(s_ul + off);
                bf16x8 vhi = lds8(s_ul + 11664 + off);
                const short* wk = wTl4 + k*2048;
                bf16x8 a0lo = *(const bf16x8*)(wk + nn*64 + nQ*8);
                bf16x8 a0hi = *(const bf16x8*)(wk + nn*64 + 32 + nQ*8);
                bf16x8 a1lo = *(const bf16x8*)(wk + (16+nn)*64 + nQ*8);
                bf16x8 a1hi = *(const bf16x8*)(wk + (16+nn)*64 + 32 + nQ*8);
                acc0 = MFMA_B16(a0lo, vlo, acc0, 0,0,0);
                acc0 = MFMA_B16(a0hi, vhi, acc0, 0,0,0);
                acc1 = MFMA_B16(a1lo, vlo, acc1, 0,0,0);
                acc1 = MFMA_B16(a1hi, vhi, acc1, 0,0,0);
            }
        int gy = y0+ty, gx = x0+tx;
        int p = gy*H2 + gx;
        u8 m = s_m[(ty+1)*18 + tx+1];
        const short* f2p = fea2 + (size_t)n*32*HW2 + p;
        short* up = u_out + (size_t)n*32*HW2 + p;
        #pragma unroll
        for (int g=0; g<2; ++g)
            #pragma unroll
            for (int e=0; e<4; ++e){
                int co = g*16 + nQ*4 + e;
                float a = g ? acc1[e] : acc0[e];
                float o = m ? a + s2f(f2p[(size_t)co*HW2]) : 0.f;
                up[(size_t)co*HW2] = f2bs(o);
            }
    }
}

// ---------------- MFMA back end v6: 16x8 tile; stage D on MFMA ----------------
__global__ __launch_bounds__(256) void fk_back6(const short* __restrict__ u,
                                                const short* __restrict__ fea1,
                                                const u8*  __restrict__ M1,
                                                const short* __restrict__ wTi2,
                                                const short* __restrict__ wTl5,
                                                const short* __restrict__ wTr1a,
                                                const short* __restrict__ wTr1b,  // [9][16][32]
                                                const float* __restrict__ r1_b2,
                                                float* __restrict__ out1)
{
    const int H1 = 384, HW1 = H1*H1, H2 = 192, HW2 = H2*H2;
    int tY = blockIdx.x / 48, tX = blockIdx.x % 48, n = blockIdx.z;
    int y0 = tY*16, x0 = tX*8;
    int uy0 = (y0>>1) - 2, ux0 = (x0>>1) - 2;

    __shared__ __align__(16) short sP0[308*36];
    __shared__ __align__(16) short sP1[240*36];
    __shared__ u8 s_m[308];
    short* s_u  = sP1;
    short* s_vl = sP0;
    short* s_v  = sP1;
    short* s_t1 = sP0;

    int tid = threadIdx.x;
    const short* uN = u + (size_t)n*32*HW2;
    for (int i = tid; i < 32*96; i += 256){
        int c = i/96, r = i%96; int ly = r>>3, lxx = r&7;
        int gy = uy0+ly, gx = ux0+lxx;
        short v = 0;
        if ((unsigned)gy < 192u && (unsigned)gx < 192u) v = uN[(size_t)c*HW2 + gy*H2 + gx];
        s_u[r*36 + c] = v;
    }
    for (int i = tid; i < 308; i += 256){
        int ry = i/14, rx = i%14; int gy = y0-3+ry, gx = x0-3+rx;
        s_m[i] = ((unsigned)gy < 384u && (unsigned)gx < 384u) ? M1[(size_t)n*HW1 + gy*H1 + gx] : 0;
    }
    __syncthreads();

    int wv = tid >> 6, lane = tid & 63;
    int nQ = lane >> 4, nn = lane & 15;

    // ---- stage A: vl[308][32] ----
    for (int ui = wv; ui < 20; ui += 4){
        int cls = ui/5, nt = ui%5;
        int pY = cls >> 1, pX = cls & 1;
        int s0 = nt*16 + nn;
        int s = s0 > 76 ? 76 : s0;
        int jr = s/7, jc = s%7;
        int ry = 2*jr + pY, rx = 2*jc + pX;
        int gY = y0-3+ry, gX = x0-3+rx;

        int tiy[4], tix[4], twk[4]; int tapN;
        if (pY == 0){
            int iA = ((gY-1)>>1) - uy0, iB = ((gY+1)>>1) - uy0;
            if (pX == 0){
                int jA = ((gX-1)>>1) - ux0, jB = ((gX+1)>>1) - ux0;
                tiy[0]=iA; tix[0]=jA; twk[0]=8;
                tiy[1]=iA; tix[1]=jB; twk[1]=6;
                tiy[2]=iB; tix[2]=jA; twk[2]=2;
                tiy[3]=iB; tix[3]=jB; twk[3]=0; tapN=4;
            } else {
                int j = (gX>>1) - ux0;
                tiy[0]=iA; tix[0]=j; twk[0]=7;
                tiy[1]=iB; tix[1]=j; twk[1]=1; tapN=2;
            }
        } else {
            int i2 = (gY>>1) - uy0;
            if (pX == 0){
                int jA = ((gX-1)>>1) - ux0, jB = ((gX+1)>>1) - ux0;
                tiy[0]=i2; tix[0]=jA; twk[0]=5;
                tiy[1]=i2; tix[1]=jB; twk[1]=3; tapN=2;
            } else {
                tiy[0]=i2; tix[0]=(gX>>1)-ux0; twk[0]=4; tapN=1;
            }
        }

        f32x4 acc0 = {0,0,0,0}, acc1 = {0,0,0,0};
        for (int t = 0; t < tapN; ++t){
            bf16x8 bfr = lds8(s_u + (tiy[t]*8 + tix[t])*36 + nQ*8);
            bf16x8 a0 = *(const bf16x8*)(wTi2 + twk[t]*1024 + nn*32 + nQ*8);
            bf16x8 a1 = *(const bf16x8*)(wTi2 + twk[t]*1024 + (16+nn)*32 + nQ*8);
            acc0 = MFMA_B16(a0, bfr, acc0, 0,0,0);
            acc1 = MFMA_B16(a1, bfr, acc1, 0,0,0);
        }
        if (s0 <= 76){
            int sidx = ry*14 + rx;
            u8 m = s_m[sidx];
            float r[8];
            #pragma unroll
            for (int g=0; g<2; ++g)
                #pragma unroll
                for (int e=0; e<4; ++e){
                    float a = (g ? acc1[e] : acc0[e]) * BNS;
                    r[g*4+e] = m ? (a > 0.f ? a : 0.2f*a) : 0.f;
                }
            bf16x4 w0 = {f2bs(r[0]),f2bs(r[1]),f2bs(r[2]),f2bs(r[3])};
            bf16x4 w1 = {f2bs(r[4]),f2bs(r[5]),f2bs(r[6]),f2bs(r[7])};
            *(bf16x4*)(s_vl + sidx*36 + nQ*4) = w0;
            *(bf16x4*)(s_vl + sidx*36 + 16 + nQ*4) = w1;
        }
    }
    __syncthreads();

    // ---- stage B: v[240][32] ----
    {
        bf16x8 wb0[9], wb1[9];
        #pragma unroll
        for (int k=0;k<9;++k){
            wb0[k] = *(const bf16x8*)(wTl5 + k*1024 + nn*32 + nQ*8);
            wb1[k] = *(const bf16x8*)(wTl5 + k*1024 + (16+nn)*32 + nQ*8);
        }
        for (int nt = wv; nt < 15; nt += 4){
            int s0 = nt*16 + nn;
            int vy = s0/12, vx = s0%12;
            f32x4 acc0 = {0,0,0,0}, acc1 = {0,0,0,0};
            #pragma unroll
            for (int ky=0; ky<3; ++ky)
                #pragma unroll
                for (int kx=0; kx<3; ++kx){
                    const int k = ky*3+kx;
                    bf16x8 bfr = lds8(s_vl + ((vy+ky)*14 + vx+kx)*36 + nQ*8);
                    acc0 = MFMA_B16(wb0[k], bfr, acc0, 0,0,0);
                    acc1 = MFMA_B16(wb1[k], bfr, acc1, 0,0,0);
                }
            u8 m = s_m[(vy+1)*14 + vx+1];
            int gY = y0-2+vy, gX = x0-2+vx;
            const short* f1 = fea1 + (size_t)n*32*HW1 + (size_t)gY*H1 + gX;
            float r[8];
            #pragma unroll
            for (int g=0; g<2; ++g)
                #pragma unroll
                for (int e=0; e<4; ++e){
                    int co = g*16 + nQ*4 + e;
                    float a = g ? acc1[e] : acc0[e];
                    r[g*4+e] = m ? a + s2f(f1[(size_t)co*HW1]) : 0.f;
                }
            bf16x4 w0 = {f2bs(r[0]),f2bs(r[1]),f2bs(r[2]),f2bs(r[3])};
            bf16x4 w1 = {f2bs(r[4]),f2bs(r[5]),f2bs(r[6]),f2bs(r[7])};
            *(bf16x4*)(s_v + s0*36 + nQ*4) = w0;
            *(bf16x4*)(s_v + s0*36 + 16 + nQ*4) = w1;
        }
    }
    __syncthreads();

    // ---- stage C: t1[180][32] ----
    {
        bf16x8 wc0[9], wc1[9];
        #pragma unroll
        for (int k=0;k<9;++k){
            wc0[k] = *(const bf16x8*)(wTr1a + k*1024 + nn*32 + nQ*8);
            wc1[k] = *(const bf16x8*)(wTr1a + k*1024 + (16+nn)*32 + nQ*8);
        }
        for (int nt = wv; nt < 12; nt += 4){
            int s0 = nt*16 + nn;
            int s = s0 > 179 ? 179 : s0;
            int qy = s/10, qx = s%10;
            f32x4 acc0 = {0,0,0,0}, acc1 = {0,0,0,0};
            #pragma unroll
            for (int ky=0; ky<3; ++ky)
                #pragma unroll
                for (int kx=0; kx<3; ++kx){
                    const int k = ky*3+kx;
                    bf16x8 bfr = lds8(s_v + ((qy+ky)*12 + qx+kx)*36 + nQ*8);
                    acc0 = MFMA_B16(wc0[k], bfr, acc0, 0,0,0);
                    acc1 = MFMA_B16(wc1[k], bfr, acc1, 0,0,0);
                }
            if (s0 <= 179){
                u8 m = s_m[(qy+2)*14 + qx+2];
                float r[8];
                #pragma unroll
                for (int g=0; g<2; ++g)
                    #pragma unroll
                    for (int e=0; e<4; ++e){
                        float a = (g ? acc1[e] : acc0[e]) * BNS;
                        r[g*4+e] = m ? (a > 0.f ? a : 0.2f*a) : 0.f;
                    }
                bf16x4 w0 = {f2bs(r[0]),f2bs(r[1]),f2bs(r[2]),f2bs(r[3])};
                bf16x4 w1 = {f2bs(r[4]),f2bs(r[5]),f2bs(r[6]),f2bs(r[7])};
                *(bf16x4*)(s_t1 + s*36 + nQ*4) = w0;
                *(bf16x4*)(s_t1 + s*36 + 16 + nQ*4) = w1;
            }
        }
    }
    __syncthreads();

    // ---- stage D: out 16x8 via MFMA (co=0 row of wTr1b) ----
    {
        float bb = r1_b2[0];
        #pragma unroll
        for (int u2 = 0; u2 < 2; ++u2){
            int nt = u2*4 + wv;          // 0..7
            int s0 = nt*16 + nn;         // 0..127
            int ty = s0 >> 3, tx = s0 & 7;
            f32x4 acc = {0,0,0,0};
            #pragma unroll
            for (int ky=0; ky<3; ++ky)
                #pragma unroll
                for (int kx=0; kx<3; ++kx){
                    const int k = ky*3+kx;
                    bf16x8 bfr = lds8(s_t1 + ((ty+ky)*10 + tx+kx)*36 + nQ*8);
                    bf16x8 aw = *(const bf16x8*)(wTr1b + k*512 + nn*32 + nQ*8);
                    acc = MFMA_B16(aw, bfr, acc, 0,0,0);
                }
            if (nQ == 0){
                u8 m = s_m[(ty+3)*14 + tx+3];
                float o = m ? acc[0] + bb : -99.f;
                out1[(size_t)n*HW1 + (y0+ty)*H1 + (x0+tx)] = o;
            }
        }
    }
}

// ---------------- launch ----------------

extern "C" void kernel_launch(void* const* d_in, const int* in_sizes, int n_in,
                              void* d_out, int out_size, void* d_ws, size_t ws_size,
                              hipStream_t stream)
{
    const float* x      = (const float*)d_in[0];
    const float* image  = (const float*)d_in[1];
    const float* masks  = (const float*)d_in[2];
    const float* roi    = (const float*)d_in[3];
    const float* w1a    = (const float*)d_in[4];
    const float* w1b    = (const float*)d_in[5];
    const float* w2a    = (const float*)d_in[6];
    const float* w2b    = (const float*)d_in[7];
    const float* w4a    = (const float*)d_in[8];
    const float* w4b    = (const float*)d_in[9];
    const float* inv4_w = (const float*)d_in[10];
    const float* l4_sub = (const float*)d_in[11];
    const float* inv2_w = (const float*)d_in[12];
    const float* l5_sub = (const float*)d_in[13];
    const float* r4_w1  = (const float*)d_in[14];
    const float* r4_w2  = (const float*)d_in[15];
    const float* r4_b2  = (const float*)d_in[16];
    const float* r1_w1  = (const float*)d_in[17];
    const float* r1_w2  = (const float*)d_in[18];
    const float* r1_b2  = (const float*)d_in[19];
    float* out = (float*)d_out;

    const int N = 8;
    const int H1 = 384, HW1 = 384*384;
    const int H2 = 192, HW2 = 192*192;
    const int H4 = 96,  HW4 = 96*96;

    char* wsp = (char*)d_ws;
    size_t off = 0;
    auto alloc = [&](size_t bytes) -> char* {
        char* p = wsp + off;
        off += (bytes + 255) & ~(size_t)255;
        return p;
    };
    bf16* FEA1 = (bf16*)alloc((size_t)N*32*HW1*2);
    u8*   M1   = (u8*)alloc((size_t)N*HW1);
    u8*   M2   = (u8*)alloc((size_t)N*HW2);
    u8*   M4   = (u8*)alloc((size_t)N*HW4);
    bf16* FEA2 = (bf16*)alloc((size_t)N*32*HW2*2);
    bf16* XS   = (bf16*)alloc((size_t)N*64*HW4*2);
    bf16* GU   = (bf16*)alloc((size_t)N*32*HW2*2);  // g, then u
    bf16* HT   = (bf16*)alloc((size_t)N*64*HW4*2);  // h, then t_leaky
    short* WT   = (short*)alloc(6*9216*2);          // [w1bT, inv2T, l5T, r1aT, w2bT, w2aT]
    short* WT4  = (short*)alloc((size_t)129024*2);  // [inv4T, w4bT, l4sT, r4w1T, w4aT]
    short* WT1a = (short*)alloc(2048*2);
    short* WTh  = (short*)alloc(2*4608*2);          // [r1_w2 head, r4_w2 head]
    (void)ws_size; (void)in_sizes; (void)n_in; (void)out_size;

    short* wT1b  = WT;
    short* wTi2  = WT + 9216;
    short* wTl5  = WT + 2*9216;
    short* wTr1a = WT + 3*9216;
    short* wT2b  = WT + 4*9216;
    short* wT2a  = WT + 5*9216;
    short* wTi4  = WT4;
    short* wT4b  = WT4 + 36864;
    short* wTl4  = WT4 + 73728;
    short* wTr4a = WT4 + 92160;
    short* wT4a  = WT4 + 110592;
    short* wTr1b = WTh;
    short* wTr4b = WTh + 4608;

    dim3 blk(256);

    // masks + weight prep
    k_mask1<<<dim3((N*HW1 + 255)/256), blk, 0, stream>>>(roi, M1, N*HW1);
    k_down<<<dim3((HW2 + 255)/256, N), blk, 0, stream>>>(M1, M2, H1, H1, H2, H2);
    k_down<<<dim3((HW4 + 255)/256, N), blk, 0, stream>>>(M2, M4, H2, H2, H4, H4);
    k_wprep<<<dim3(36, 6), blk, 0, stream>>>(w1b, inv2_w, l5_sub, r1_w1, w2b, w2a, WT);
    k_wprep4<<<dim3(144, 5), blk, 0, stream>>>(inv4_w, w4b, l4_sub, r4_w1, w4a, WT4);
    k_wprep_misc<<<dim3(18, 3), blk, 0, stream>>>(w1a, r1_w2, r4_w2, WT1a, WTh);

    // front
    conv1ab3<<<dim3(1152, 1, N), blk, 0, stream>>>(image, masks, M1, WT1a, wT1b, (short*)FEA1);
    mconv_s2m<32><<<dim3(288, 1, N), blk, 0, stream>>>((const short*)FEA1, H1, wT2a, M2, (short*)GU, H2, 12);
    mconv_s1<32,32,0><<<dim3(144, 1, N), blk, 0, stream>>>((const short*)GU, H2, wT2b, M2, nullptr, (short*)FEA2, 12);
    mconv_s2m<64><<<dim3(72, 1, N), blk, 0, stream>>>((const short*)FEA2, H2, wT4a, M4, (short*)HT, H4, 6);
    mconv_s1<64,64,3><<<dim3(36, 1, N), blk, 0, stream>>>((const short*)HT, H4, wT4b, M4, x, (short*)XS, 6);

    // refine_OS4
    mconv_s1<64,32,1><<<dim3(36, 1, N), blk, 0, stream>>>((const short*)XS, H4, wTr4a, M4, nullptr, (short*)HT, 6);
    mconv_head32<<<dim3(36, 1, N), blk, 0, stream>>>((const short*)HT, H4, wTr4b, r4_b2, M4, out, 6);

    // layer4 fused (MFMA) -> u
    fk_l4c<<<dim3(144, 1, N), blk, 0, stream>>>((const short*)XS, (const short*)FEA2, M2,
                                                wTi4, wTl4, (short*)GU);

    // MFMA back end -> out1
    fk_back6<<<dim3(1152, 1, N), blk, 0, stream>>>((const short*)GU, (const short*)FEA1, M1,
                                                   wTi2, wTl5, wTr1a, wTr1b, r1_b2,
                                                   out + (size_t)N*HW4);
}